// Round 2
// baseline (6426.548 us; speedup 1.0000x reference)
//
#include <hip/hip_runtime.h>
#include <hip/hip_bf16.h>
#include <math.h>

// Problem constants
#define HH 180
#define WW 360
#define CC 768
#define FF 91          // kept W-frequencies (km = 91)
#define NPOS (HH*FF)   // 16380 frequency positions
#define NROW (HH*WW)   // 64800 spatial rows
#define LAT 3072
#define CHC 96         // channels per filter chunk (= one block-diag block)
#define NCHUNK 8
#define MCH 8100       // rows per MLP chunk (64800 = 8*8100)

typedef __attribute__((ext_vector_type(8))) short bf16x8;
typedef __attribute__((ext_vector_type(4))) float f32x4;
typedef __attribute__((ext_vector_type(4))) unsigned int u32x4;

__device__ __forceinline__ float gelu_f(float x) {
    return 0.5f * x * (1.0f + erff(x * 0.7071067811865476f));
}

// ---------------- modulation: both scale/shift MLPs ----------------
__global__ __launch_bounds__(256) void modulation_kernel(
        const float* __restrict__ e,
        const float* __restrict__ fs_w0, const float* __restrict__ fs_b0,
        const float* __restrict__ fs_w1, const float* __restrict__ fs_b1,
        const float* __restrict__ ms_w0, const float* __restrict__ ms_b0,
        const float* __restrict__ ms_w1, const float* __restrict__ ms_b1,
        float* __restrict__ s_f, float* __restrict__ t_f,
        float* __restrict__ s_m, float* __restrict__ t_m) {
    __shared__ float es[64];
    __shared__ float mid[6144];
    int t = threadIdx.x;
    if (t < 64) es[t] = e[t];
    __syncthreads();
    int blk = blockIdx.x;
    if (blk < 12) {
        for (int j = t; j < 1536; j += 256) {
            float a = fs_b0[j];
            for (int k = 0; k < 64; k++) a += es[k] * fs_w0[k*1536 + j];
            mid[j] = gelu_f(a);
        }
        __syncthreads();
        if (t < 128) {
            int jo = blk*128 + t;
            float a = fs_b1[jo];
            for (int j = 0; j < 1536; j++) a += mid[j] * fs_w1[(size_t)j*1536 + jo];
            if (jo < 768) s_f[jo] = 1.0f + a;
            else          t_f[jo - 768] = a;
        }
    } else {
        int b2 = blk - 12;
        for (int j = t; j < 6144; j += 256) {
            float a = ms_b0[j];
            for (int k = 0; k < 64; k++) a += es[k] * ms_w0[k*6144 + j];
            mid[j] = gelu_f(a);
        }
        __syncthreads();
        if (t < 128) {
            int jo = b2*128 + t;
            float a = ms_b1[jo];
            for (int j = 0; j < 6144; j++) a += mid[j] * ms_w1[(size_t)j*6144 + jo];
            if (jo < 3072) s_m[jo] = 1.0f + a;
            else           t_m[jo - 3072] = a;
        }
    }
}

// ---------------- LayerNorm fp32 out (one wave per 768-row) ----------------
__global__ __launch_bounds__(256) void ln_f32_kernel(const float* __restrict__ in,
        const float* __restrict__ w, const float* __restrict__ b,
        float* __restrict__ out) {
    int row = blockIdx.x*4 + (threadIdx.x >> 6);
    int l = threadIdx.x & 63;
    const float* p = in + (size_t)row*CC;
    float v[12]; float s = 0.f, sq = 0.f;
    #pragma unroll
    for (int i = 0; i < 12; i++) { float tv = p[l + 64*i]; v[i] = tv; s += tv; sq += tv*tv; }
    #pragma unroll
    for (int m = 1; m < 64; m <<= 1) { s += __shfl_xor(s, m); sq += __shfl_xor(sq, m); }
    float mean = s * (1.0f/768.0f);
    float var  = sq * (1.0f/768.0f) - mean*mean;
    float rstd = rsqrtf(var + 1e-5f);
    float* o = out + (size_t)row*CC;
    #pragma unroll
    for (int i = 0; i < 12; i++) { int c = l + 64*i; o[c] = (v[i]-mean)*rstd*w[c] + b[c]; }
}

// ---------------- LayerNorm bf16 out ----------------
__global__ __launch_bounds__(256) void ln_bf16_kernel(const float* __restrict__ in,
        const float* __restrict__ w, const float* __restrict__ b,
        __hip_bfloat16* __restrict__ out) {
    int row = blockIdx.x*4 + (threadIdx.x >> 6);
    int l = threadIdx.x & 63;
    const float* p = in + (size_t)row*CC;
    float v[12]; float s = 0.f, sq = 0.f;
    #pragma unroll
    for (int i = 0; i < 12; i++) { float tv = p[l + 64*i]; v[i] = tv; s += tv; sq += tv*tv; }
    #pragma unroll
    for (int m = 1; m < 64; m <<= 1) { s += __shfl_xor(s, m); sq += __shfl_xor(sq, m); }
    float mean = s * (1.0f/768.0f);
    float var  = sq * (1.0f/768.0f) - mean*mean;
    float rstd = rsqrtf(var + 1e-5f);
    __hip_bfloat16* o = out + (size_t)row*CC;
    #pragma unroll
    for (int i = 0; i < 12; i++) { int c = l + 64*i; o[c] = __float2bfloat16((v[i]-mean)*rstd*w[c] + b[c]); }
}

// ---------------- forward rDFT along W (360 -> 91 complex freqs), one 96-ch chunk ----------------
// Y[h,f,c] = (1/sqrt(360)) * sum_w x[h,w,cb0+c] * e^{-2pi i f w/360}
__global__ __launch_bounds__(256) void wdft_kernel(const float* __restrict__ hln,
        int cb0, float* __restrict__ Yr, float* __restrict__ Yi) {
    int h = blockIdx.y;
    int cbase = blockIdx.x * 32;   // 0,32,64 within chunk
    __shared__ float Xs[360*32];
    int t = threadIdx.x;
    const float* src = hln + (size_t)h*WW*CC + cb0 + cbase;
    for (int e2 = t; e2 < 360*32; e2 += 256) {
        int w = e2 >> 5, c = e2 & 31;
        Xs[e2] = src[(size_t)w*CC + c];
    }
    __syncthreads();
    int c = t & 31, fg = t >> 5;   // fg 0..7 ; f = fg + 8q, q<12 (covers 0..95, guard <91)
    float ar[12], ai[12], rr[12], ri[12], stc[12], sts[12];
    #pragma unroll
    for (int q = 0; q < 12; q++) {
        int f = fg + 8*q;
        float ang = -6.283185307179586f * (float)f / 360.0f;
        float s_, c_; sincosf(ang, &s_, &c_);
        stc[q] = c_; sts[q] = s_;
        rr[q] = 1.0f; ri[q] = 0.0f; ar[q] = 0.0f; ai[q] = 0.0f;
    }
    for (int w = 0; w < 360; w++) {
        float xv = Xs[w*32 + c];
        #pragma unroll
        for (int q = 0; q < 12; q++) {
            ar[q] += xv * rr[q];
            ai[q] += xv * ri[q];
            float nr = rr[q]*stc[q] - ri[q]*sts[q];
            float ni = rr[q]*sts[q] + ri[q]*stc[q];
            rr[q] = nr; ri[q] = ni;
        }
    }
    const float rn = 0.05270462766947299f;  // 1/sqrt(360)
    #pragma unroll
    for (int q = 0; q < 12; q++) {
        int f = fg + 8*q;
        if (f < FF) {
            size_t idx = ((size_t)h*FF + f)*CHC + cbase + c;
            Yr[idx] = ar[q]*rn;
            Yi[idx] = ai[q]*rn;
        }
    }
}

// ---------------- complex FFT along H (180 -> 180), sign = -1 fwd / +1 inv, chunk ----------------
__global__ __launch_bounds__(512) void hfft_kernel(const float* __restrict__ Ir,
        const float* __restrict__ Ii, float* __restrict__ Or_, float* __restrict__ Oi_,
        float sign) {
    int f = blockIdx.x;
    int cbase = blockIdx.y * 32;   // 0,32,64
    __shared__ float Sr[180*32];
    __shared__ float Si[180*32];
    int t = threadIdx.x;
    for (int e2 = t; e2 < 180*32; e2 += 512) {
        int h = e2 >> 5, c = e2 & 31;
        size_t idx = ((size_t)h*FF + f)*CHC + cbase + c;
        Sr[e2] = Ir[idx];
        Si[e2] = Ii[idx];
    }
    __syncthreads();
    int c = t & 31, g = t >> 5;   // g 0..15 ; o = g + 16q, q<12 (guard <180)
    float ar[12], ai[12], rr[12], ri[12], stc[12], sts[12];
    #pragma unroll
    for (int q = 0; q < 12; q++) {
        int o = g + 16*q;
        float ang = sign * 6.283185307179586f * (float)o / 180.0f;
        float s_, c_; sincosf(ang, &s_, &c_);
        stc[q] = c_; sts[q] = s_;
        rr[q] = 1.0f; ri[q] = 0.0f; ar[q] = 0.0f; ai[q] = 0.0f;
    }
    for (int i = 0; i < 180; i++) {
        float yr = Sr[i*32 + c], yi = Si[i*32 + c];
        #pragma unroll
        for (int q = 0; q < 12; q++) {
            ar[q] += yr*rr[q] - yi*ri[q];
            ai[q] += yr*ri[q] + yi*rr[q];
            float nr = rr[q]*stc[q] - ri[q]*sts[q];
            float ni = rr[q]*sts[q] + ri[q]*stc[q];
            rr[q] = nr; ri[q] = ni;
        }
    }
    const float rn = 0.07453559924999299f;  // 1/sqrt(180)
    #pragma unroll
    for (int q = 0; q < 12; q++) {
        int o = g + 16*q;
        if (o < 180) {
            size_t idx = ((size_t)o*FF + f)*CHC + cbase + c;
            Or_[idx] = ar[q]*rn;
            Oi_[idx] = ai[q]*rn;
        }
    }
}

// ---------------- per-frequency block-diagonal complex matmul (one block wb) ----------------
// LAYER 0: o = relu((I@W + b)*s + t) ; LAYER 1: o = softshrink(I@W + b)
template<int LAYER>
__global__ __launch_bounds__(192) void bd_kernel(
        const float* __restrict__ Ir, const float* __restrict__ Ii,
        const float* __restrict__ wgt, const float* __restrict__ bias,
        const float* __restrict__ sf, const float* __restrict__ tf,
        int wb,
        float* __restrict__ Or_, float* __restrict__ Oi_) {
    int tile = blockIdx.x;   // 32 positions per tile
    int p0 = tile * 32;
    __shared__ float2 Ls[32*96];
    int t = threadIdx.x;
    for (int e2 = t; e2 < 32*96; e2 += 192) {
        int pp = e2 / 96, cc = e2 - pp*96;
        int p = p0 + pp; if (p >= NPOS) p = NPOS - 1;
        size_t idx = (size_t)p*CHC + cc;
        Ls[e2] = make_float2(Ir[idx], Ii[idx]);
    }
    __syncthreads();
    int oc = (t >= 96) ? (t - 96) : t;
    int pg = (t >= 96) ? 1 : 0;
    const float* Wr = wgt + (size_t)wb * 9216;          // w[0][wb][k][oc]
    const float* Wi = wgt + (size_t)(8 + wb) * 9216;    // w[1][wb][k][oc]
    float br = bias[wb*96 + oc];
    float bi = bias[768 + wb*96 + oc];
    float ar[16], ai[16];
    #pragma unroll
    for (int i = 0; i < 16; i++) { ar[i] = br; ai[i] = bi; }
    for (int k = 0; k < 96; k++) {
        float wr = Wr[k*96 + oc];
        float wi = Wi[k*96 + oc];
        #pragma unroll
        for (int i = 0; i < 16; i++) {
            float2 y = Ls[(pg + 2*i)*96 + k];
            ar[i] += y.x*wr - y.y*wi;
            ai[i] += y.x*wi + y.y*wr;
        }
    }
    if (LAYER == 0) {
        float s  = sf[wb*96 + oc];
        float tt = tf[wb*96 + oc];
        #pragma unroll
        for (int i = 0; i < 16; i++) {
            int p = p0 + pg + 2*i;
            if (p < NPOS) {
                size_t idx = (size_t)p*CHC + oc;
                Or_[idx] = fmaxf(ar[i]*s + tt, 0.0f);
                Oi_[idx] = fmaxf(ai[i]*s + tt, 0.0f);
            }
        }
    } else {
        #pragma unroll
        for (int i = 0; i < 16; i++) {
            int p = p0 + pg + 2*i;
            if (p < NPOS) {
                float vr = ar[i], vi = ai[i];
                vr = (vr > 0.01f) ? (vr - 0.01f) : ((vr < -0.01f) ? (vr + 0.01f) : 0.0f);
                vi = (vi > 0.01f) ? (vi - 0.01f) : ((vi < -0.01f) ? (vi + 0.01f) : 0.0f);
                size_t idx = (size_t)p*CHC + oc;
                Or_[idx] = vr;
                Oi_[idx] = vi;
            }
        }
    }
}

// ---------------- inverse rDFT along W + bias(hln in hout) + residual(x), in place ----------------
__global__ __launch_bounds__(512) void iwdft_kernel(const float* __restrict__ Zr,
        const float* __restrict__ Zi, const float* __restrict__ xin,
        int cb0, float* __restrict__ hout) {
    int h = blockIdx.y;
    int cbase = blockIdx.x * 16;   // 0..80 within chunk
    __shared__ float Sr[91*16];
    __shared__ float Si[91*16];
    int t = threadIdx.x;
    for (int e2 = t; e2 < 91*16; e2 += 512) {
        int f = e2 >> 4, c = e2 & 15;
        size_t idx = ((size_t)h*FF + f)*CHC + cbase + c;
        Sr[e2] = Zr[idx];
        Si[e2] = Zi[idx];
    }
    __syncthreads();
    int c = t & 15, g = t >> 4;   // g 0..31 ; w = g + 32q, q<12 (guard <360)
    float acc[12], rr[12], ri[12], stc[12], sts[12];
    #pragma unroll
    for (int q = 0; q < 12; q++) {
        int w = g + 32*q;
        float ang = 6.283185307179586f * (float)w / 360.0f;
        float s_, c_; sincosf(ang, &s_, &c_);
        stc[q] = c_; sts[q] = s_;
        rr[q] = 1.0f; ri[q] = 0.0f; acc[q] = 0.0f;
    }
    for (int f = 0; f < 91; f++) {
        float zr = Sr[f*16 + c], zi = Si[f*16 + c];
        float m = (f == 0) ? 1.0f : 2.0f;
        zr *= m; zi *= m;
        #pragma unroll
        for (int q = 0; q < 12; q++) {
            acc[q] += zr*rr[q] - zi*ri[q];
            float nr = rr[q]*stc[q] - ri[q]*sts[q];
            float ni = rr[q]*sts[q] + ri[q]*stc[q];
            rr[q] = nr; ri[q] = ni;
        }
    }
    const float rn = 0.05270462766947299f;  // 1/sqrt(360)
    #pragma unroll
    for (int q = 0; q < 12; q++) {
        int w = g + 32*q;
        if (w < 360) {
            size_t o = ((size_t)h*WW + w)*CC + cb0 + cbase + c;
            hout[o] = acc[q]*rn + hout[o] + xin[o];
        }
    }
}

// ---------------- weight transpose + bf16 convert: dst[n*K+k] = bf16(src[k*N+n]) ----------------
__global__ __launch_bounds__(256) void transpose_bf16_kernel(const float* __restrict__ src,
        __hip_bfloat16* __restrict__ dst, int K, int N) {
    size_t j = (size_t)blockIdx.x * 256 + threadIdx.x;
    if (j < (size_t)K * N) {
        int n = (int)(j / K);
        int k = (int)(j - (size_t)n * K);
        dst[j] = __float2bfloat16(src[(size_t)k * N + n]);
    }
}

// ---------------- bf16 MFMA GEMM, 128x128 tile, BK=32, 4 waves ----------------
// MODE 0: hmid = bf16(gelu((A@B + bias)*s + t))   MODE 1: out = A@B + bias + resid (fp32)
template<int MODE>
__global__ __launch_bounds__(256) void gemm_kernel(
        const __hip_bfloat16* __restrict__ A,   // [M][K] bf16
        const __hip_bfloat16* __restrict__ Bt,  // [N][K] bf16 (pre-transposed)
        int M, int K, int N,
        const float* __restrict__ bias,
        const float* __restrict__ sv, const float* __restrict__ tv,
        const float* resid, void* out) {
    __shared__ unsigned short As[128*32];
    __shared__ unsigned short Bs[128*32];
    int tid = threadIdx.x;
    int nbase = blockIdx.x * 128;
    int mbase = blockIdx.y * 128;
    int l = tid & 63, wv = tid >> 6;
    int wm = wv & 1, wn = wv >> 1;
    int lm = l & 15;
    int kgrp = (l >> 4) * 8;
    f32x4 acc[4][4] = {};
    int nkt = K >> 5;
    for (int kt = 0; kt < nkt; kt++) {
        int kb = kt * 32;
        __syncthreads();
        #pragma unroll
        for (int r = 0; r < 2; r++) {
            int ch = tid + 256*r;          // 0..511
            int row = ch >> 2;
            int ko = (ch & 3) * 8;
            int am = mbase + row; if (am >= M) am = M - 1;
            u32x4 va = *(const u32x4*)(A + (size_t)am * K + kb + ko);
            int bn = nbase + row;          // N is a multiple of 128
            u32x4 vb = *(const u32x4*)(Bt + (size_t)bn * K + kb + ko);
            *(u32x4*)(As + ch*8) = va;
            *(u32x4*)(Bs + ch*8) = vb;
        }
        __syncthreads();
        bf16x8 af[4], bfv[4];
        #pragma unroll
        for (int i = 0; i < 4; i++) {
            af[i]  = *(const bf16x8*)(As + (wm*64 + i*16 + lm)*32 + kgrp);
            bfv[i] = *(const bf16x8*)(Bs + (wn*64 + i*16 + lm)*32 + kgrp);
        }
        #pragma unroll
        for (int i = 0; i < 4; i++)
            #pragma unroll
            for (int j = 0; j < 4; j++)
                acc[i][j] = __builtin_amdgcn_mfma_f32_16x16x32_bf16(af[i], bfv[j], acc[i][j], 0, 0, 0);
    }
    int r0 = (l >> 4) * 4;
    #pragma unroll
    for (int j = 0; j < 4; j++) {
        int col = nbase + wn*64 + j*16 + lm;
        float bb = bias[col];
        float ss = 0.f, tt = 0.f;
        if (MODE == 0) { ss = sv[col]; tt = tv[col]; }
        #pragma unroll
        for (int i = 0; i < 4; i++) {
            int rowb = mbase + wm*64 + i*16 + r0;
            #pragma unroll
            for (int r = 0; r < 4; r++) {
                int row = rowb + r;
                if (row < M) {
                    float v = acc[i][j][r] + bb;
                    if (MODE == 0) {
                        v = gelu_f(v*ss + tt);
                        ((__hip_bfloat16*)out)[(size_t)row*N + col] = __float2bfloat16(v);
                    } else {
                        ((float*)out)[(size_t)row*N + col] = v + resid[(size_t)row*N + col];
                    }
                }
            }
        }
    }
}

extern "C" void kernel_launch(void* const* d_in, const int* in_sizes, int n_in,
                              void* d_out, int out_size, void* d_ws, size_t ws_size,
                              hipStream_t stream) {
    const float* x     = (const float*)d_in[0];
    const float* emb   = (const float*)d_in[1];
    const float* n1w   = (const float*)d_in[2];
    const float* n1b   = (const float*)d_in[3];
    const float* n2w   = (const float*)d_in[4];
    const float* n2b   = (const float*)d_in[5];
    const float* w1    = (const float*)d_in[6];
    const float* b1    = (const float*)d_in[7];
    const float* w2    = (const float*)d_in[8];
    const float* b2    = (const float*)d_in[9];
    const float* fs_w0 = (const float*)d_in[10];
    const float* fs_b0 = (const float*)d_in[11];
    const float* fs_w1 = (const float*)d_in[12];
    const float* fs_b1 = (const float*)d_in[13];
    const float* fc1w  = (const float*)d_in[14];
    const float* fc1b  = (const float*)d_in[15];
    const float* fc2w  = (const float*)d_in[16];
    const float* fc2b  = (const float*)d_in[17];
    const float* ms_w0 = (const float*)d_in[18];
    const float* ms_b0 = (const float*)d_in[19];
    const float* ms_w1 = (const float*)d_in[20];
    const float* ms_b1 = (const float*)d_in[21];
    float* out = (float*)d_out;
    (void)in_sizes; (void)n_in; (void)out_size; (void)ws_size;

    char* wsb = (char*)d_ws;
    size_t off = 0;
    auto alloc = [&](size_t nbytes) -> void* {
        void* p = wsb + off;
        off += (nbytes + 255) & ~(size_t)255;
        return p;
    };
    // total ws usage ~97 MB
    float* s_f  = (float*)alloc(768*4);
    float* t_f  = (float*)alloc(768*4);
    float* s_m  = (float*)alloc(3072*4);
    float* t_m  = (float*)alloc(3072*4);
    float* Yr   = (float*)alloc((size_t)NPOS*CHC*4);
    float* Yi   = (float*)alloc((size_t)NPOS*CHC*4);
    float* Zr   = (float*)alloc((size_t)NPOS*CHC*4);
    float* Zi   = (float*)alloc((size_t)NPOS*CHC*4);
    __hip_bfloat16* wT1  = (__hip_bfloat16*)alloc((size_t)CC*LAT*2);
    __hip_bfloat16* wT2  = (__hip_bfloat16*)alloc((size_t)CC*LAT*2);
    __hip_bfloat16* h2c  = (__hip_bfloat16*)alloc((size_t)MCH*CC*2);
    __hip_bfloat16* hmid = (__hip_bfloat16*)alloc((size_t)MCH*LAT*2);

    // 1. modulation scale/shift vectors
    modulation_kernel<<<60, 256, 0, stream>>>(emb, fs_w0, fs_b0, fs_w1, fs_b1,
                                              ms_w0, ms_b0, ms_w1, ms_b1,
                                              s_f, t_f, s_m, t_m);
    // 2. LN1 -> d_out (h_ln lives in d_out)
    ln_f32_kernel<<<NROW/4, 256, 0, stream>>>(x, n1w, n1b, out);
    // 3. weight convert+transpose (independent of filter path)
    transpose_bf16_kernel<<<(CC*LAT + 255)/256, 256, 0, stream>>>(fc1w, wT1, 768, 3072);
    transpose_bf16_kernel<<<(CC*LAT + 255)/256, 256, 0, stream>>>(fc2w, wT2, 3072, 768);

    // 4. filter path, 8 chunks of 96 channels (one block-diag block each)
    for (int ch = 0; ch < NCHUNK; ch++) {
        int cb0 = ch * CHC;
        wdft_kernel<<<dim3(3, 180), 256, 0, stream>>>(out, cb0, Yr, Yi);
        hfft_kernel<<<dim3(91, 3), 512, 0, stream>>>(Yr, Yi, Zr, Zi, -1.0f);
        bd_kernel<0><<<dim3(512, 1), 192, 0, stream>>>(Zr, Zi, w1, b1, s_f, t_f, ch, Yr, Yi);
        bd_kernel<1><<<dim3(512, 1), 192, 0, stream>>>(Yr, Yi, w2, b2, nullptr, nullptr, ch, Zr, Zi);
        hfft_kernel<<<dim3(91, 3), 512, 0, stream>>>(Zr, Zi, Yr, Yi, 1.0f);
        // in-place: out = idft + out(h_ln) + x  for this channel slice
        iwdft_kernel<<<dim3(6, 180), 512, 0, stream>>>(Yr, Yi, x, cb0, out);
    }

    // 5. MLP path, 8 chunks of 8100 rows (d_out holds h; update in place)
    for (int mc = 0; mc < NCHUNK; mc++) {
        size_t base = (size_t)mc * MCH;
        // LN2 of chunk -> h2c (bf16)
        ln_bf16_kernel<<<MCH/4, 256, 0, stream>>>(out + base*CC, n2w, n2b, h2c);
        // fc1 + modulation + gelu -> hmid (bf16)
        gemm_kernel<0><<<dim3(LAT/128, (MCH+127)/128), 256, 0, stream>>>(
            h2c, wT1, MCH, CC, LAT, fc1b, s_m, t_m, nullptr, hmid);
        // fc2 + bias + residual(h) -> out (in place, elementwise)
        gemm_kernel<1><<<dim3(CC/128, (MCH+127)/128), 256, 0, stream>>>(
            hmid, wT2, MCH, LAT, CC, fc2b, nullptr, nullptr, out + base*CC, out + base*CC);
    }
}

// Round 3
// 5947.436 us; speedup vs baseline: 1.0806x; 1.0806x over previous
//
#include <hip/hip_runtime.h>
#include <hip/hip_bf16.h>
#include <math.h>

// Problem constants
#define HH 180
#define WW 360
#define CC 768
#define FF 91          // kept W-frequencies (km = 91)
#define NPOS (HH*FF)   // 16380 frequency positions
#define NROW (HH*WW)   // 64800 spatial rows
#define LAT 3072
#define CHC 96         // channels per filter chunk (= one block-diag block)
#define NCHUNK 8
#define MCH 8100       // rows per MLP chunk (64800 = 8*8100)

typedef __attribute__((ext_vector_type(8))) short bf16x8;
typedef __attribute__((ext_vector_type(4))) float f32x4;
typedef __attribute__((ext_vector_type(4))) unsigned int u32x4;

__device__ __forceinline__ float gelu_f(float x) {
    return 0.5f * x * (1.0f + erff(x * 0.7071067811865476f));
}

// ---------------- modulation stage A: mid = gelu(e @ w0 + b0), both paths ----------------
// outputs: mid_f[1536], mid_m[6144] ; 7680 outputs over 30 blocks x 256
__global__ __launch_bounds__(256) void mod_a_kernel(
        const float* __restrict__ e,
        const float* __restrict__ fs_w0, const float* __restrict__ fs_b0,
        const float* __restrict__ ms_w0, const float* __restrict__ ms_b0,
        float* __restrict__ mid_f, float* __restrict__ mid_m) {
    __shared__ float es[64];
    int t = threadIdx.x;
    if (t < 64) es[t] = e[t];
    __syncthreads();
    int j = blockIdx.x * 256 + t;
    if (j < 1536) {
        float a = fs_b0[j];
        #pragma unroll 8
        for (int k = 0; k < 64; k++) a += es[k] * fs_w0[k*1536 + j];
        mid_f[j] = gelu_f(a);
    } else {
        int jm = j - 1536;   // < 6144
        float a = ms_b0[jm];
        #pragma unroll 8
        for (int k = 0; k < 64; k++) a += es[k] * ms_w0[k*6144 + jm];
        mid_m[jm] = gelu_f(a);
    }
}

// ---------------- modulation stage B: o = mid @ w1 + b1 -> s,t ----------------
// blocks 0..23: filter (1536 outputs) ; blocks 24..119: mlp (6144 outputs)
// block = 512 thr = 8 k-groups x 64 outputs
__global__ __launch_bounds__(512) void mod_b_kernel(
        const float* __restrict__ mid_f, const float* __restrict__ mid_m,
        const float* __restrict__ fs_w1, const float* __restrict__ fs_b1,
        const float* __restrict__ ms_w1, const float* __restrict__ ms_b1,
        float* __restrict__ s_f, float* __restrict__ t_f,
        float* __restrict__ s_m, float* __restrict__ t_m) {
    __shared__ float red[8*64];
    int t = threadIdx.x;
    int g = t >> 6;          // k-group 0..7
    int jl = t & 63;         // output lane
    int blk = blockIdx.x;
    if (blk < 24) {
        int jo = blk*64 + jl;
        const int N = 1536, NQ = 192;
        float a = 0.f;
        const float* w = fs_w1 + (size_t)(g*NQ)*N + jo;
        for (int j = 0; j < NQ; j++) a += mid_f[g*NQ + j] * w[(size_t)j*N];
        red[t] = a;
        __syncthreads();
        if (t < 64) {
            float s = fs_b1[jo];
            #pragma unroll
            for (int q = 0; q < 8; q++) s += red[q*64 + jl];
            if (jo < 768) s_f[jo] = 1.0f + s;
            else          t_f[jo - 768] = s;
        }
    } else {
        int jo = (blk - 24)*64 + jl;
        const int N = 6144, NQ = 768;
        float a = 0.f;
        const float* w = ms_w1 + (size_t)(g*NQ)*N + jo;
        for (int j = 0; j < NQ; j++) a += mid_m[g*NQ + j] * w[(size_t)j*N];
        red[t] = a;
        __syncthreads();
        if (t < 64) {
            float s = ms_b1[jo];
            #pragma unroll
            for (int q = 0; q < 8; q++) s += red[q*64 + jl];
            if (jo < 3072) s_m[jo] = 1.0f + s;
            else           t_m[jo - 3072] = s;
        }
    }
}

// ---------------- LayerNorm fp32 out (one wave per 768-row) ----------------
__global__ __launch_bounds__(256) void ln_f32_kernel(const float* __restrict__ in,
        const float* __restrict__ w, const float* __restrict__ b,
        float* __restrict__ out) {
    int row = blockIdx.x*4 + (threadIdx.x >> 6);
    int l = threadIdx.x & 63;
    const float* p = in + (size_t)row*CC;
    float v[12]; float s = 0.f, sq = 0.f;
    #pragma unroll
    for (int i = 0; i < 12; i++) { float tv = p[l + 64*i]; v[i] = tv; s += tv; sq += tv*tv; }
    #pragma unroll
    for (int m = 1; m < 64; m <<= 1) { s += __shfl_xor(s, m); sq += __shfl_xor(sq, m); }
    float mean = s * (1.0f/768.0f);
    float var  = sq * (1.0f/768.0f) - mean*mean;
    float rstd = rsqrtf(var + 1e-5f);
    float* o = out + (size_t)row*CC;
    #pragma unroll
    for (int i = 0; i < 12; i++) { int c = l + 64*i; o[c] = (v[i]-mean)*rstd*w[c] + b[c]; }
}

// ---------------- LayerNorm bf16 out ----------------
__global__ __launch_bounds__(256) void ln_bf16_kernel(const float* __restrict__ in,
        const float* __restrict__ w, const float* __restrict__ b,
        __hip_bfloat16* __restrict__ out) {
    int row = blockIdx.x*4 + (threadIdx.x >> 6);
    int l = threadIdx.x & 63;
    const float* p = in + (size_t)row*CC;
    float v[12]; float s = 0.f, sq = 0.f;
    #pragma unroll
    for (int i = 0; i < 12; i++) { float tv = p[l + 64*i]; v[i] = tv; s += tv; sq += tv*tv; }
    #pragma unroll
    for (int m = 1; m < 64; m <<= 1) { s += __shfl_xor(s, m); sq += __shfl_xor(sq, m); }
    float mean = s * (1.0f/768.0f);
    float var  = sq * (1.0f/768.0f) - mean*mean;
    float rstd = rsqrtf(var + 1e-5f);
    __hip_bfloat16* o = out + (size_t)row*CC;
    #pragma unroll
    for (int i = 0; i < 12; i++) { int c = l + 64*i; o[c] = __float2bfloat16((v[i]-mean)*rstd*w[c] + b[c]); }
}

// ---------------- forward rDFT along W (360 -> 91 complex freqs), one 96-ch chunk ----------------
__global__ __launch_bounds__(256) void wdft_kernel(const float* __restrict__ hln,
        int cb0, float* __restrict__ Yr, float* __restrict__ Yi) {
    int h = blockIdx.y;
    int cbase = blockIdx.x * 32;   // 0,32,64 within chunk
    __shared__ float Xs[360*32];
    int t = threadIdx.x;
    const float* src = hln + (size_t)h*WW*CC + cb0 + cbase;
    for (int e2 = t; e2 < 360*32; e2 += 256) {
        int w = e2 >> 5, c = e2 & 31;
        Xs[e2] = src[(size_t)w*CC + c];
    }
    __syncthreads();
    int c = t & 31, fg = t >> 5;   // fg 0..7 ; f = fg + 8q, q<12 (covers 0..95, guard <91)
    float ar[12], ai[12], rr[12], ri[12], stc[12], sts[12];
    #pragma unroll
    for (int q = 0; q < 12; q++) {
        int f = fg + 8*q;
        float ang = -6.283185307179586f * (float)f / 360.0f;
        float s_, c_; sincosf(ang, &s_, &c_);
        stc[q] = c_; sts[q] = s_;
        rr[q] = 1.0f; ri[q] = 0.0f; ar[q] = 0.0f; ai[q] = 0.0f;
    }
    for (int w = 0; w < 360; w++) {
        float xv = Xs[w*32 + c];
        #pragma unroll
        for (int q = 0; q < 12; q++) {
            ar[q] += xv * rr[q];
            ai[q] += xv * ri[q];
            float nr = rr[q]*stc[q] - ri[q]*sts[q];
            float ni = rr[q]*sts[q] + ri[q]*stc[q];
            rr[q] = nr; ri[q] = ni;
        }
    }
    const float rn = 0.05270462766947299f;  // 1/sqrt(360)
    #pragma unroll
    for (int q = 0; q < 12; q++) {
        int f = fg + 8*q;
        if (f < FF) {
            size_t idx = ((size_t)h*FF + f)*CHC + cbase + c;
            Yr[idx] = ar[q]*rn;
            Yi[idx] = ai[q]*rn;
        }
    }
}

// ---------------- complex FFT along H (180 -> 180), sign = -1 fwd / +1 inv, chunk ----------------
__global__ __launch_bounds__(512) void hfft_kernel(const float* __restrict__ Ir,
        const float* __restrict__ Ii, float* __restrict__ Or_, float* __restrict__ Oi_,
        float sign) {
    int f = blockIdx.x;
    int cbase = blockIdx.y * 32;   // 0,32,64
    __shared__ float Sr[180*32];
    __shared__ float Si[180*32];
    int t = threadIdx.x;
    for (int e2 = t; e2 < 180*32; e2 += 512) {
        int h = e2 >> 5, c = e2 & 31;
        size_t idx = ((size_t)h*FF + f)*CHC + cbase + c;
        Sr[e2] = Ir[idx];
        Si[e2] = Ii[idx];
    }
    __syncthreads();
    int c = t & 31, g = t >> 5;   // g 0..15 ; o = g + 16q, q<12 (guard <180)
    float ar[12], ai[12], rr[12], ri[12], stc[12], sts[12];
    #pragma unroll
    for (int q = 0; q < 12; q++) {
        int o = g + 16*q;
        float ang = sign * 6.283185307179586f * (float)o / 180.0f;
        float s_, c_; sincosf(ang, &s_, &c_);
        stc[q] = c_; sts[q] = s_;
        rr[q] = 1.0f; ri[q] = 0.0f; ar[q] = 0.0f; ai[q] = 0.0f;
    }
    for (int i = 0; i < 180; i++) {
        float yr = Sr[i*32 + c], yi = Si[i*32 + c];
        #pragma unroll
        for (int q = 0; q < 12; q++) {
            ar[q] += yr*rr[q] - yi*ri[q];
            ai[q] += yr*ri[q] + yi*rr[q];
            float nr = rr[q]*stc[q] - ri[q]*sts[q];
            float ni = rr[q]*sts[q] + ri[q]*stc[q];
            rr[q] = nr; ri[q] = ni;
        }
    }
    const float rn = 0.07453559924999299f;  // 1/sqrt(180)
    #pragma unroll
    for (int q = 0; q < 12; q++) {
        int o = g + 16*q;
        if (o < 180) {
            size_t idx = ((size_t)o*FF + f)*CHC + cbase + c;
            Or_[idx] = ar[q]*rn;
            Oi_[idx] = ai[q]*rn;
        }
    }
}

// ---------------- per-frequency block-diagonal complex matmul (one block wb) ----------------
template<int LAYER>
__global__ __launch_bounds__(192) void bd_kernel(
        const float* __restrict__ Ir, const float* __restrict__ Ii,
        const float* __restrict__ wgt, const float* __restrict__ bias,
        const float* __restrict__ sf, const float* __restrict__ tf,
        int wb,
        float* __restrict__ Or_, float* __restrict__ Oi_) {
    int tile = blockIdx.x;   // 32 positions per tile
    int p0 = tile * 32;
    __shared__ float2 Ls[32*96];
    int t = threadIdx.x;
    for (int e2 = t; e2 < 32*96; e2 += 192) {
        int pp = e2 / 96, cc = e2 - pp*96;
        int p = p0 + pp; if (p >= NPOS) p = NPOS - 1;
        size_t idx = (size_t)p*CHC + cc;
        Ls[e2] = make_float2(Ir[idx], Ii[idx]);
    }
    __syncthreads();
    int oc = (t >= 96) ? (t - 96) : t;
    int pg = (t >= 96) ? 1 : 0;
    const float* Wr = wgt + (size_t)wb * 9216;          // w[0][wb][k][oc]
    const float* Wi = wgt + (size_t)(8 + wb) * 9216;    // w[1][wb][k][oc]
    float br = bias[wb*96 + oc];
    float bi = bias[768 + wb*96 + oc];
    float ar[16], ai[16];
    #pragma unroll
    for (int i = 0; i < 16; i++) { ar[i] = br; ai[i] = bi; }
    for (int k = 0; k < 96; k++) {
        float wr = Wr[k*96 + oc];
        float wi = Wi[k*96 + oc];
        #pragma unroll
        for (int i = 0; i < 16; i++) {
            float2 y = Ls[(pg + 2*i)*96 + k];
            ar[i] += y.x*wr - y.y*wi;
            ai[i] += y.x*wi + y.y*wr;
        }
    }
    if (LAYER == 0) {
        float s  = sf[wb*96 + oc];
        float tt = tf[wb*96 + oc];
        #pragma unroll
        for (int i = 0; i < 16; i++) {
            int p = p0 + pg + 2*i;
            if (p < NPOS) {
                size_t idx = (size_t)p*CHC + oc;
                Or_[idx] = fmaxf(ar[i]*s + tt, 0.0f);
                Oi_[idx] = fmaxf(ai[i]*s + tt, 0.0f);
            }
        }
    } else {
        #pragma unroll
        for (int i = 0; i < 16; i++) {
            int p = p0 + pg + 2*i;
            if (p < NPOS) {
                float vr = ar[i], vi = ai[i];
                vr = (vr > 0.01f) ? (vr - 0.01f) : ((vr < -0.01f) ? (vr + 0.01f) : 0.0f);
                vi = (vi > 0.01f) ? (vi - 0.01f) : ((vi < -0.01f) ? (vi + 0.01f) : 0.0f);
                size_t idx = (size_t)p*CHC + oc;
                Or_[idx] = vr;
                Oi_[idx] = vi;
            }
        }
    }
}

// ---------------- inverse rDFT along W + bias(hln in hout) + residual(x), in place ----------------
__global__ __launch_bounds__(512) void iwdft_kernel(const float* __restrict__ Zr,
        const float* __restrict__ Zi, const float* __restrict__ xin,
        int cb0, float* __restrict__ hout) {
    int h = blockIdx.y;
    int cbase = blockIdx.x * 16;   // 0..80 within chunk
    __shared__ float Sr[91*16];
    __shared__ float Si[91*16];
    int t = threadIdx.x;
    for (int e2 = t; e2 < 91*16; e2 += 512) {
        int f = e2 >> 4, c = e2 & 15;
        size_t idx = ((size_t)h*FF + f)*CHC + cbase + c;
        Sr[e2] = Zr[idx];
        Si[e2] = Zi[idx];
    }
    __syncthreads();
    int c = t & 15, g = t >> 4;   // g 0..31 ; w = g + 32q, q<12 (guard <360)
    float acc[12], rr[12], ri[12], stc[12], sts[12];
    #pragma unroll
    for (int q = 0; q < 12; q++) {
        int w = g + 32*q;
        float ang = 6.283185307179586f * (float)w / 360.0f;
        float s_, c_; sincosf(ang, &s_, &c_);
        stc[q] = c_; sts[q] = s_;
        rr[q] = 1.0f; ri[q] = 0.0f; acc[q] = 0.0f;
    }
    for (int f = 0; f < 91; f++) {
        float zr = Sr[f*16 + c], zi = Si[f*16 + c];
        float m = (f == 0) ? 1.0f : 2.0f;
        zr *= m; zi *= m;
        #pragma unroll
        for (int q = 0; q < 12; q++) {
            acc[q] += zr*rr[q] - zi*ri[q];
            float nr = rr[q]*stc[q] - ri[q]*sts[q];
            float ni = rr[q]*sts[q] + ri[q]*stc[q];
            rr[q] = nr; ri[q] = ni;
        }
    }
    const float rn = 0.05270462766947299f;  // 1/sqrt(360)
    #pragma unroll
    for (int q = 0; q < 12; q++) {
        int w = g + 32*q;
        if (w < 360) {
            size_t o = ((size_t)h*WW + w)*CC + cb0 + cbase + c;
            hout[o] = acc[q]*rn + hout[o] + xin[o];
        }
    }
}

// ---------------- weight transpose + bf16 convert: dst[n*K+k] = bf16(src[k*N+n]) ----------------
__global__ __launch_bounds__(256) void transpose_bf16_kernel(const float* __restrict__ src,
        __hip_bfloat16* __restrict__ dst, int K, int N) {
    size_t j = (size_t)blockIdx.x * 256 + threadIdx.x;
    if (j < (size_t)K * N) {
        int n = (int)(j / K);
        int k = (int)(j - (size_t)n * K);
        dst[j] = __float2bfloat16(src[(size_t)k * N + n]);
    }
}

// ---------------- bf16 MFMA GEMM, 128x128 tile, BK=32, 4 waves, global_load_lds staging ----------------
// MODE 0: hmid = bf16(gelu((A@B + bias)*s + t))   MODE 1: out = A@B + bias + resid (fp32)
template<int MODE>
__global__ __launch_bounds__(256) void gemm_kernel(
        const __hip_bfloat16* __restrict__ A,   // [M][K] bf16
        const __hip_bfloat16* __restrict__ Bt,  // [N][K] bf16 (pre-transposed)
        int M, int K, int N,
        const float* __restrict__ bias,
        const float* __restrict__ sv, const float* __restrict__ tv,
        const float* resid, void* out) {
    __shared__ unsigned short As[128*32];
    __shared__ unsigned short Bs[128*32];
    int tid = threadIdx.x;
    int nbase = blockIdx.x * 128;
    int mbase = blockIdx.y * 128;
    int l = tid & 63, wv = tid >> 6;
    int wm = wv & 1, wn = wv >> 1;
    int lm = l & 15;
    int kgrp = (l >> 4) * 8;
    f32x4 acc[4][4] = {};
    int nkt = K >> 5;
    for (int kt = 0; kt < nkt; kt++) {
        int kb = kt * 32;
        __syncthreads();
        // async global->LDS staging, 16B per lane per instruction
        #pragma unroll
        for (int i = 0; i < 2; i++) {
            int ch = (wv*2 + i)*64 + l;    // 0..511 ; LDS chunk = ch*16B, HW: base + lane*16
            int row = ch >> 2;
            int ko = (ch & 3) * 8;
            int am = mbase + row; if (am >= M) am = M - 1;
            const __hip_bfloat16* ga = A  + (size_t)am * K + kb + ko;
            const __hip_bfloat16* gb = Bt + (size_t)(nbase + row) * K + kb + ko;
            __builtin_amdgcn_global_load_lds(
                (const __attribute__((address_space(1))) void*)(unsigned long long)(uintptr_t)ga,
                (__attribute__((address_space(3))) void*)(unsigned long long)(uintptr_t)(As + (wv*2 + i)*512),
                16, 0, 0);
            __builtin_amdgcn_global_load_lds(
                (const __attribute__((address_space(1))) void*)(unsigned long long)(uintptr_t)gb,
                (__attribute__((address_space(3))) void*)(unsigned long long)(uintptr_t)(Bs + (wv*2 + i)*512),
                16, 0, 0);
        }
        __syncthreads();
        bf16x8 af[4], bfv[4];
        #pragma unroll
        for (int i = 0; i < 4; i++) {
            af[i]  = *(const bf16x8*)(As + (wm*64 + i*16 + lm)*32 + kgrp);
            bfv[i] = *(const bf16x8*)(Bs + (wn*64 + i*16 + lm)*32 + kgrp);
        }
        #pragma unroll
        for (int i = 0; i < 4; i++)
            #pragma unroll
            for (int j = 0; j < 4; j++)
                acc[i][j] = __builtin_amdgcn_mfma_f32_16x16x32_bf16(af[i], bfv[j], acc[i][j], 0, 0, 0);
    }
    int r0 = (l >> 4) * 4;
    #pragma unroll
    for (int j = 0; j < 4; j++) {
        int col = nbase + wn*64 + j*16 + lm;
        float bb = bias[col];
        float ss = 0.f, tt = 0.f;
        if (MODE == 0) { ss = sv[col]; tt = tv[col]; }
        #pragma unroll
        for (int i = 0; i < 4; i++) {
            int rowb = mbase + wm*64 + i*16 + r0;
            #pragma unroll
            for (int r = 0; r < 4; r++) {
                int row = rowb + r;
                if (row < M) {
                    float v = acc[i][j][r] + bb;
                    if (MODE == 0) {
                        v = gelu_f(v*ss + tt);
                        ((__hip_bfloat16*)out)[(size_t)row*N + col] = __float2bfloat16(v);
                    } else {
                        ((float*)out)[(size_t)row*N + col] = v + resid[(size_t)row*N + col];
                    }
                }
            }
        }
    }
}

extern "C" void kernel_launch(void* const* d_in, const int* in_sizes, int n_in,
                              void* d_out, int out_size, void* d_ws, size_t ws_size,
                              hipStream_t stream) {
    const float* x     = (const float*)d_in[0];
    const float* emb   = (const float*)d_in[1];
    const float* n1w   = (const float*)d_in[2];
    const float* n1b   = (const float*)d_in[3];
    const float* n2w   = (const float*)d_in[4];
    const float* n2b   = (const float*)d_in[5];
    const float* w1    = (const float*)d_in[6];
    const float* b1    = (const float*)d_in[7];
    const float* w2    = (const float*)d_in[8];
    const float* b2    = (const float*)d_in[9];
    const float* fs_w0 = (const float*)d_in[10];
    const float* fs_b0 = (const float*)d_in[11];
    const float* fs_w1 = (const float*)d_in[12];
    const float* fs_b1 = (const float*)d_in[13];
    const float* fc1w  = (const float*)d_in[14];
    const float* fc1b  = (const float*)d_in[15];
    const float* fc2w  = (const float*)d_in[16];
    const float* fc2b  = (const float*)d_in[17];
    const float* ms_w0 = (const float*)d_in[18];
    const float* ms_b0 = (const float*)d_in[19];
    const float* ms_w1 = (const float*)d_in[20];
    const float* ms_b1 = (const float*)d_in[21];
    float* out = (float*)d_out;
    (void)in_sizes; (void)n_in; (void)out_size; (void)ws_size;

    char* wsb = (char*)d_ws;
    size_t off = 0;
    auto alloc = [&](size_t nbytes) -> void* {
        void* p = wsb + off;
        off += (nbytes + 255) & ~(size_t)255;
        return p;
    };
    // total ws usage ~97 MB
    float* s_f  = (float*)alloc(768*4);
    float* t_f  = (float*)alloc(768*4);
    float* s_m  = (float*)alloc(3072*4);
    float* t_m  = (float*)alloc(3072*4);
    float* midf = (float*)alloc(1536*4);
    float* midm = (float*)alloc(6144*4);
    float* Yr   = (float*)alloc((size_t)NPOS*CHC*4);
    float* Yi   = (float*)alloc((size_t)NPOS*CHC*4);
    float* Zr   = (float*)alloc((size_t)NPOS*CHC*4);
    float* Zi   = (float*)alloc((size_t)NPOS*CHC*4);
    __hip_bfloat16* wT1  = (__hip_bfloat16*)alloc((size_t)CC*LAT*2);
    __hip_bfloat16* wT2  = (__hip_bfloat16*)alloc((size_t)CC*LAT*2);
    __hip_bfloat16* h2c  = (__hip_bfloat16*)alloc((size_t)MCH*CC*2);
    __hip_bfloat16* hmid = (__hip_bfloat16*)alloc((size_t)MCH*LAT*2);

    // 1. modulation scale/shift vectors (two-stage, parallel)
    mod_a_kernel<<<30, 256, 0, stream>>>(emb, fs_w0, fs_b0, ms_w0, ms_b0, midf, midm);
    mod_b_kernel<<<120, 512, 0, stream>>>(midf, midm, fs_w1, fs_b1, ms_w1, ms_b1,
                                          s_f, t_f, s_m, t_m);
    // 2. LN1 -> d_out (h_ln lives in d_out)
    ln_f32_kernel<<<NROW/4, 256, 0, stream>>>(x, n1w, n1b, out);
    // 3. weight convert+transpose (independent of filter path)
    transpose_bf16_kernel<<<(CC*LAT + 255)/256, 256, 0, stream>>>(fc1w, wT1, 768, 3072);
    transpose_bf16_kernel<<<(CC*LAT + 255)/256, 256, 0, stream>>>(fc2w, wT2, 3072, 768);

    // 4. filter path, 8 chunks of 96 channels (one block-diag block each)
    for (int ch = 0; ch < NCHUNK; ch++) {
        int cb0 = ch * CHC;
        wdft_kernel<<<dim3(3, 180), 256, 0, stream>>>(out, cb0, Yr, Yi);
        hfft_kernel<<<dim3(91, 3), 512, 0, stream>>>(Yr, Yi, Zr, Zi, -1.0f);
        bd_kernel<0><<<dim3(512, 1), 192, 0, stream>>>(Zr, Zi, w1, b1, s_f, t_f, ch, Yr, Yi);
        bd_kernel<1><<<dim3(512, 1), 192, 0, stream>>>(Yr, Yi, w2, b2, nullptr, nullptr, ch, Zr, Zi);
        hfft_kernel<<<dim3(91, 3), 512, 0, stream>>>(Zr, Zi, Yr, Yi, 1.0f);
        // in-place: out = idft + out(h_ln) + x  for this channel slice
        iwdft_kernel<<<dim3(6, 180), 512, 0, stream>>>(Yr, Yi, x, cb0, out);
    }

    // 5. MLP path, 8 chunks of 8100 rows (d_out holds h; update in place)
    for (int mc = 0; mc < NCHUNK; mc++) {
        size_t base = (size_t)mc * MCH;
        // LN2 of chunk -> h2c (bf16)
        ln_bf16_kernel<<<MCH/4, 256, 0, stream>>>(out + base*CC, n2w, n2b, h2c);
        // fc1 + modulation + gelu -> hmid (bf16)
        gemm_kernel<0><<<dim3(LAT/128, (MCH+127)/128), 256, 0, stream>>>(
            h2c, wT1, MCH, CC, LAT, fc1b, s_m, t_m, nullptr, hmid);
        // fc2 + bias + residual(h) -> out (in place, elementwise)
        gemm_kernel<1><<<dim3(CC/128, (MCH+127)/128), 256, 0, stream>>>(
            hmid, wT2, MCH, LAT, CC, fc2b, nullptr, nullptr, out + base*CC, out + base*CC);
    }
}

// Round 4
// 5443.049 us; speedup vs baseline: 1.1807x; 1.0927x over previous
//
#include <hip/hip_runtime.h>
#include <hip/hip_bf16.h>
#include <math.h>

// Problem constants
#define HH 180
#define WW 360
#define CC 768
#define FF 91          // kept W-frequencies (km = 91)
#define NPOS (HH*FF)   // 16380 frequency positions
#define NROW (HH*WW)   // 64800 spatial rows
#define LAT 3072
#define CHC 96         // channels per filter chunk (= one block-diag block)
#define NCHUNK 8
#define MCH 8100       // rows per MLP chunk (64800 = 8*8100)

typedef __attribute__((ext_vector_type(8))) short bf16x8;
typedef __attribute__((ext_vector_type(4))) float f32x4;
typedef __attribute__((ext_vector_type(4))) unsigned int u32x4;

__device__ __forceinline__ float gelu_f(float x) {
    return 0.5f * x * (1.0f + erff(x * 0.7071067811865476f));
}

// ---------------- modulation stage A: mid = gelu(e @ w0 + b0), both paths ----------------
__global__ __launch_bounds__(256) void mod_a_kernel(
        const float* __restrict__ e,
        const float* __restrict__ fs_w0, const float* __restrict__ fs_b0,
        const float* __restrict__ ms_w0, const float* __restrict__ ms_b0,
        float* __restrict__ mid_f, float* __restrict__ mid_m) {
    __shared__ float es[64];
    int t = threadIdx.x;
    if (t < 64) es[t] = e[t];
    __syncthreads();
    int j = blockIdx.x * 256 + t;
    if (j < 1536) {
        float a = fs_b0[j];
        #pragma unroll 8
        for (int k = 0; k < 64; k++) a += es[k] * fs_w0[k*1536 + j];
        mid_f[j] = gelu_f(a);
    } else {
        int jm = j - 1536;   // < 6144
        float a = ms_b0[jm];
        #pragma unroll 8
        for (int k = 0; k < 64; k++) a += es[k] * ms_w0[k*6144 + jm];
        mid_m[jm] = gelu_f(a);
    }
}

// ---------------- modulation stage B: o = mid @ w1 + b1 -> s,t ----------------
__global__ __launch_bounds__(512) void mod_b_kernel(
        const float* __restrict__ mid_f, const float* __restrict__ mid_m,
        const float* __restrict__ fs_w1, const float* __restrict__ fs_b1,
        const float* __restrict__ ms_w1, const float* __restrict__ ms_b1,
        float* __restrict__ s_f, float* __restrict__ t_f,
        float* __restrict__ s_m, float* __restrict__ t_m) {
    __shared__ float red[8*64];
    int t = threadIdx.x;
    int g = t >> 6;          // k-group 0..7
    int jl = t & 63;         // output lane
    int blk = blockIdx.x;
    if (blk < 24) {
        int jo = blk*64 + jl;
        const int N = 1536, NQ = 192;
        float a = 0.f;
        const float* w = fs_w1 + (size_t)(g*NQ)*N + jo;
        for (int j = 0; j < NQ; j++) a += mid_f[g*NQ + j] * w[(size_t)j*N];
        red[t] = a;
        __syncthreads();
        if (t < 64) {
            float s = fs_b1[jo];
            #pragma unroll
            for (int q = 0; q < 8; q++) s += red[q*64 + jl];
            if (jo < 768) s_f[jo] = 1.0f + s;
            else          t_f[jo - 768] = s;
        }
    } else {
        int jo = (blk - 24)*64 + jl;
        const int N = 6144, NQ = 768;
        float a = 0.f;
        const float* w = ms_w1 + (size_t)(g*NQ)*N + jo;
        for (int j = 0; j < NQ; j++) a += mid_m[g*NQ + j] * w[(size_t)j*N];
        red[t] = a;
        __syncthreads();
        if (t < 64) {
            float s = ms_b1[jo];
            #pragma unroll
            for (int q = 0; q < 8; q++) s += red[q*64 + jl];
            if (jo < 3072) s_m[jo] = 1.0f + s;
            else           t_m[jo - 3072] = s;
        }
    }
}

// ---------------- LayerNorm fp32 out (one wave per 768-row) ----------------
__global__ __launch_bounds__(256) void ln_f32_kernel(const float* __restrict__ in,
        const float* __restrict__ w, const float* __restrict__ b,
        float* __restrict__ out) {
    int row = blockIdx.x*4 + (threadIdx.x >> 6);
    int l = threadIdx.x & 63;
    const float* p = in + (size_t)row*CC;
    float v[12]; float s = 0.f, sq = 0.f;
    #pragma unroll
    for (int i = 0; i < 12; i++) { float tv = p[l + 64*i]; v[i] = tv; s += tv; sq += tv*tv; }
    #pragma unroll
    for (int m = 1; m < 64; m <<= 1) { s += __shfl_xor(s, m); sq += __shfl_xor(sq, m); }
    float mean = s * (1.0f/768.0f);
    float var  = sq * (1.0f/768.0f) - mean*mean;
    float rstd = rsqrtf(var + 1e-5f);
    float* o = out + (size_t)row*CC;
    #pragma unroll
    for (int i = 0; i < 12; i++) { int c = l + 64*i; o[c] = (v[i]-mean)*rstd*w[c] + b[c]; }
}

// ---------------- LayerNorm bf16 out ----------------
__global__ __launch_bounds__(256) void ln_bf16_kernel(const float* __restrict__ in,
        const float* __restrict__ w, const float* __restrict__ b,
        __hip_bfloat16* __restrict__ out) {
    int row = blockIdx.x*4 + (threadIdx.x >> 6);
    int l = threadIdx.x & 63;
    const float* p = in + (size_t)row*CC;
    float v[12]; float s = 0.f, sq = 0.f;
    #pragma unroll
    for (int i = 0; i < 12; i++) { float tv = p[l + 64*i]; v[i] = tv; s += tv; sq += tv*tv; }
    #pragma unroll
    for (int m = 1; m < 64; m <<= 1) { s += __shfl_xor(s, m); sq += __shfl_xor(sq, m); }
    float mean = s * (1.0f/768.0f);
    float var  = sq * (1.0f/768.0f) - mean*mean;
    float rstd = rsqrtf(var + 1e-5f);
    __hip_bfloat16* o = out + (size_t)row*CC;
    #pragma unroll
    for (int i = 0; i < 12; i++) { int c = l + 64*i; o[c] = __float2bfloat16((v[i]-mean)*rstd*w[c] + b[c]); }
}

// ---------------- forward rDFT along W (360 -> 91 complex freqs), one 96-ch chunk ----------------
// split: blockIdx.z in {0,1} covers f in [48z, 48z+48), q<6
__global__ __launch_bounds__(256) void wdft_kernel(const float* __restrict__ hln,
        int cb0, float* __restrict__ Yr, float* __restrict__ Yi) {
    int h = blockIdx.y;
    int cbase = blockIdx.x * 32;   // 0,32,64 within chunk
    int zz = blockIdx.z;           // 0,1
    __shared__ float Xs[360*32];
    int t = threadIdx.x;
    const float* src = hln + (size_t)h*WW*CC + cb0 + cbase;
    for (int e2 = t; e2 < 360*32; e2 += 256) {
        int w = e2 >> 5, c = e2 & 31;
        Xs[e2] = src[(size_t)w*CC + c];
    }
    __syncthreads();
    int c = t & 31, fg = t >> 5;   // fg 0..7 ; f = fg + 8q + 48zz, q<6 (guard <91)
    float ar[6], ai[6], rr[6], ri[6], stc[6], sts[6];
    #pragma unroll
    for (int q = 0; q < 6; q++) {
        int f = fg + 8*q + 48*zz;
        float ang = -6.283185307179586f * (float)f / 360.0f;
        float s_, c_; sincosf(ang, &s_, &c_);
        stc[q] = c_; sts[q] = s_;
        rr[q] = 1.0f; ri[q] = 0.0f; ar[q] = 0.0f; ai[q] = 0.0f;
    }
    for (int w = 0; w < 360; w++) {
        float xv = Xs[w*32 + c];
        #pragma unroll
        for (int q = 0; q < 6; q++) {
            ar[q] += xv * rr[q];
            ai[q] += xv * ri[q];
            float nr = rr[q]*stc[q] - ri[q]*sts[q];
            float ni = rr[q]*sts[q] + ri[q]*stc[q];
            rr[q] = nr; ri[q] = ni;
        }
    }
    const float rn = 0.05270462766947299f;  // 1/sqrt(360)
    #pragma unroll
    for (int q = 0; q < 6; q++) {
        int f = fg + 8*q + 48*zz;
        if (f < FF) {
            size_t idx = ((size_t)h*FF + f)*CHC + cbase + c;
            Yr[idx] = ar[q]*rn;
            Yi[idx] = ai[q]*rn;
        }
    }
}

// ---------------- complex FFT along H (180 -> 180), sign = -1 fwd / +1 inv, chunk ----------------
// split: blockIdx.z in {0..3} covers o in [48z, 48z+48), q<3
__global__ __launch_bounds__(512) void hfft_kernel(const float* __restrict__ Ir,
        const float* __restrict__ Ii, float* __restrict__ Or_, float* __restrict__ Oi_,
        float sign) {
    int f = blockIdx.x;
    int cbase = blockIdx.y * 32;   // 0,32,64
    int zz = blockIdx.z;           // 0..3
    __shared__ float Sr[180*32];
    __shared__ float Si[180*32];
    int t = threadIdx.x;
    for (int e2 = t; e2 < 180*32; e2 += 512) {
        int h = e2 >> 5, c = e2 & 31;
        size_t idx = ((size_t)h*FF + f)*CHC + cbase + c;
        Sr[e2] = Ir[idx];
        Si[e2] = Ii[idx];
    }
    __syncthreads();
    int c = t & 31, g = t >> 5;   // g 0..15 ; o = g + 16q + 48zz, q<3 (guard <180)
    float ar[3], ai[3], rr[3], ri[3], stc[3], sts[3];
    #pragma unroll
    for (int q = 0; q < 3; q++) {
        int o = g + 16*q + 48*zz;
        float ang = sign * 6.283185307179586f * (float)o / 180.0f;
        float s_, c_; sincosf(ang, &s_, &c_);
        stc[q] = c_; sts[q] = s_;
        rr[q] = 1.0f; ri[q] = 0.0f; ar[q] = 0.0f; ai[q] = 0.0f;
    }
    for (int i = 0; i < 180; i++) {
        float yr = Sr[i*32 + c], yi = Si[i*32 + c];
        #pragma unroll
        for (int q = 0; q < 3; q++) {
            ar[q] += yr*rr[q] - yi*ri[q];
            ai[q] += yr*ri[q] + yi*rr[q];
            float nr = rr[q]*stc[q] - ri[q]*sts[q];
            float ni = rr[q]*sts[q] + ri[q]*stc[q];
            rr[q] = nr; ri[q] = ni;
        }
    }
    const float rn = 0.07453559924999299f;  // 1/sqrt(180)
    #pragma unroll
    for (int q = 0; q < 3; q++) {
        int o = g + 16*q + 48*zz;
        if (o < 180) {
            size_t idx = ((size_t)o*FF + f)*CHC + cbase + c;
            Or_[idx] = ar[q]*rn;
            Oi_[idx] = ai[q]*rn;
        }
    }
}

// ---------------- per-frequency block-diagonal complex matmul (one block wb) ----------------
template<int LAYER>
__global__ __launch_bounds__(192) void bd_kernel(
        const float* __restrict__ Ir, const float* __restrict__ Ii,
        const float* __restrict__ wgt, const float* __restrict__ bias,
        const float* __restrict__ sf, const float* __restrict__ tf,
        int wb,
        float* __restrict__ Or_, float* __restrict__ Oi_) {
    int tile = blockIdx.x;   // 32 positions per tile
    int p0 = tile * 32;
    __shared__ float2 Ls[32*96];
    int t = threadIdx.x;
    for (int e2 = t; e2 < 32*96; e2 += 192) {
        int pp = e2 / 96, cc = e2 - pp*96;
        int p = p0 + pp; if (p >= NPOS) p = NPOS - 1;
        size_t idx = (size_t)p*CHC + cc;
        Ls[e2] = make_float2(Ir[idx], Ii[idx]);
    }
    __syncthreads();
    int oc = (t >= 96) ? (t - 96) : t;
    int pg = (t >= 96) ? 1 : 0;
    const float* Wr = wgt + (size_t)wb * 9216;          // w[0][wb][k][oc]
    const float* Wi = wgt + (size_t)(8 + wb) * 9216;    // w[1][wb][k][oc]
    float br = bias[wb*96 + oc];
    float bi = bias[768 + wb*96 + oc];
    float ar[16], ai[16];
    #pragma unroll
    for (int i = 0; i < 16; i++) { ar[i] = br; ai[i] = bi; }
    for (int k = 0; k < 96; k++) {
        float wr = Wr[k*96 + oc];
        float wi = Wi[k*96 + oc];
        #pragma unroll
        for (int i = 0; i < 16; i++) {
            float2 y = Ls[(pg + 2*i)*96 + k];
            ar[i] += y.x*wr - y.y*wi;
            ai[i] += y.x*wi + y.y*wr;
        }
    }
    if (LAYER == 0) {
        float s  = sf[wb*96 + oc];
        float tt = tf[wb*96 + oc];
        #pragma unroll
        for (int i = 0; i < 16; i++) {
            int p = p0 + pg + 2*i;
            if (p < NPOS) {
                size_t idx = (size_t)p*CHC + oc;
                Or_[idx] = fmaxf(ar[i]*s + tt, 0.0f);
                Oi_[idx] = fmaxf(ai[i]*s + tt, 0.0f);
            }
        }
    } else {
        #pragma unroll
        for (int i = 0; i < 16; i++) {
            int p = p0 + pg + 2*i;
            if (p < NPOS) {
                float vr = ar[i], vi = ai[i];
                vr = (vr > 0.01f) ? (vr - 0.01f) : ((vr < -0.01f) ? (vr + 0.01f) : 0.0f);
                vi = (vi > 0.01f) ? (vi - 0.01f) : ((vi < -0.01f) ? (vi + 0.01f) : 0.0f);
                size_t idx = (size_t)p*CHC + oc;
                Or_[idx] = vr;
                Oi_[idx] = vi;
            }
        }
    }
}

// ---------------- inverse rDFT along W + bias(hln in hout) + residual(x), in place ----------------
// split: blockIdx.z in {0,1} covers w in [192z, 192z+192), q<6
__global__ __launch_bounds__(512) void iwdft_kernel(const float* __restrict__ Zr,
        const float* __restrict__ Zi, const float* __restrict__ xin,
        int cb0, float* __restrict__ hout) {
    int h = blockIdx.y;
    int cbase = blockIdx.x * 16;   // 0..80 within chunk
    int zz = blockIdx.z;           // 0,1
    __shared__ float Sr[91*16];
    __shared__ float Si[91*16];
    int t = threadIdx.x;
    for (int e2 = t; e2 < 91*16; e2 += 512) {
        int f = e2 >> 4, c = e2 & 15;
        size_t idx = ((size_t)h*FF + f)*CHC + cbase + c;
        Sr[e2] = Zr[idx];
        Si[e2] = Zi[idx];
    }
    __syncthreads();
    int c = t & 15, g = t >> 4;   // g 0..31 ; w = g + 32q + 192zz, q<6 (guard <360)
    float acc[6], rr[6], ri[6], stc[6], sts[6];
    #pragma unroll
    for (int q = 0; q < 6; q++) {
        int w = g + 32*q + 192*zz;
        float ang = 6.283185307179586f * (float)w / 360.0f;
        float s_, c_; sincosf(ang, &s_, &c_);
        stc[q] = c_; sts[q] = s_;
        rr[q] = 1.0f; ri[q] = 0.0f; acc[q] = 0.0f;
    }
    for (int f = 0; f < 91; f++) {
        float zr = Sr[f*16 + c], zi = Si[f*16 + c];
        float m = (f == 0) ? 1.0f : 2.0f;
        zr *= m; zi *= m;
        #pragma unroll
        for (int q = 0; q < 6; q++) {
            acc[q] += zr*rr[q] - zi*ri[q];
            float nr = rr[q]*stc[q] - ri[q]*sts[q];
            float ni = rr[q]*sts[q] + ri[q]*stc[q];
            rr[q] = nr; ri[q] = ni;
        }
    }
    const float rn = 0.05270462766947299f;  // 1/sqrt(360)
    #pragma unroll
    for (int q = 0; q < 6; q++) {
        int w = g + 32*q + 192*zz;
        if (w < 360) {
            size_t o = ((size_t)h*WW + w)*CC + cb0 + cbase + c;
            hout[o] = acc[q]*rn + hout[o] + xin[o];
        }
    }
}

// ---------------- tiled weight transpose + bf16 convert: dst[n*K+k] = bf16(src[k*N+n]) ----------------
// K, N multiples of 32
__global__ __launch_bounds__(256) void transpose_bf16_kernel(const float* __restrict__ src,
        __hip_bfloat16* __restrict__ dst, int K, int N) {
    __shared__ float tile[32][33];
    int n0 = blockIdx.x * 32;
    int k0 = blockIdx.y * 32;
    int tx = threadIdx.x & 31;
    int ty = threadIdx.x >> 5;   // 0..7
    #pragma unroll
    for (int r = 0; r < 32; r += 8) {
        tile[ty + r][tx] = src[(size_t)(k0 + ty + r) * N + n0 + tx];
    }
    __syncthreads();
    #pragma unroll
    for (int r = 0; r < 32; r += 8) {
        dst[(size_t)(n0 + ty + r) * K + k0 + tx] = __float2bfloat16(tile[tx][ty + r]);
    }
}

// ---------------- bf16 MFMA GEMM, 128x128 tile, BK=32, 4 waves, global_load_lds staging ----------------
// MODE 0: hmid = bf16(gelu((A@B + bias)*s + t))   MODE 1: out = A@B + bias + resid (fp32)
template<int MODE>
__global__ __launch_bounds__(256) void gemm_kernel(
        const __hip_bfloat16* __restrict__ A,   // [M][K] bf16
        const __hip_bfloat16* __restrict__ Bt,  // [N][K] bf16 (pre-transposed)
        int M, int K, int N,
        const float* __restrict__ bias,
        const float* __restrict__ sv, const float* __restrict__ tv,
        const float* resid, void* out) {
    __shared__ unsigned short As[128*32];
    __shared__ unsigned short Bs[128*32];
    int tid = threadIdx.x;
    int nbase = blockIdx.x * 128;
    int mbase = blockIdx.y * 128;
    int l = tid & 63, wv = tid >> 6;
    int wm = wv & 1, wn = wv >> 1;
    int lm = l & 15;
    int kgrp = (l >> 4) * 8;
    f32x4 acc[4][4] = {};
    int nkt = K >> 5;
    for (int kt = 0; kt < nkt; kt++) {
        int kb = kt * 32;
        __syncthreads();
        // async global->LDS staging, 16B per lane per instruction
        #pragma unroll
        for (int i = 0; i < 2; i++) {
            int ch = (wv*2 + i)*64 + l;    // 0..511 ; LDS chunk = ch*16B, HW: base + lane*16
            int row = ch >> 2;
            int ko = (ch & 3) * 8;
            int am = mbase + row; if (am >= M) am = M - 1;
            const __hip_bfloat16* ga = A  + (size_t)am * K + kb + ko;
            const __hip_bfloat16* gb = Bt + (size_t)(nbase + row) * K + kb + ko;
            __builtin_amdgcn_global_load_lds(
                (const __attribute__((address_space(1))) void*)(unsigned long long)(uintptr_t)ga,
                (__attribute__((address_space(3))) void*)(unsigned long long)(uintptr_t)(As + (wv*2 + i)*512),
                16, 0, 0);
            __builtin_amdgcn_global_load_lds(
                (const __attribute__((address_space(1))) void*)(unsigned long long)(uintptr_t)gb,
                (__attribute__((address_space(3))) void*)(unsigned long long)(uintptr_t)(Bs + (wv*2 + i)*512),
                16, 0, 0);
        }
        __syncthreads();
        bf16x8 af[4], bfv[4];
        #pragma unroll
        for (int i = 0; i < 4; i++) {
            af[i]  = *(const bf16x8*)(As + (wm*64 + i*16 + lm)*32 + kgrp);
            bfv[i] = *(const bf16x8*)(Bs + (wn*64 + i*16 + lm)*32 + kgrp);
        }
        #pragma unroll
        for (int i = 0; i < 4; i++)
            #pragma unroll
            for (int j = 0; j < 4; j++)
                acc[i][j] = __builtin_amdgcn_mfma_f32_16x16x32_bf16(af[i], bfv[j], acc[i][j], 0, 0, 0);
    }
    int r0 = (l >> 4) * 4;
    #pragma unroll
    for (int j = 0; j < 4; j++) {
        int col = nbase + wn*64 + j*16 + lm;
        float bb = bias[col];
        float ss = 0.f, tt = 0.f;
        if (MODE == 0) { ss = sv[col]; tt = tv[col]; }
        #pragma unroll
        for (int i = 0; i < 4; i++) {
            int rowb = mbase + wm*64 + i*16 + r0;
            #pragma unroll
            for (int r = 0; r < 4; r++) {
                int row = rowb + r;
                if (row < M) {
                    float v = acc[i][j][r] + bb;
                    if (MODE == 0) {
                        v = gelu_f(v*ss + tt);
                        ((__hip_bfloat16*)out)[(size_t)row*N + col] = __float2bfloat16(v);
                    } else {
                        ((float*)out)[(size_t)row*N + col] = v + resid[(size_t)row*N + col];
                    }
                }
            }
        }
    }
}

extern "C" void kernel_launch(void* const* d_in, const int* in_sizes, int n_in,
                              void* d_out, int out_size, void* d_ws, size_t ws_size,
                              hipStream_t stream) {
    const float* x     = (const float*)d_in[0];
    const float* emb   = (const float*)d_in[1];
    const float* n1w   = (const float*)d_in[2];
    const float* n1b   = (const float*)d_in[3];
    const float* n2w   = (const float*)d_in[4];
    const float* n2b   = (const float*)d_in[5];
    const float* w1    = (const float*)d_in[6];
    const float* b1    = (const float*)d_in[7];
    const float* w2    = (const float*)d_in[8];
    const float* b2    = (const float*)d_in[9];
    const float* fs_w0 = (const float*)d_in[10];
    const float* fs_b0 = (const float*)d_in[11];
    const float* fs_w1 = (const float*)d_in[12];
    const float* fs_b1 = (const float*)d_in[13];
    const float* fc1w  = (const float*)d_in[14];
    const float* fc1b  = (const float*)d_in[15];
    const float* fc2w  = (const float*)d_in[16];
    const float* fc2b  = (const float*)d_in[17];
    const float* ms_w0 = (const float*)d_in[18];
    const float* ms_b0 = (const float*)d_in[19];
    const float* ms_w1 = (const float*)d_in[20];
    const float* ms_b1 = (const float*)d_in[21];
    float* out = (float*)d_out;
    (void)in_sizes; (void)n_in; (void)out_size; (void)ws_size;

    char* wsb = (char*)d_ws;
    size_t off = 0;
    auto alloc = [&](size_t nbytes) -> void* {
        void* p = wsb + off;
        off += (nbytes + 255) & ~(size_t)255;
        return p;
    };
    // total ws usage ~97 MB
    float* s_f  = (float*)alloc(768*4);
    float* t_f  = (float*)alloc(768*4);
    float* s_m  = (float*)alloc(3072*4);
    float* t_m  = (float*)alloc(3072*4);
    float* midf = (float*)alloc(1536*4);
    float* midm = (float*)alloc(6144*4);
    float* Yr   = (float*)alloc((size_t)NPOS*CHC*4);
    float* Yi   = (float*)alloc((size_t)NPOS*CHC*4);
    float* Zr   = (float*)alloc((size_t)NPOS*CHC*4);
    float* Zi   = (float*)alloc((size_t)NPOS*CHC*4);
    __hip_bfloat16* wT1  = (__hip_bfloat16*)alloc((size_t)CC*LAT*2);
    __hip_bfloat16* wT2  = (__hip_bfloat16*)alloc((size_t)CC*LAT*2);
    __hip_bfloat16* h2c  = (__hip_bfloat16*)alloc((size_t)MCH*CC*2);
    __hip_bfloat16* hmid = (__hip_bfloat16*)alloc((size_t)MCH*LAT*2);

    // 1. modulation scale/shift vectors (two-stage, parallel)
    mod_a_kernel<<<30, 256, 0, stream>>>(emb, fs_w0, fs_b0, ms_w0, ms_b0, midf, midm);
    mod_b_kernel<<<120, 512, 0, stream>>>(midf, midm, fs_w1, fs_b1, ms_w1, ms_b1,
                                          s_f, t_f, s_m, t_m);
    // 2. LN1 -> d_out (h_ln lives in d_out)
    ln_f32_kernel<<<NROW/4, 256, 0, stream>>>(x, n1w, n1b, out);
    // 3. weight convert+transpose (tiled; independent of filter path)
    transpose_bf16_kernel<<<dim3(LAT/32, CC/32), 256, 0, stream>>>(fc1w, wT1, 768, 3072);
    transpose_bf16_kernel<<<dim3(CC/32, LAT/32), 256, 0, stream>>>(fc2w, wT2, 3072, 768);

    // 4. filter path, 8 chunks of 96 channels (one block-diag block each)
    for (int ch = 0; ch < NCHUNK; ch++) {
        int cb0 = ch * CHC;
        wdft_kernel<<<dim3(3, 180, 2), 256, 0, stream>>>(out, cb0, Yr, Yi);
        hfft_kernel<<<dim3(91, 3, 4), 512, 0, stream>>>(Yr, Yi, Zr, Zi, -1.0f);
        bd_kernel<0><<<dim3(512, 1), 192, 0, stream>>>(Zr, Zi, w1, b1, s_f, t_f, ch, Yr, Yi);
        bd_kernel<1><<<dim3(512, 1), 192, 0, stream>>>(Yr, Yi, w2, b2, nullptr, nullptr, ch, Zr, Zi);
        hfft_kernel<<<dim3(91, 3, 4), 512, 0, stream>>>(Zr, Zi, Yr, Yi, 1.0f);
        // in-place: out = idft + out(h_ln) + x  for this channel slice
        iwdft_kernel<<<dim3(6, 180, 2), 512, 0, stream>>>(Yr, Yi, x, cb0, out);
    }

    // 5. MLP path, 8 chunks of 8100 rows (d_out holds h; update in place)
    for (int mc = 0; mc < NCHUNK; mc++) {
        size_t base = (size_t)mc * MCH;
        // LN2 of chunk -> h2c (bf16)
        ln_bf16_kernel<<<MCH/4, 256, 0, stream>>>(out + base*CC, n2w, n2b, h2c);
        // fc1 + modulation + gelu -> hmid (bf16)
        gemm_kernel<0><<<dim3(LAT/128, (MCH+127)/128), 256, 0, stream>>>(
            h2c, wT1, MCH, CC, LAT, fc1b, s_m, t_m, nullptr, hmid);
        // fc2 + bias + residual(h) -> out (in place, elementwise)
        gemm_kernel<1><<<dim3(CC/128, (MCH+127)/128), 256, 0, stream>>>(
            hmid, wT2, MCH, LAT, CC, fc2b, nullptr, nullptr, out + base*CC, out + base*CC);
    }
}

// Round 5
// 5335.765 us; speedup vs baseline: 1.2044x; 1.0201x over previous
//
#include <hip/hip_runtime.h>
#include <hip/hip_bf16.h>
#include <math.h>

// Problem constants
#define HH 180
#define WW 360
#define CC 768
#define FF 91          // kept W-frequencies (km = 91)
#define NPOS (HH*FF)   // 16380 frequency positions
#define NROW (HH*WW)   // 64800 spatial rows
#define LAT 3072
#define CHC 96         // channels per filter chunk (= one block-diag block)
#define NCHUNK 8

typedef __attribute__((ext_vector_type(8))) short bf16x8;
typedef __attribute__((ext_vector_type(4))) float f32x4;
typedef __attribute__((ext_vector_type(4))) unsigned int u32x4;

__device__ __forceinline__ float gelu_f(float x) {
    return 0.5f * x * (1.0f + erff(x * 0.7071067811865476f));
}

// ---------------- modulation stage A ----------------
__global__ __launch_bounds__(256) void mod_a_kernel(
        const float* __restrict__ e,
        const float* __restrict__ fs_w0, const float* __restrict__ fs_b0,
        const float* __restrict__ ms_w0, const float* __restrict__ ms_b0,
        float* __restrict__ mid_f, float* __restrict__ mid_m) {
    __shared__ float es[64];
    int t = threadIdx.x;
    if (t < 64) es[t] = e[t];
    __syncthreads();
    int j = blockIdx.x * 256 + t;
    if (j < 1536) {
        float a = fs_b0[j];
        #pragma unroll 8
        for (int k = 0; k < 64; k++) a += es[k] * fs_w0[k*1536 + j];
        mid_f[j] = gelu_f(a);
    } else {
        int jm = j - 1536;
        float a = ms_b0[jm];
        #pragma unroll 8
        for (int k = 0; k < 64; k++) a += es[k] * ms_w0[k*6144 + jm];
        mid_m[jm] = gelu_f(a);
    }
}

// ---------------- modulation stage B ----------------
__global__ __launch_bounds__(512) void mod_b_kernel(
        const float* __restrict__ mid_f, const float* __restrict__ mid_m,
        const float* __restrict__ fs_w1, const float* __restrict__ fs_b1,
        const float* __restrict__ ms_w1, const float* __restrict__ ms_b1,
        float* __restrict__ s_f, float* __restrict__ t_f,
        float* __restrict__ s_m, float* __restrict__ t_m) {
    __shared__ float red[8*64];
    int t = threadIdx.x;
    int g = t >> 6;
    int jl = t & 63;
    int blk = blockIdx.x;
    if (blk < 24) {
        int jo = blk*64 + jl;
        const int N = 1536, NQ = 192;
        float a = 0.f;
        const float* w = fs_w1 + (size_t)(g*NQ)*N + jo;
        for (int j = 0; j < NQ; j++) a += mid_f[g*NQ + j] * w[(size_t)j*N];
        red[t] = a;
        __syncthreads();
        if (t < 64) {
            float s = fs_b1[jo];
            #pragma unroll
            for (int q = 0; q < 8; q++) s += red[q*64 + jl];
            if (jo < 768) s_f[jo] = 1.0f + s;
            else          t_f[jo - 768] = s;
        }
    } else {
        int jo = (blk - 24)*64 + jl;
        const int N = 6144, NQ = 768;
        float a = 0.f;
        const float* w = ms_w1 + (size_t)(g*NQ)*N + jo;
        for (int j = 0; j < NQ; j++) a += mid_m[g*NQ + j] * w[(size_t)j*N];
        red[t] = a;
        __syncthreads();
        if (t < 64) {
            float s = ms_b1[jo];
            #pragma unroll
            for (int q = 0; q < 8; q++) s += red[q*64 + jl];
            if (jo < 3072) s_m[jo] = 1.0f + s;
            else           t_m[jo - 3072] = s;
        }
    }
}

// ---------------- LayerNorm fp32 out ----------------
__global__ __launch_bounds__(256) void ln_f32_kernel(const float* __restrict__ in,
        const float* __restrict__ w, const float* __restrict__ b,
        float* __restrict__ out) {
    int row = blockIdx.x*4 + (threadIdx.x >> 6);
    int l = threadIdx.x & 63;
    const float* p = in + (size_t)row*CC;
    float v[12]; float s = 0.f, sq = 0.f;
    #pragma unroll
    for (int i = 0; i < 12; i++) { float tv = p[l + 64*i]; v[i] = tv; s += tv; sq += tv*tv; }
    #pragma unroll
    for (int m = 1; m < 64; m <<= 1) { s += __shfl_xor(s, m); sq += __shfl_xor(sq, m); }
    float mean = s * (1.0f/768.0f);
    float var  = sq * (1.0f/768.0f) - mean*mean;
    float rstd = rsqrtf(var + 1e-5f);
    float* o = out + (size_t)row*CC;
    #pragma unroll
    for (int i = 0; i < 12; i++) { int c = l + 64*i; o[c] = (v[i]-mean)*rstd*w[c] + b[c]; }
}

// ---------------- LayerNorm bf16 out ----------------
__global__ __launch_bounds__(256) void ln_bf16_kernel(const float* __restrict__ in,
        const float* __restrict__ w, const float* __restrict__ b,
        __hip_bfloat16* __restrict__ out) {
    int row = blockIdx.x*4 + (threadIdx.x >> 6);
    int l = threadIdx.x & 63;
    const float* p = in + (size_t)row*CC;
    float v[12]; float s = 0.f, sq = 0.f;
    #pragma unroll
    for (int i = 0; i < 12; i++) { float tv = p[l + 64*i]; v[i] = tv; s += tv; sq += tv*tv; }
    #pragma unroll
    for (int m = 1; m < 64; m <<= 1) { s += __shfl_xor(s, m); sq += __shfl_xor(sq, m); }
    float mean = s * (1.0f/768.0f);
    float var  = sq * (1.0f/768.0f) - mean*mean;
    float rstd = rsqrtf(var + 1e-5f);
    __hip_bfloat16* o = out + (size_t)row*CC;
    #pragma unroll
    for (int i = 0; i < 12; i++) { int c = l + 64*i; o[c] = __float2bfloat16((v[i]-mean)*rstd*w[c] + b[c]); }
}

// ---------------- forward rDFT along W, radix-4 folded ----------------
// Y[f] = sum_{v<90} e^{-i th f v} * u_{f%4}[v],  u_k[v] = sum_j (-i)^{kj} x[v+90j]
// u0=(x0+x1+x2+x3,0) u2=(x0-x1+x2-x3,0) u1=(A,-B) u3=(A,B), A=x0-x2, B=x1-x3
// 256 thr = 32 fl x 8 cl ; f = fl+32q (q<3, guard<91) ; c = cy*16 + cl + 8*j2 (j2<2)
__global__ __launch_bounds__(256) void wdft_kernel(const float* __restrict__ hln,
        int cb0, float* __restrict__ Yr, float* __restrict__ Yi) {
    int h = blockIdx.y;
    int cy = blockIdx.x;            // 0..5 (cspan 16)
    __shared__ float2 P[4*90*16];   // plane k at k*1440
    int t = threadIdx.x;
    const float rn = 0.05270462766947299f;  // 1/sqrt(360)
    for (int e2 = t; e2 < 90*16; e2 += 256) {
        int v = e2 >> 4, cc = e2 & 15;
        size_t base = ((size_t)h*WW + v)*CC + cb0 + cy*16 + cc;
        float x0 = hln[base];
        float x1 = hln[base + 90*CC];
        float x2 = hln[base + 180*CC];
        float x3 = hln[base + 270*CC];
        float u0 = (x0+x1+x2+x3)*rn;
        float u2 = (x0-x1+x2-x3)*rn;
        float A  = (x0-x2)*rn;
        float B  = (x1-x3)*rn;
        P[0*1440 + e2] = make_float2(u0, 0.f);
        P[1*1440 + e2] = make_float2(A, -B);
        P[2*1440 + e2] = make_float2(u2, 0.f);
        P[3*1440 + e2] = make_float2(A,  B);
    }
    __syncthreads();
    int fl = t & 31, cl = t >> 5;   // fl<32, cl<8
    int pbase = (fl & 3) * 1440;
    const float TH = 6.283185307179586f / 360.0f;
    float Tc[3], Ts[3], sc[3], ss[3];
    float Y[3][2][2];
    #pragma unroll
    for (int q = 0; q < 3; q++) {
        int f = fl + 32*q;
        float s_, c_; sincosf(TH * (float)f, &s_, &c_);
        sc[q] = c_; ss[q] = s_;
        Tc[q] = 1.f; Ts[q] = 0.f;
        Y[q][0][0]=Y[q][0][1]=Y[q][1][0]=Y[q][1][1]=0.f;
    }
    for (int v = 0; v < 90; v++) {
        float2 u0v = P[pbase + v*16 + cl];
        float2 u1v = P[pbase + v*16 + cl + 8];
        #pragma unroll
        for (int q = 0; q < 3; q++) {
            // twiddle e^{-i th f v}: re += ur*cos + ui*sin ; im += ui*cos - ur*sin
            Y[q][0][0] += u0v.x*Tc[q] + u0v.y*Ts[q];
            Y[q][0][1] += u0v.y*Tc[q] - u0v.x*Ts[q];
            Y[q][1][0] += u1v.x*Tc[q] + u1v.y*Ts[q];
            Y[q][1][1] += u1v.y*Tc[q] - u1v.x*Ts[q];
            float nc = Tc[q]*sc[q] - Ts[q]*ss[q];
            float ns = Tc[q]*ss[q] + Ts[q]*sc[q];
            Tc[q] = nc; Ts[q] = ns;
        }
    }
    #pragma unroll
    for (int q = 0; q < 3; q++) {
        int f = fl + 32*q;
        if (f < FF) {
            #pragma unroll
            for (int j2 = 0; j2 < 2; j2++) {
                size_t idx = ((size_t)h*FF + f)*CHC + cy*16 + cl + 8*j2;
                Yr[idx] = Y[q][j2][0];
                Yi[idx] = Y[q][j2][1];
            }
        }
    }
}

// ---------------- complex FFT along H (180), radix-4 folded, sign=-1 fwd / +1 inv ----------------
// O[t] = sum_{v<45} e^{s i ph t v} u_{t%4}[v], u_k[v] = sum_j (s i)^{kj} Z[v+45j]
// 128 thr = 32 tl x 4 cl ; t = tl+32q (q<6, guard<180) ; c = cy*12 + cl + 4*j2 (j2<3)
__global__ __launch_bounds__(128) void hfft_kernel(const float* __restrict__ Ir,
        const float* __restrict__ Ii, float* __restrict__ Or_, float* __restrict__ Oi_,
        float sign) {
    int f = blockIdx.x;
    int cy = blockIdx.y;            // 0..7 (cspan 12)
    __shared__ float2 P[4*45*12];   // plane k at k*540
    int t = threadIdx.x;
    const float rn = 0.07453559924999299f;  // 1/sqrt(180)
    for (int e2 = t; e2 < 45*12; e2 += 128) {
        int v = e2 / 12, cc = e2 - v*12;
        size_t i0 = ((size_t)(v      )*FF + f)*CHC + cy*12 + cc;
        size_t i1 = ((size_t)(v + 45 )*FF + f)*CHC + cy*12 + cc;
        size_t i2 = ((size_t)(v + 90 )*FF + f)*CHC + cy*12 + cc;
        size_t i3 = ((size_t)(v + 135)*FF + f)*CHC + cy*12 + cc;
        float z0r = Ir[i0]*rn, z0i = Ii[i0]*rn;
        float z1r = Ir[i1]*rn, z1i = Ii[i1]*rn;
        float z2r = Ir[i2]*rn, z2i = Ii[i2]*rn;
        float z3r = Ir[i3]*rn, z3i = Ii[i3]*rn;
        float d02r = z0r - z2r, d02i = z0i - z2i;
        float d13r = z1r - z3r, d13i = z1i - z3i;
        P[0*540 + e2] = make_float2(z0r+z1r+z2r+z3r, z0i+z1i+z2i+z3i);
        P[2*540 + e2] = make_float2(z0r-z1r+z2r-z3r, z0i-z1i+z2i-z3i);
        // u1 = d02 + s*i*d13 ; u3 = d02 - s*i*d13
        P[1*540 + e2] = make_float2(d02r - sign*d13i, d02i + sign*d13r);
        P[3*540 + e2] = make_float2(d02r + sign*d13i, d02i - sign*d13r);
    }
    __syncthreads();
    int tl = t & 31, cl = t >> 5;   // tl<32, cl<4
    int pbase = (tl & 3) * 540;
    const float PH = 6.283185307179586f / 180.0f;
    float Tc[6], Ts[6], sc[6], ss[6];
    float O[6][3][2];
    #pragma unroll
    for (int q = 0; q < 6; q++) {
        int tq = tl + 32*q;
        float s_, c_; sincosf(sign * PH * (float)tq, &s_, &c_);
        sc[q] = c_; ss[q] = s_;
        Tc[q] = 1.f; Ts[q] = 0.f;
        #pragma unroll
        for (int j2 = 0; j2 < 3; j2++) { O[q][j2][0] = 0.f; O[q][j2][1] = 0.f; }
    }
    for (int v = 0; v < 45; v++) {
        float2 u[3];
        #pragma unroll
        for (int j2 = 0; j2 < 3; j2++) u[j2] = P[pbase + v*12 + cl + 4*j2];
        #pragma unroll
        for (int q = 0; q < 6; q++) {
            #pragma unroll
            for (int j2 = 0; j2 < 3; j2++) {
                // O += (Tc + i Ts)*(ur + i ui)
                O[q][j2][0] += u[j2].x*Tc[q] - u[j2].y*Ts[q];
                O[q][j2][1] += u[j2].x*Ts[q] + u[j2].y*Tc[q];
            }
            float nc = Tc[q]*sc[q] - Ts[q]*ss[q];
            float ns = Tc[q]*ss[q] + Ts[q]*sc[q];
            Tc[q] = nc; Ts[q] = ns;
        }
    }
    #pragma unroll
    for (int q = 0; q < 6; q++) {
        int tq = tl + 32*q;
        if (tq < HH) {
            #pragma unroll
            for (int j2 = 0; j2 < 3; j2++) {
                size_t idx = ((size_t)tq*FF + f)*CHC + cy*12 + cl + 4*j2;
                Or_[idx] = O[q][j2][0];
                Oi_[idx] = O[q][j2][1];
            }
        }
    }
}

// ---------------- per-frequency block-diagonal complex matmul ----------------
template<int LAYER>
__global__ __launch_bounds__(192) void bd_kernel(
        const float* __restrict__ Ir, const float* __restrict__ Ii,
        const float* __restrict__ wgt, const float* __restrict__ bias,
        const float* __restrict__ sf, const float* __restrict__ tf,
        int wb,
        float* __restrict__ Or_, float* __restrict__ Oi_) {
    int tile = blockIdx.x;
    int p0 = tile * 32;
    __shared__ float2 Ls[32*96];
    int t = threadIdx.x;
    for (int e2 = t; e2 < 32*96; e2 += 192) {
        int pp = e2 / 96, cc = e2 - pp*96;
        int p = p0 + pp; if (p >= NPOS) p = NPOS - 1;
        size_t idx = (size_t)p*CHC + cc;
        Ls[e2] = make_float2(Ir[idx], Ii[idx]);
    }
    __syncthreads();
    int oc = (t >= 96) ? (t - 96) : t;
    int pg = (t >= 96) ? 1 : 0;
    const float* Wr = wgt + (size_t)wb * 9216;
    const float* Wi = wgt + (size_t)(8 + wb) * 9216;
    float br = bias[wb*96 + oc];
    float bi = bias[768 + wb*96 + oc];
    float ar[16], ai[16];
    #pragma unroll
    for (int i = 0; i < 16; i++) { ar[i] = br; ai[i] = bi; }
    for (int k = 0; k < 96; k++) {
        float wr = Wr[k*96 + oc];
        float wi = Wi[k*96 + oc];
        #pragma unroll
        for (int i = 0; i < 16; i++) {
            float2 y = Ls[(pg + 2*i)*96 + k];
            ar[i] += y.x*wr - y.y*wi;
            ai[i] += y.x*wi + y.y*wr;
        }
    }
    if (LAYER == 0) {
        float s  = sf[wb*96 + oc];
        float tt = tf[wb*96 + oc];
        #pragma unroll
        for (int i = 0; i < 16; i++) {
            int p = p0 + pg + 2*i;
            if (p < NPOS) {
                size_t idx = (size_t)p*CHC + oc;
                Or_[idx] = fmaxf(ar[i]*s + tt, 0.0f);
                Oi_[idx] = fmaxf(ai[i]*s + tt, 0.0f);
            }
        }
    } else {
        #pragma unroll
        for (int i = 0; i < 16; i++) {
            int p = p0 + pg + 2*i;
            if (p < NPOS) {
                float vr = ar[i], vi = ai[i];
                vr = (vr > 0.01f) ? (vr - 0.01f) : ((vr < -0.01f) ? (vr + 0.01f) : 0.0f);
                vi = (vi > 0.01f) ? (vi - 0.01f) : ((vi < -0.01f) ? (vi + 0.01f) : 0.0f);
                size_t idx = (size_t)p*CHC + oc;
                Or_[idx] = vr;
                Oi_[idx] = vi;
            }
        }
    }
}

// ---------------- inverse rDFT along W, quarter-output symmetry, in place ----------------
// C'_k = sum_n m*Z[4n+k]*rho^n (one shared rotation rho = e^{i*4*th*w});
// C_k = e^{i th k w} C'_k ; out(w+90j) = sum_k Re(i^{kj} C_k)
// 256 thr = 16 cl x 16 wl ; wp = bx*16+wl (guard<90) ; c = cy*48 + cl + 16*j2 (j2<3)
__global__ __launch_bounds__(256) void iwdft_kernel(const float* __restrict__ Zr,
        const float* __restrict__ Zi, const float* __restrict__ xin,
        int cb0, float* __restrict__ hout) {
    int h = blockIdx.z;
    int cy = blockIdx.y;            // 0,1
    __shared__ float2 Sz[92*48];    // f-major, pre-scaled by rn*m_f, row 91 = 0
    int t = threadIdx.x;
    const float rn = 0.05270462766947299f;  // 1/sqrt(360)
    for (int e2 = t; e2 < 92*48; e2 += 256) {
        int f = e2 / 48, c = e2 - f*48;
        if (f < FF) {
            size_t idx = ((size_t)h*FF + f)*CHC + cy*48 + c;
            float m = (f == 0) ? rn : 2.0f*rn;
            Sz[e2] = make_float2(m*Zr[idx], m*Zi[idx]);
        } else {
            Sz[e2] = make_float2(0.f, 0.f);
        }
    }
    __syncthreads();
    int cl = t & 15, wl = t >> 4;
    int wp = blockIdx.x*16 + wl;    // guard < 90 at store
    const float TH = 6.283185307179586f / 360.0f;
    float s4, c4; sincosf(4.0f*TH*(float)wp, &s4, &c4);
    float C[4][3][2];
    #pragma unroll
    for (int k = 0; k < 4; k++)
        #pragma unroll
        for (int j2 = 0; j2 < 3; j2++) { C[k][j2][0] = 0.f; C[k][j2][1] = 0.f; }
    float Rr = 1.f, Ri = 0.f;
    for (int n = 0; n < 23; n++) {
        #pragma unroll
        for (int k = 0; k < 4; k++) {
            int frow = (4*n + k)*48 + cl;
            #pragma unroll
            for (int j2 = 0; j2 < 3; j2++) {
                float2 z = Sz[frow + 16*j2];
                C[k][j2][0] += z.x*Rr - z.y*Ri;
                C[k][j2][1] += z.x*Ri + z.y*Rr;
            }
        }
        float nr = Rr*c4 - Ri*s4;
        float ni = Rr*s4 + Ri*c4;
        Rr = nr; Ri = ni;
    }
    if (wp < 90) {
        float ck[4], sk[4];
        ck[0] = 1.f; sk[0] = 0.f;
        #pragma unroll
        for (int k = 1; k < 4; k++) sincosf(TH*(float)(k*wp), &sk[k], &ck[k]);
        #pragma unroll
        for (int j2 = 0; j2 < 3; j2++) {
            float re[4], im[4];
            #pragma unroll
            for (int k = 0; k < 4; k++) {
                re[k] = C[k][j2][0]*ck[k] - C[k][j2][1]*sk[k];
                im[k] = C[k][j2][0]*sk[k] + C[k][j2][1]*ck[k];
            }
            float o0 = re[0] + re[1] + re[2] + re[3];
            float o1 = re[0] - im[1] - re[2] + im[3];
            float o2 = re[0] - re[1] + re[2] - re[3];
            float o3 = re[0] + im[1] - re[2] - im[3];
            int cfull = cb0 + cy*48 + cl + 16*j2;
            size_t b0 = ((size_t)h*WW + wp      )*CC + cfull;
            size_t b1 = ((size_t)h*WW + wp +  90)*CC + cfull;
            size_t b2 = ((size_t)h*WW + wp + 180)*CC + cfull;
            size_t b3 = ((size_t)h*WW + wp + 270)*CC + cfull;
            hout[b0] = o0 + hout[b0] + xin[b0];
            hout[b1] = o1 + hout[b1] + xin[b1];
            hout[b2] = o2 + hout[b2] + xin[b2];
            hout[b3] = o3 + hout[b3] + xin[b3];
        }
    }
}

// ---------------- tiled weight transpose + bf16 convert ----------------
__global__ __launch_bounds__(256) void transpose_bf16_kernel(const float* __restrict__ src,
        __hip_bfloat16* __restrict__ dst, int K, int N) {
    __shared__ float tile[32][33];
    int n0 = blockIdx.x * 32;
    int k0 = blockIdx.y * 32;
    int tx = threadIdx.x & 31;
    int ty = threadIdx.x >> 5;
    #pragma unroll
    for (int r = 0; r < 32; r += 8) {
        tile[ty + r][tx] = src[(size_t)(k0 + ty + r) * N + n0 + tx];
    }
    __syncthreads();
    #pragma unroll
    for (int r = 0; r < 32; r += 8) {
        dst[(size_t)(n0 + ty + r) * K + k0 + tx] = __float2bfloat16(tile[tx][ty + r]);
    }
}

// ---------------- bf16 MFMA GEMM, 128x128 tile, BK=32, 4 waves, global_load_lds ----------------
template<int MODE>
__global__ __launch_bounds__(256) void gemm_kernel(
        const __hip_bfloat16* __restrict__ A,
        const __hip_bfloat16* __restrict__ Bt,
        int M, int K, int N,
        const float* __restrict__ bias,
        const float* __restrict__ sv, const float* __restrict__ tv,
        const float* resid, void* out) {
    __shared__ unsigned short As[128*32];
    __shared__ unsigned short Bs[128*32];
    int tid = threadIdx.x;
    int nbase = blockIdx.x * 128;
    int mbase = blockIdx.y * 128;
    int l = tid & 63, wv = tid >> 6;
    int wm = wv & 1, wn = wv >> 1;
    int lm = l & 15;
    int kgrp = (l >> 4) * 8;
    f32x4 acc[4][4] = {};
    int nkt = K >> 5;
    for (int kt = 0; kt < nkt; kt++) {
        int kb = kt * 32;
        __syncthreads();
        #pragma unroll
        for (int i = 0; i < 2; i++) {
            int ch = (wv*2 + i)*64 + l;
            int row = ch >> 2;
            int ko = (ch & 3) * 8;
            int am = mbase + row; if (am >= M) am = M - 1;
            const __hip_bfloat16* ga = A  + (size_t)am * K + kb + ko;
            const __hip_bfloat16* gb = Bt + (size_t)(nbase + row) * K + kb + ko;
            __builtin_amdgcn_global_load_lds(
                (const __attribute__((address_space(1))) void*)(unsigned long long)(uintptr_t)ga,
                (__attribute__((address_space(3))) void*)(unsigned long long)(uintptr_t)(As + (wv*2 + i)*512),
                16, 0, 0);
            __builtin_amdgcn_global_load_lds(
                (const __attribute__((address_space(1))) void*)(unsigned long long)(uintptr_t)gb,
                (__attribute__((address_space(3))) void*)(unsigned long long)(uintptr_t)(Bs + (wv*2 + i)*512),
                16, 0, 0);
        }
        __syncthreads();
        bf16x8 af[4], bfv[4];
        #pragma unroll
        for (int i = 0; i < 4; i++) {
            af[i]  = *(const bf16x8*)(As + (wm*64 + i*16 + lm)*32 + kgrp);
            bfv[i] = *(const bf16x8*)(Bs + (wn*64 + i*16 + lm)*32 + kgrp);
        }
        #pragma unroll
        for (int i = 0; i < 4; i++)
            #pragma unroll
            for (int j = 0; j < 4; j++)
                acc[i][j] = __builtin_amdgcn_mfma_f32_16x16x32_bf16(af[i], bfv[j], acc[i][j], 0, 0, 0);
    }
    int r0 = (l >> 4) * 4;
    #pragma unroll
    for (int j = 0; j < 4; j++) {
        int col = nbase + wn*64 + j*16 + lm;
        float bb = bias[col];
        float ss = 0.f, tt = 0.f;
        if (MODE == 0) { ss = sv[col]; tt = tv[col]; }
        #pragma unroll
        for (int i = 0; i < 4; i++) {
            int rowb = mbase + wm*64 + i*16 + r0;
            #pragma unroll
            for (int r = 0; r < 4; r++) {
                int row = rowb + r;
                if (row < M) {
                    float v = acc[i][j][r] + bb;
                    if (MODE == 0) {
                        v = gelu_f(v*ss + tt);
                        ((__hip_bfloat16*)out)[(size_t)row*N + col] = __float2bfloat16(v);
                    } else {
                        ((float*)out)[(size_t)row*N + col] = v + resid[(size_t)row*N + col];
                    }
                }
            }
        }
    }
}

extern "C" void kernel_launch(void* const* d_in, const int* in_sizes, int n_in,
                              void* d_out, int out_size, void* d_ws, size_t ws_size,
                              hipStream_t stream) {
    const float* x     = (const float*)d_in[0];
    const float* emb   = (const float*)d_in[1];
    const float* n1w   = (const float*)d_in[2];
    const float* n1b   = (const float*)d_in[3];
    const float* n2w   = (const float*)d_in[4];
    const float* n2b   = (const float*)d_in[5];
    const float* w1    = (const float*)d_in[6];
    const float* b1    = (const float*)d_in[7];
    const float* w2    = (const float*)d_in[8];
    const float* b2    = (const float*)d_in[9];
    const float* fs_w0 = (const float*)d_in[10];
    const float* fs_b0 = (const float*)d_in[11];
    const float* fs_w1 = (const float*)d_in[12];
    const float* fs_b1 = (const float*)d_in[13];
    const float* fc1w  = (const float*)d_in[14];
    const float* fc1b  = (const float*)d_in[15];
    const float* fc2w  = (const float*)d_in[16];
    const float* fc2b  = (const float*)d_in[17];
    const float* ms_w0 = (const float*)d_in[18];
    const float* ms_b0 = (const float*)d_in[19];
    const float* ms_w1 = (const float*)d_in[20];
    const float* ms_b1 = (const float*)d_in[21];
    float* out = (float*)d_out;
    (void)in_sizes; (void)n_in; (void)out_size; (void)ws_size;

    char* wsb = (char*)d_ws;
    size_t off = 0;
    auto alloc = [&](size_t nbytes) -> void* {
        void* p = wsb + off;
        off += (nbytes + 255) & ~(size_t)255;
        return p;
    };
    // total ws usage ~533 MB (ws_size ~796 MB per harness fill evidence)
    float* s_f  = (float*)alloc(768*4);
    float* t_f  = (float*)alloc(768*4);
    float* s_m  = (float*)alloc(3072*4);
    float* t_m  = (float*)alloc(3072*4);
    float* midf = (float*)alloc(1536*4);
    float* midm = (float*)alloc(6144*4);
    float* Yr   = (float*)alloc((size_t)NPOS*CHC*4);
    float* Yi   = (float*)alloc((size_t)NPOS*CHC*4);
    float* Zr   = (float*)alloc((size_t)NPOS*CHC*4);
    float* Zi   = (float*)alloc((size_t)NPOS*CHC*4);
    __hip_bfloat16* wT1  = (__hip_bfloat16*)alloc((size_t)CC*LAT*2);
    __hip_bfloat16* wT2  = (__hip_bfloat16*)alloc((size_t)CC*LAT*2);
    __hip_bfloat16* h2   = (__hip_bfloat16*)alloc((size_t)NROW*CC*2);
    __hip_bfloat16* hmid = (__hip_bfloat16*)alloc((size_t)NROW*LAT*2);

    // 1. modulation scale/shift vectors
    mod_a_kernel<<<30, 256, 0, stream>>>(emb, fs_w0, fs_b0, ms_w0, ms_b0, midf, midm);
    mod_b_kernel<<<120, 512, 0, stream>>>(midf, midm, fs_w1, fs_b1, ms_w1, ms_b1,
                                          s_f, t_f, s_m, t_m);
    // 2. LN1 -> d_out (h_ln lives in d_out)
    ln_f32_kernel<<<NROW/4, 256, 0, stream>>>(x, n1w, n1b, out);
    // 3. weight convert+transpose
    transpose_bf16_kernel<<<dim3(LAT/32, CC/32), 256, 0, stream>>>(fc1w, wT1, 768, 3072);
    transpose_bf16_kernel<<<dim3(CC/32, LAT/32), 256, 0, stream>>>(fc2w, wT2, 3072, 768);

    // 4. filter path, 8 chunks of 96 channels
    for (int ch = 0; ch < NCHUNK; ch++) {
        int cb0 = ch * CHC;
        wdft_kernel<<<dim3(6, 180), 256, 0, stream>>>(out, cb0, Yr, Yi);
        hfft_kernel<<<dim3(91, 8), 128, 0, stream>>>(Yr, Yi, Zr, Zi, -1.0f);
        bd_kernel<0><<<dim3(512, 1), 192, 0, stream>>>(Zr, Zi, w1, b1, s_f, t_f, ch, Yr, Yi);
        bd_kernel<1><<<dim3(512, 1), 192, 0, stream>>>(Yr, Yi, w2, b2, nullptr, nullptr, ch, Zr, Zi);
        hfft_kernel<<<dim3(91, 8), 128, 0, stream>>>(Zr, Zi, Yr, Yi, 1.0f);
        iwdft_kernel<<<dim3(6, 2, 180), 256, 0, stream>>>(Yr, Yi, x, cb0, out);
    }

    // 5. MLP path, single pass (d_out holds h; update in place)
    ln_bf16_kernel<<<NROW/4, 256, 0, stream>>>(out, n2w, n2b, h2);
    gemm_kernel<0><<<dim3(LAT/128, (NROW+127)/128), 256, 0, stream>>>(
        h2, wT1, NROW, CC, LAT, fc1b, s_m, t_m, nullptr, hmid);
    gemm_kernel<1><<<dim3(CC/128, (NROW+127)/128), 256, 0, stream>>>(
        hmid, wT2, NROW, LAT, CC, fc2b, nullptr, nullptr, out, out);
}

// Round 6
// 4086.966 us; speedup vs baseline: 1.5724x; 1.3056x over previous
//
#include <hip/hip_runtime.h>
#include <hip/hip_bf16.h>
#include <math.h>

// Problem constants
#define HH 180
#define WW 360
#define CC 768
#define FF 91          // kept W-frequencies (km = 91)
#define NPOS (HH*FF)   // 16380 frequency positions
#define NROW (HH*WW)   // 64800 spatial rows
#define LAT 3072

typedef __attribute__((ext_vector_type(8))) short bf16x8;
typedef __attribute__((ext_vector_type(4))) float f32x4;
typedef __attribute__((ext_vector_type(4))) unsigned int u32x4;

__device__ __forceinline__ float gelu_f(float x) {
    return 0.5f * x * (1.0f + erff(x * 0.7071067811865476f));
}

// ---------------- modulation stage A ----------------
__global__ __launch_bounds__(256) void mod_a_kernel(
        const float* __restrict__ e,
        const float* __restrict__ fs_w0, const float* __restrict__ fs_b0,
        const float* __restrict__ ms_w0, const float* __restrict__ ms_b0,
        float* __restrict__ mid_f, float* __restrict__ mid_m) {
    __shared__ float es[64];
    int t = threadIdx.x;
    if (t < 64) es[t] = e[t];
    __syncthreads();
    int j = blockIdx.x * 256 + t;
    if (j < 1536) {
        float a = fs_b0[j];
        #pragma unroll 8
        for (int k = 0; k < 64; k++) a += es[k] * fs_w0[k*1536 + j];
        mid_f[j] = gelu_f(a);
    } else {
        int jm = j - 1536;
        float a = ms_b0[jm];
        #pragma unroll 8
        for (int k = 0; k < 64; k++) a += es[k] * ms_w0[k*6144 + jm];
        mid_m[jm] = gelu_f(a);
    }
}

// ---------------- modulation stage B ----------------
__global__ __launch_bounds__(512) void mod_b_kernel(
        const float* __restrict__ mid_f, const float* __restrict__ mid_m,
        const float* __restrict__ fs_w1, const float* __restrict__ fs_b1,
        const float* __restrict__ ms_w1, const float* __restrict__ ms_b1,
        float* __restrict__ s_f, float* __restrict__ t_f,
        float* __restrict__ s_m, float* __restrict__ t_m) {
    __shared__ float red[8*64];
    int t = threadIdx.x;
    int g = t >> 6;
    int jl = t & 63;
    int blk = blockIdx.x;
    if (blk < 24) {
        int jo = blk*64 + jl;
        const int N = 1536, NQ = 192;
        float a = 0.f;
        const float* w = fs_w1 + (size_t)(g*NQ)*N + jo;
        for (int j = 0; j < NQ; j++) a += mid_f[g*NQ + j] * w[(size_t)j*N];
        red[t] = a;
        __syncthreads();
        if (t < 64) {
            float s = fs_b1[jo];
            #pragma unroll
            for (int q = 0; q < 8; q++) s += red[q*64 + jl];
            if (jo < 768) s_f[jo] = 1.0f + s;
            else          t_f[jo - 768] = s;
        }
    } else {
        int jo = (blk - 24)*64 + jl;
        const int N = 6144, NQ = 768;
        float a = 0.f;
        const float* w = ms_w1 + (size_t)(g*NQ)*N + jo;
        for (int j = 0; j < NQ; j++) a += mid_m[g*NQ + j] * w[(size_t)j*N];
        red[t] = a;
        __syncthreads();
        if (t < 64) {
            float s = ms_b1[jo];
            #pragma unroll
            for (int q = 0; q < 8; q++) s += red[q*64 + jl];
            if (jo < 3072) s_m[jo] = 1.0f + s;
            else           t_m[jo - 3072] = s;
        }
    }
}

// ---------------- LayerNorm fp32 out ----------------
__global__ __launch_bounds__(256) void ln_f32_kernel(const float* __restrict__ in,
        const float* __restrict__ w, const float* __restrict__ b,
        float* __restrict__ out) {
    int row = blockIdx.x*4 + (threadIdx.x >> 6);
    int l = threadIdx.x & 63;
    const float* p = in + (size_t)row*CC;
    float v[12]; float s = 0.f, sq = 0.f;
    #pragma unroll
    for (int i = 0; i < 12; i++) { float tv = p[l + 64*i]; v[i] = tv; s += tv; sq += tv*tv; }
    #pragma unroll
    for (int m = 1; m < 64; m <<= 1) { s += __shfl_xor(s, m); sq += __shfl_xor(sq, m); }
    float mean = s * (1.0f/768.0f);
    float var  = sq * (1.0f/768.0f) - mean*mean;
    float rstd = rsqrtf(var + 1e-5f);
    float* o = out + (size_t)row*CC;
    #pragma unroll
    for (int i = 0; i < 12; i++) { int c = l + 64*i; o[c] = (v[i]-mean)*rstd*w[c] + b[c]; }
}

// ---------------- LayerNorm bf16 out ----------------
__global__ __launch_bounds__(256) void ln_bf16_kernel(const float* __restrict__ in,
        const float* __restrict__ w, const float* __restrict__ b,
        __hip_bfloat16* __restrict__ out) {
    int row = blockIdx.x*4 + (threadIdx.x >> 6);
    int l = threadIdx.x & 63;
    const float* p = in + (size_t)row*CC;
    float v[12]; float s = 0.f, sq = 0.f;
    #pragma unroll
    for (int i = 0; i < 12; i++) { float tv = p[l + 64*i]; v[i] = tv; s += tv; sq += tv*tv; }
    #pragma unroll
    for (int m = 1; m < 64; m <<= 1) { s += __shfl_xor(s, m); sq += __shfl_xor(sq, m); }
    float mean = s * (1.0f/768.0f);
    float var  = sq * (1.0f/768.0f) - mean*mean;
    float rstd = rsqrtf(var + 1e-5f);
    __hip_bfloat16* o = out + (size_t)row*CC;
    #pragma unroll
    for (int i = 0; i < 12; i++) { int c = l + 64*i; o[c] = __float2bfloat16((v[i]-mean)*rstd*w[c] + b[c]); }
}

// ---------------- forward rDFT along W, radix-4 folded, full width ----------------
// 256 thr = 32 fl x 8 cl ; f = fl+32q (q<3, guard<91) ; c = cy*16 + cl + 8*j2 (j2<2)
__global__ __launch_bounds__(256) void wdft_kernel(const float* __restrict__ hln,
        float* __restrict__ Yr, float* __restrict__ Yi) {
    int h = blockIdx.y;
    int cy = blockIdx.x;            // 0..47 (cspan 16)
    __shared__ float2 P[4*90*16];   // plane k at k*1440
    int t = threadIdx.x;
    const float rn = 0.05270462766947299f;  // 1/sqrt(360)
    for (int e2 = t; e2 < 90*16; e2 += 256) {
        int v = e2 >> 4, cc = e2 & 15;
        size_t base = ((size_t)h*WW + v)*CC + cy*16 + cc;
        float x0 = hln[base];
        float x1 = hln[base + 90*CC];
        float x2 = hln[base + 180*CC];
        float x3 = hln[base + 270*CC];
        float u0 = (x0+x1+x2+x3)*rn;
        float u2 = (x0-x1+x2-x3)*rn;
        float A  = (x0-x2)*rn;
        float B  = (x1-x3)*rn;
        P[0*1440 + e2] = make_float2(u0, 0.f);
        P[1*1440 + e2] = make_float2(A, -B);
        P[2*1440 + e2] = make_float2(u2, 0.f);
        P[3*1440 + e2] = make_float2(A,  B);
    }
    __syncthreads();
    int fl = t & 31, cl = t >> 5;   // fl<32, cl<8
    int pbase = (fl & 3) * 1440;
    const float TH = 6.283185307179586f / 360.0f;
    float Tc[3], Ts[3], sc[3], ss[3];
    float Y[3][2][2];
    #pragma unroll
    for (int q = 0; q < 3; q++) {
        int f = fl + 32*q;
        float s_, c_; sincosf(TH * (float)f, &s_, &c_);
        sc[q] = c_; ss[q] = s_;
        Tc[q] = 1.f; Ts[q] = 0.f;
        Y[q][0][0]=Y[q][0][1]=Y[q][1][0]=Y[q][1][1]=0.f;
    }
    for (int v = 0; v < 90; v++) {
        float2 u0v = P[pbase + v*16 + cl];
        float2 u1v = P[pbase + v*16 + cl + 8];
        #pragma unroll
        for (int q = 0; q < 3; q++) {
            Y[q][0][0] += u0v.x*Tc[q] + u0v.y*Ts[q];
            Y[q][0][1] += u0v.y*Tc[q] - u0v.x*Ts[q];
            Y[q][1][0] += u1v.x*Tc[q] + u1v.y*Ts[q];
            Y[q][1][1] += u1v.y*Tc[q] - u1v.x*Ts[q];
            float nc = Tc[q]*sc[q] - Ts[q]*ss[q];
            float ns = Tc[q]*ss[q] + Ts[q]*sc[q];
            Tc[q] = nc; Ts[q] = ns;
        }
    }
    #pragma unroll
    for (int q = 0; q < 3; q++) {
        int f = fl + 32*q;
        if (f < FF) {
            #pragma unroll
            for (int j2 = 0; j2 < 2; j2++) {
                size_t idx = ((size_t)h*FF + f)*CC + cy*16 + cl + 8*j2;
                Yr[idx] = Y[q][j2][0];
                Yi[idx] = Y[q][j2][1];
            }
        }
    }
}

// ---------------- complex FFT along H (180), radix-4 folded, full width ----------------
// 128 thr = 32 tl x 4 cl ; t = tl+32q (q<6, guard<180) ; c = cy*12 + cl + 4*j2 (j2<3)
__global__ __launch_bounds__(128) void hfft_kernel(const float* __restrict__ Ir,
        const float* __restrict__ Ii, float* __restrict__ Or_, float* __restrict__ Oi_,
        float sign) {
    int f = blockIdx.x;
    int cy = blockIdx.y;            // 0..63 (cspan 12)
    __shared__ float2 P[4*45*12];   // plane k at k*540
    int t = threadIdx.x;
    const float rn = 0.07453559924999299f;  // 1/sqrt(180)
    for (int e2 = t; e2 < 45*12; e2 += 128) {
        int v = e2 / 12, cc = e2 - v*12;
        size_t i0 = ((size_t)(v      )*FF + f)*CC + cy*12 + cc;
        size_t i1 = ((size_t)(v + 45 )*FF + f)*CC + cy*12 + cc;
        size_t i2 = ((size_t)(v + 90 )*FF + f)*CC + cy*12 + cc;
        size_t i3 = ((size_t)(v + 135)*FF + f)*CC + cy*12 + cc;
        float z0r = Ir[i0]*rn, z0i = Ii[i0]*rn;
        float z1r = Ir[i1]*rn, z1i = Ii[i1]*rn;
        float z2r = Ir[i2]*rn, z2i = Ii[i2]*rn;
        float z3r = Ir[i3]*rn, z3i = Ii[i3]*rn;
        float d02r = z0r - z2r, d02i = z0i - z2i;
        float d13r = z1r - z3r, d13i = z1i - z3i;
        P[0*540 + e2] = make_float2(z0r+z1r+z2r+z3r, z0i+z1i+z2i+z3i);
        P[2*540 + e2] = make_float2(z0r-z1r+z2r-z3r, z0i-z1i+z2i-z3i);
        P[1*540 + e2] = make_float2(d02r - sign*d13i, d02i + sign*d13r);
        P[3*540 + e2] = make_float2(d02r + sign*d13i, d02i - sign*d13r);
    }
    __syncthreads();
    int tl = t & 31, cl = t >> 5;   // tl<32, cl<4
    int pbase = (tl & 3) * 540;
    const float PH = 6.283185307179586f / 180.0f;
    float Tc[6], Ts[6], sc[6], ss[6];
    float O[6][3][2];
    #pragma unroll
    for (int q = 0; q < 6; q++) {
        int tq = tl + 32*q;
        float s_, c_; sincosf(sign * PH * (float)tq, &s_, &c_);
        sc[q] = c_; ss[q] = s_;
        Tc[q] = 1.f; Ts[q] = 0.f;
        #pragma unroll
        for (int j2 = 0; j2 < 3; j2++) { O[q][j2][0] = 0.f; O[q][j2][1] = 0.f; }
    }
    for (int v = 0; v < 45; v++) {
        float2 u[3];
        #pragma unroll
        for (int j2 = 0; j2 < 3; j2++) u[j2] = P[pbase + v*12 + cl + 4*j2];
        #pragma unroll
        for (int q = 0; q < 6; q++) {
            #pragma unroll
            for (int j2 = 0; j2 < 3; j2++) {
                O[q][j2][0] += u[j2].x*Tc[q] - u[j2].y*Ts[q];
                O[q][j2][1] += u[j2].x*Ts[q] + u[j2].y*Tc[q];
            }
            float nc = Tc[q]*sc[q] - Ts[q]*ss[q];
            float ns = Tc[q]*ss[q] + Ts[q]*sc[q];
            Tc[q] = nc; Ts[q] = ns;
        }
    }
    #pragma unroll
    for (int q = 0; q < 6; q++) {
        int tq = tl + 32*q;
        if (tq < HH) {
            #pragma unroll
            for (int j2 = 0; j2 < 3; j2++) {
                size_t idx = ((size_t)tq*FF + f)*CC + cy*12 + cl + 4*j2;
                Or_[idx] = O[q][j2][0];
                Oi_[idx] = O[q][j2][1];
            }
        }
    }
}

// ---------------- per-frequency block-diagonal complex matmul, full width ----------------
template<int LAYER>
__global__ __launch_bounds__(192) void bd_kernel(
        const float* __restrict__ Ir, const float* __restrict__ Ii,
        const float* __restrict__ wgt, const float* __restrict__ bias,
        const float* __restrict__ sf, const float* __restrict__ tf,
        float* __restrict__ Or_, float* __restrict__ Oi_) {
    int tile = blockIdx.x;
    int wb = blockIdx.y;     // 0..7
    int p0 = tile * 32;
    __shared__ float2 Ls[32*96];
    int t = threadIdx.x;
    for (int e2 = t; e2 < 32*96; e2 += 192) {
        int pp = e2 / 96, cc = e2 - pp*96;
        int p = p0 + pp; if (p >= NPOS) p = NPOS - 1;
        size_t idx = (size_t)p*CC + wb*96 + cc;
        Ls[e2] = make_float2(Ir[idx], Ii[idx]);
    }
    __syncthreads();
    int oc = (t >= 96) ? (t - 96) : t;
    int pg = (t >= 96) ? 1 : 0;
    const float* Wr = wgt + (size_t)wb * 9216;
    const float* Wi = wgt + (size_t)(8 + wb) * 9216;
    float br = bias[wb*96 + oc];
    float bi = bias[768 + wb*96 + oc];
    float ar[16], ai[16];
    #pragma unroll
    for (int i = 0; i < 16; i++) { ar[i] = br; ai[i] = bi; }
    for (int k = 0; k < 96; k++) {
        float wr = Wr[k*96 + oc];
        float wi = Wi[k*96 + oc];
        #pragma unroll
        for (int i = 0; i < 16; i++) {
            float2 y = Ls[(pg + 2*i)*96 + k];
            ar[i] += y.x*wr - y.y*wi;
            ai[i] += y.x*wi + y.y*wr;
        }
    }
    if (LAYER == 0) {
        float s  = sf[wb*96 + oc];
        float tt = tf[wb*96 + oc];
        #pragma unroll
        for (int i = 0; i < 16; i++) {
            int p = p0 + pg + 2*i;
            if (p < NPOS) {
                size_t idx = (size_t)p*CC + wb*96 + oc;
                Or_[idx] = fmaxf(ar[i]*s + tt, 0.0f);
                Oi_[idx] = fmaxf(ai[i]*s + tt, 0.0f);
            }
        }
    } else {
        #pragma unroll
        for (int i = 0; i < 16; i++) {
            int p = p0 + pg + 2*i;
            if (p < NPOS) {
                float vr = ar[i], vi = ai[i];
                vr = (vr > 0.01f) ? (vr - 0.01f) : ((vr < -0.01f) ? (vr + 0.01f) : 0.0f);
                vi = (vi > 0.01f) ? (vi - 0.01f) : ((vi < -0.01f) ? (vi + 0.01f) : 0.0f);
                size_t idx = (size_t)p*CC + wb*96 + oc;
                Or_[idx] = vr;
                Oi_[idx] = vi;
            }
        }
    }
}

// ---------------- inverse rDFT along W, quarter-output symmetry, full width, in place ----------------
// 256 thr = 16 cl x 16 wl ; wp = bx*16+wl (guard<90) ; c = cy*48 + cl + 16*j2 (j2<3)
__global__ __launch_bounds__(256) void iwdft_kernel(const float* __restrict__ Zr,
        const float* __restrict__ Zi, const float* __restrict__ xin,
        float* __restrict__ hout) {
    int h = blockIdx.z;
    int cy = blockIdx.y;            // 0..15 (cspan 48)
    __shared__ float2 Sz[92*48];    // f-major, pre-scaled by rn*m_f, row 91 = 0
    int t = threadIdx.x;
    const float rn = 0.05270462766947299f;  // 1/sqrt(360)
    for (int e2 = t; e2 < 92*48; e2 += 256) {
        int f = e2 / 48, c = e2 - f*48;
        if (f < FF) {
            size_t idx = ((size_t)h*FF + f)*CC + cy*48 + c;
            float m = (f == 0) ? rn : 2.0f*rn;
            Sz[e2] = make_float2(m*Zr[idx], m*Zi[idx]);
        } else {
            Sz[e2] = make_float2(0.f, 0.f);
        }
    }
    __syncthreads();
    int cl = t & 15, wl = t >> 4;
    int wp = blockIdx.x*16 + wl;    // guard < 90 at store
    const float TH = 6.283185307179586f / 360.0f;
    float s4, c4; sincosf(4.0f*TH*(float)wp, &s4, &c4);
    float C[4][3][2];
    #pragma unroll
    for (int k = 0; k < 4; k++)
        #pragma unroll
        for (int j2 = 0; j2 < 3; j2++) { C[k][j2][0] = 0.f; C[k][j2][1] = 0.f; }
    float Rr = 1.f, Ri = 0.f;
    for (int n = 0; n < 23; n++) {
        #pragma unroll
        for (int k = 0; k < 4; k++) {
            int frow = (4*n + k)*48 + cl;
            #pragma unroll
            for (int j2 = 0; j2 < 3; j2++) {
                float2 z = Sz[frow + 16*j2];
                C[k][j2][0] += z.x*Rr - z.y*Ri;
                C[k][j2][1] += z.x*Ri + z.y*Rr;
            }
        }
        float nr = Rr*c4 - Ri*s4;
        float ni = Rr*s4 + Ri*c4;
        Rr = nr; Ri = ni;
    }
    if (wp < 90) {
        float ck[4], sk[4];
        ck[0] = 1.f; sk[0] = 0.f;
        #pragma unroll
        for (int k = 1; k < 4; k++) sincosf(TH*(float)(k*wp), &sk[k], &ck[k]);
        #pragma unroll
        for (int j2 = 0; j2 < 3; j2++) {
            float re[4], im[4];
            #pragma unroll
            for (int k = 0; k < 4; k++) {
                re[k] = C[k][j2][0]*ck[k] - C[k][j2][1]*sk[k];
                im[k] = C[k][j2][0]*sk[k] + C[k][j2][1]*ck[k];
            }
            float o0 = re[0] + re[1] + re[2] + re[3];
            float o1 = re[0] - im[1] - re[2] + im[3];
            float o2 = re[0] - re[1] + re[2] - re[3];
            float o3 = re[0] + im[1] - re[2] - im[3];
            int cfull = cy*48 + cl + 16*j2;
            size_t b0 = ((size_t)h*WW + wp      )*CC + cfull;
            size_t b1 = ((size_t)h*WW + wp +  90)*CC + cfull;
            size_t b2 = ((size_t)h*WW + wp + 180)*CC + cfull;
            size_t b3 = ((size_t)h*WW + wp + 270)*CC + cfull;
            hout[b0] = o0 + hout[b0] + xin[b0];
            hout[b1] = o1 + hout[b1] + xin[b1];
            hout[b2] = o2 + hout[b2] + xin[b2];
            hout[b3] = o3 + hout[b3] + xin[b3];
        }
    }
}

// ---------------- tiled weight transpose + bf16 convert ----------------
__global__ __launch_bounds__(256) void transpose_bf16_kernel(const float* __restrict__ src,
        __hip_bfloat16* __restrict__ dst, int K, int N) {
    __shared__ float tile[32][33];
    int n0 = blockIdx.x * 32;
    int k0 = blockIdx.y * 32;
    int tx = threadIdx.x & 31;
    int ty = threadIdx.x >> 5;
    #pragma unroll
    for (int r = 0; r < 32; r += 8) {
        tile[ty + r][tx] = src[(size_t)(k0 + ty + r) * N + n0 + tx];
    }
    __syncthreads();
    #pragma unroll
    for (int r = 0; r < 32; r += 8) {
        dst[(size_t)(n0 + ty + r) * K + k0 + tx] = __float2bfloat16(tile[tx][ty + r]);
    }
}

// ---------------- bf16 MFMA GEMM, 128x128 tile, BK=64, 4 waves ----------------
// global_load_lds with XOR-swizzled source (slot = k_chunk ^ (row&7)) -> conflict-free ds_read
// MODE 0: hmid = bf16(gelu((A@B + bias)*s + t)), LDS-staged coalesced store
// MODE 1: out = A@B + bias + resid (fp32, direct store)
template<int MODE>
__global__ __launch_bounds__(256) void gemm_kernel(
        const __hip_bfloat16* __restrict__ A,
        const __hip_bfloat16* __restrict__ Bt,
        int M, int K, int N,
        const float* __restrict__ bias,
        const float* __restrict__ sv, const float* __restrict__ tv,
        const float* resid, void* out) {
    __shared__ __align__(16) unsigned short SH[128*136];  // 34.8KB; staging uses first 32KB
    unsigned short* As = SH;              // [128][64]
    unsigned short* Bs = SH + 128*64;     // [128][64]
    int tid = threadIdx.x;
    int nbase = blockIdx.x * 128;
    int mbase = blockIdx.y * 128;
    int l = tid & 63, wv = tid >> 6;
    int wm = wv & 1, wn = wv >> 1;
    int lm = l & 15;
    int kq = l >> 4;                      // 0..3
    f32x4 acc[4][4] = {};
    int nkt = K >> 6;                     // BK=64
    for (int kt = 0; kt < nkt; kt++) {
        int kb = kt << 6;
        __syncthreads();
        #pragma unroll
        for (int i = 0; i < 4; i++) {
            int ch = i*256 + tid;         // 0..1023 ; LDS dest = ch*16B (lane-linear)
            int row = ch >> 3;
            int sl = ch & 7;
            int kg = (sl ^ (row & 7)) << 3;   // swizzled global k-offset (elements)
            int am = mbase + row; if (am >= M) am = M - 1;
            const __hip_bfloat16* ga = A  + (size_t)am * K + kb + kg;
            const __hip_bfloat16* gb = Bt + (size_t)(nbase + row) * K + kb + kg;
            __builtin_amdgcn_global_load_lds(
                (const __attribute__((address_space(1))) void*)(unsigned long long)(uintptr_t)ga,
                (__attribute__((address_space(3))) void*)(unsigned long long)(uintptr_t)(As + ch*8),
                16, 0, 0);
            __builtin_amdgcn_global_load_lds(
                (const __attribute__((address_space(1))) void*)(unsigned long long)(uintptr_t)gb,
                (__attribute__((address_space(3))) void*)(unsigned long long)(uintptr_t)(Bs + ch*8),
                16, 0, 0);
        }
        __syncthreads();
        #pragma unroll
        for (int kk = 0; kk < 2; kk++) {
            bf16x8 af[4], bfv[4];
            #pragma unroll
            for (int i = 0; i < 4; i++) {
                int ra = wm*64 + i*16 + lm;
                af[i]  = *(const bf16x8*)(As + ra*64 + ((((kk<<2)+kq) ^ (ra&7))<<3));
                int rb = wn*64 + i*16 + lm;
                bfv[i] = *(const bf16x8*)(Bs + rb*64 + ((((kk<<2)+kq) ^ (rb&7))<<3));
            }
            #pragma unroll
            for (int i = 0; i < 4; i++)
                #pragma unroll
                for (int j = 0; j < 4; j++)
                    acc[i][j] = __builtin_amdgcn_mfma_f32_16x16x32_bf16(af[i], bfv[j], acc[i][j], 0, 0, 0);
        }
    }
    int r0 = kq * 4;
    if (MODE == 0) {
        __syncthreads();   // staging LDS now dead; reuse for epilogue tile [128][136]
        #pragma unroll
        for (int j = 0; j < 4; j++) {
            int col = wn*64 + j*16 + lm;
            int gcol = nbase + col;
            float bb = bias[gcol];
            float ss = sv[gcol], tt = tv[gcol];
            #pragma unroll
            for (int i = 0; i < 4; i++) {
                int rowb = wm*64 + i*16 + r0;
                #pragma unroll
                for (int r = 0; r < 4; r++) {
                    float v = gelu_f((acc[i][j][r] + bb)*ss + tt);
                    __hip_bfloat16 hb = __float2bfloat16(v);
                    SH[(rowb + r)*136 + col] = *reinterpret_cast<unsigned short*>(&hb);
                }
            }
        }
        __syncthreads();
        #pragma unroll
        for (int it = 0; it < 8; it++) {
            int chunk = it*256 + tid;     // 0..2047 ; 16 chunks of 8 cols per row
            int row = chunk >> 4;
            int c8 = chunk & 15;
            int mr = mbase + row;
            if (mr < M) {
                *(u32x4*)((__hip_bfloat16*)out + (size_t)mr*N + nbase + c8*8) =
                    *(const u32x4*)(SH + row*136 + c8*8);
            }
        }
    } else {
        #pragma unroll
        for (int j = 0; j < 4; j++) {
            int col = nbase + wn*64 + j*16 + lm;
            float bb = bias[col];
            #pragma unroll
            for (int i = 0; i < 4; i++) {
                int rowb = mbase + wm*64 + i*16 + r0;
                #pragma unroll
                for (int r = 0; r < 4; r++) {
                    int row = rowb + r;
                    if (row < M) {
                        float v = acc[i][j][r] + bb;
                        ((float*)out)[(size_t)row*N + col] = v + resid[(size_t)row*N + col];
                    }
                }
            }
        }
    }
}

extern "C" void kernel_launch(void* const* d_in, const int* in_sizes, int n_in,
                              void* d_out, int out_size, void* d_ws, size_t ws_size,
                              hipStream_t stream) {
    const float* x     = (const float*)d_in[0];
    const float* emb   = (const float*)d_in[1];
    const float* n1w   = (const float*)d_in[2];
    const float* n1b   = (const float*)d_in[3];
    const float* n2w   = (const float*)d_in[4];
    const float* n2b   = (const float*)d_in[5];
    const float* w1    = (const float*)d_in[6];
    const float* b1    = (const float*)d_in[7];
    const float* w2    = (const float*)d_in[8];
    const float* b2    = (const float*)d_in[9];
    const float* fs_w0 = (const float*)d_in[10];
    const float* fs_b0 = (const float*)d_in[11];
    const float* fs_w1 = (const float*)d_in[12];
    const float* fs_b1 = (const float*)d_in[13];
    const float* fc1w  = (const float*)d_in[14];
    const float* fc1b  = (const float*)d_in[15];
    const float* fc2w  = (const float*)d_in[16];
    const float* fc2b  = (const float*)d_in[17];
    const float* ms_w0 = (const float*)d_in[18];
    const float* ms_b0 = (const float*)d_in[19];
    const float* ms_w1 = (const float*)d_in[20];
    const float* ms_b1 = (const float*)d_in[21];
    float* out = (float*)d_out;
    (void)in_sizes; (void)n_in; (void)out_size; (void)ws_size;

    char* wsb = (char*)d_ws;
    size_t off = 0;
    auto alloc = [&](size_t nbytes) -> void* {
        void* p = wsb + off;
        off += (nbytes + 255) & ~(size_t)255;
        return p;
    };
    // ws usage: 4x50.3 (YZ) + 9.4 (wT) + 99.5 (h2) + 398 (hmid) = ~708 MB  (ws_size = 796 MB)
    float* s_f  = (float*)alloc(768*4);
    float* t_f  = (float*)alloc(768*4);
    float* s_m  = (float*)alloc(3072*4);
    float* t_m  = (float*)alloc(3072*4);
    float* midf = (float*)alloc(1536*4);
    float* midm = (float*)alloc(6144*4);
    float* Yr   = (float*)alloc((size_t)NPOS*CC*4);
    float* Yi   = (float*)alloc((size_t)NPOS*CC*4);
    float* Zr   = (float*)alloc((size_t)NPOS*CC*4);
    float* Zi   = (float*)alloc((size_t)NPOS*CC*4);
    __hip_bfloat16* wT1  = (__hip_bfloat16*)alloc((size_t)CC*LAT*2);
    __hip_bfloat16* wT2  = (__hip_bfloat16*)alloc((size_t)CC*LAT*2);
    __hip_bfloat16* h2   = (__hip_bfloat16*)alloc((size_t)NROW*CC*2);
    __hip_bfloat16* hmid = (__hip_bfloat16*)alloc((size_t)NROW*LAT*2);

    // 1. modulation scale/shift vectors
    mod_a_kernel<<<30, 256, 0, stream>>>(emb, fs_w0, fs_b0, ms_w0, ms_b0, midf, midm);
    mod_b_kernel<<<120, 512, 0, stream>>>(midf, midm, fs_w1, fs_b1, ms_w1, ms_b1,
                                          s_f, t_f, s_m, t_m);
    // 2. LN1 -> d_out (h_ln lives in d_out)
    ln_f32_kernel<<<NROW/4, 256, 0, stream>>>(x, n1w, n1b, out);
    // 3. weight convert+transpose
    transpose_bf16_kernel<<<dim3(LAT/32, CC/32), 256, 0, stream>>>(fc1w, wT1, 768, 3072);
    transpose_bf16_kernel<<<dim3(CC/32, LAT/32), 256, 0, stream>>>(fc2w, wT2, 3072, 768);

    // 4. filter path, full width (6 dispatches)
    wdft_kernel<<<dim3(48, 180), 256, 0, stream>>>(out, Yr, Yi);
    hfft_kernel<<<dim3(91, 64), 128, 0, stream>>>(Yr, Yi, Zr, Zi, -1.0f);
    bd_kernel<0><<<dim3(512, 8), 192, 0, stream>>>(Zr, Zi, w1, b1, s_f, t_f, Yr, Yi);
    bd_kernel<1><<<dim3(512, 8), 192, 0, stream>>>(Yr, Yi, w2, b2, nullptr, nullptr, Zr, Zi);
    hfft_kernel<<<dim3(91, 64), 128, 0, stream>>>(Zr, Zi, Yr, Yi, 1.0f);
    iwdft_kernel<<<dim3(6, 16, 180), 256, 0, stream>>>(Yr, Yi, x, out);

    // 5. MLP path, single pass (d_out holds h; update in place)
    ln_bf16_kernel<<<NROW/4, 256, 0, stream>>>(out, n2w, n2b, h2);
    gemm_kernel<0><<<dim3(LAT/128, (NROW+127)/128), 256, 0, stream>>>(
        h2, wT1, NROW, CC, LAT, fc1b, s_m, t_m, nullptr, hmid);
    gemm_kernel<1><<<dim3(CC/128, (NROW+127)/128), 256, 0, stream>>>(
        hmid, wT2, NROW, LAT, CC, fc2b, nullptr, nullptr, out, out);
}

// Round 7
// 2684.778 us; speedup vs baseline: 2.3937x; 1.5223x over previous
//
#include <hip/hip_runtime.h>
#include <hip/hip_bf16.h>
#include <math.h>

// Problem constants
#define HH 180
#define WW 360
#define CC 768
#define FF 91          // kept W-frequencies (km = 91)
#define NPOS (HH*FF)   // 16380 frequency positions
#define NROW (HH*WW)   // 64800 spatial rows
#define LAT 3072

typedef __attribute__((ext_vector_type(8))) short bf16x8;
typedef __attribute__((ext_vector_type(4))) float f32x4;
typedef __attribute__((ext_vector_type(4))) unsigned int u32x4;

__device__ __forceinline__ float gelu_f(float x) {
    return 0.5f * x * (1.0f + erff(x * 0.7071067811865476f));
}

// ---------------- modulation stage A ----------------
__global__ __launch_bounds__(256) void mod_a_kernel(
        const float* __restrict__ e,
        const float* __restrict__ fs_w0, const float* __restrict__ fs_b0,
        const float* __restrict__ ms_w0, const float* __restrict__ ms_b0,
        float* __restrict__ mid_f, float* __restrict__ mid_m) {
    __shared__ float es[64];
    int t = threadIdx.x;
    if (t < 64) es[t] = e[t];
    __syncthreads();
    int j = blockIdx.x * 256 + t;
    if (j < 1536) {
        float a = fs_b0[j];
        #pragma unroll 8
        for (int k = 0; k < 64; k++) a += es[k] * fs_w0[k*1536 + j];
        mid_f[j] = gelu_f(a);
    } else {
        int jm = j - 1536;
        float a = ms_b0[jm];
        #pragma unroll 8
        for (int k = 0; k < 64; k++) a += es[k] * ms_w0[k*6144 + jm];
        mid_m[jm] = gelu_f(a);
    }
}

// ---------------- modulation stage B ----------------
__global__ __launch_bounds__(512) void mod_b_kernel(
        const float* __restrict__ mid_f, const float* __restrict__ mid_m,
        const float* __restrict__ fs_w1, const float* __restrict__ fs_b1,
        const float* __restrict__ ms_w1, const float* __restrict__ ms_b1,
        float* __restrict__ s_f, float* __restrict__ t_f,
        float* __restrict__ s_m, float* __restrict__ t_m) {
    __shared__ float red[8*64];
    int t = threadIdx.x;
    int g = t >> 6;
    int jl = t & 63;
    int blk = blockIdx.x;
    if (blk < 24) {
        int jo = blk*64 + jl;
        const int N = 1536, NQ = 192;
        float a = 0.f;
        const float* w = fs_w1 + (size_t)(g*NQ)*N + jo;
        for (int j = 0; j < NQ; j++) a += mid_f[g*NQ + j] * w[(size_t)j*N];
        red[t] = a;
        __syncthreads();
        if (t < 64) {
            float s = fs_b1[jo];
            #pragma unroll
            for (int q = 0; q < 8; q++) s += red[q*64 + jl];
            if (jo < 768) s_f[jo] = 1.0f + s;
            else          t_f[jo - 768] = s;
        }
    } else {
        int jo = (blk - 24)*64 + jl;
        const int N = 6144, NQ = 768;
        float a = 0.f;
        const float* w = ms_w1 + (size_t)(g*NQ)*N + jo;
        for (int j = 0; j < NQ; j++) a += mid_m[g*NQ + j] * w[(size_t)j*N];
        red[t] = a;
        __syncthreads();
        if (t < 64) {
            float s = ms_b1[jo];
            #pragma unroll
            for (int q = 0; q < 8; q++) s += red[q*64 + jl];
            if (jo < 3072) s_m[jo] = 1.0f + s;
            else           t_m[jo - 3072] = s;
        }
    }
}

// ---------------- LayerNorm fp32 out ----------------
__global__ __launch_bounds__(256) void ln_f32_kernel(const float* __restrict__ in,
        const float* __restrict__ w, const float* __restrict__ b,
        float* __restrict__ out) {
    int row = blockIdx.x*4 + (threadIdx.x >> 6);
    int l = threadIdx.x & 63;
    const float* p = in + (size_t)row*CC;
    float v[12]; float s = 0.f, sq = 0.f;
    #pragma unroll
    for (int i = 0; i < 12; i++) { float tv = p[l + 64*i]; v[i] = tv; s += tv; sq += tv*tv; }
    #pragma unroll
    for (int m = 1; m < 64; m <<= 1) { s += __shfl_xor(s, m); sq += __shfl_xor(sq, m); }
    float mean = s * (1.0f/768.0f);
    float var  = sq * (1.0f/768.0f) - mean*mean;
    float rstd = rsqrtf(var + 1e-5f);
    float* o = out + (size_t)row*CC;
    #pragma unroll
    for (int i = 0; i < 12; i++) { int c = l + 64*i; o[c] = (v[i]-mean)*rstd*w[c] + b[c]; }
}

// ---------------- LayerNorm bf16 out ----------------
__global__ __launch_bounds__(256) void ln_bf16_kernel(const float* __restrict__ in,
        const float* __restrict__ w, const float* __restrict__ b,
        __hip_bfloat16* __restrict__ out) {
    int row = blockIdx.x*4 + (threadIdx.x >> 6);
    int l = threadIdx.x & 63;
    const float* p = in + (size_t)row*CC;
    float v[12]; float s = 0.f, sq = 0.f;
    #pragma unroll
    for (int i = 0; i < 12; i++) { float tv = p[l + 64*i]; v[i] = tv; s += tv; sq += tv*tv; }
    #pragma unroll
    for (int m = 1; m < 64; m <<= 1) { s += __shfl_xor(s, m); sq += __shfl_xor(sq, m); }
    float mean = s * (1.0f/768.0f);
    float var  = sq * (1.0f/768.0f) - mean*mean;
    float rstd = rsqrtf(var + 1e-5f);
    __hip_bfloat16* o = out + (size_t)row*CC;
    #pragma unroll
    for (int i = 0; i < 12; i++) { int c = l + 64*i; o[c] = __float2bfloat16((v[i]-mean)*rstd*w[c] + b[c]); }
}

// ---------------- forward rDFT along W, radix-4 folded, full width ----------------
__global__ __launch_bounds__(256) void wdft_kernel(const float* __restrict__ hln,
        float* __restrict__ Yr, float* __restrict__ Yi) {
    int h = blockIdx.y;
    int cy = blockIdx.x;            // 0..47 (cspan 16)
    __shared__ float2 P[4*90*16];   // plane k at k*1440
    int t = threadIdx.x;
    const float rn = 0.05270462766947299f;  // 1/sqrt(360)
    for (int e2 = t; e2 < 90*16; e2 += 256) {
        int v = e2 >> 4, cc = e2 & 15;
        size_t base = ((size_t)h*WW + v)*CC + cy*16 + cc;
        float x0 = hln[base];
        float x1 = hln[base + 90*CC];
        float x2 = hln[base + 180*CC];
        float x3 = hln[base + 270*CC];
        float u0 = (x0+x1+x2+x3)*rn;
        float u2 = (x0-x1+x2-x3)*rn;
        float A  = (x0-x2)*rn;
        float B  = (x1-x3)*rn;
        P[0*1440 + e2] = make_float2(u0, 0.f);
        P[1*1440 + e2] = make_float2(A, -B);
        P[2*1440 + e2] = make_float2(u2, 0.f);
        P[3*1440 + e2] = make_float2(A,  B);
    }
    __syncthreads();
    int fl = t & 31, cl = t >> 5;   // fl<32, cl<8
    int pbase = (fl & 3) * 1440;
    const float TH = 6.283185307179586f / 360.0f;
    float Tc[3], Ts[3], sc[3], ss[3];
    float Y[3][2][2];
    #pragma unroll
    for (int q = 0; q < 3; q++) {
        int f = fl + 32*q;
        float s_, c_; sincosf(TH * (float)f, &s_, &c_);
        sc[q] = c_; ss[q] = s_;
        Tc[q] = 1.f; Ts[q] = 0.f;
        Y[q][0][0]=Y[q][0][1]=Y[q][1][0]=Y[q][1][1]=0.f;
    }
    for (int v = 0; v < 90; v++) {
        float2 u0v = P[pbase + v*16 + cl];
        float2 u1v = P[pbase + v*16 + cl + 8];
        #pragma unroll
        for (int q = 0; q < 3; q++) {
            Y[q][0][0] += u0v.x*Tc[q] + u0v.y*Ts[q];
            Y[q][0][1] += u0v.y*Tc[q] - u0v.x*Ts[q];
            Y[q][1][0] += u1v.x*Tc[q] + u1v.y*Ts[q];
            Y[q][1][1] += u1v.y*Tc[q] - u1v.x*Ts[q];
            float nc = Tc[q]*sc[q] - Ts[q]*ss[q];
            float ns = Tc[q]*ss[q] + Ts[q]*sc[q];
            Tc[q] = nc; Ts[q] = ns;
        }
    }
    #pragma unroll
    for (int q = 0; q < 3; q++) {
        int f = fl + 32*q;
        if (f < FF) {
            #pragma unroll
            for (int j2 = 0; j2 < 2; j2++) {
                size_t idx = ((size_t)h*FF + f)*CC + cy*16 + cl + 8*j2;
                Yr[idx] = Y[q][j2][0];
                Yi[idx] = Y[q][j2][1];
            }
        }
    }
}

// ---------------- complex FFT along H (180), radix-4 folded, full width ----------------
__global__ __launch_bounds__(128) void hfft_kernel(const float* __restrict__ Ir,
        const float* __restrict__ Ii, float* __restrict__ Or_, float* __restrict__ Oi_,
        float sign) {
    int f = blockIdx.x;
    int cy = blockIdx.y;            // 0..63 (cspan 12)
    __shared__ float2 P[4*45*12];   // plane k at k*540
    int t = threadIdx.x;
    const float rn = 0.07453559924999299f;  // 1/sqrt(180)
    for (int e2 = t; e2 < 45*12; e2 += 128) {
        int v = e2 / 12, cc = e2 - v*12;
        size_t i0 = ((size_t)(v      )*FF + f)*CC + cy*12 + cc;
        size_t i1 = ((size_t)(v + 45 )*FF + f)*CC + cy*12 + cc;
        size_t i2 = ((size_t)(v + 90 )*FF + f)*CC + cy*12 + cc;
        size_t i3 = ((size_t)(v + 135)*FF + f)*CC + cy*12 + cc;
        float z0r = Ir[i0]*rn, z0i = Ii[i0]*rn;
        float z1r = Ir[i1]*rn, z1i = Ii[i1]*rn;
        float z2r = Ir[i2]*rn, z2i = Ii[i2]*rn;
        float z3r = Ir[i3]*rn, z3i = Ii[i3]*rn;
        float d02r = z0r - z2r, d02i = z0i - z2i;
        float d13r = z1r - z3r, d13i = z1i - z3i;
        P[0*540 + e2] = make_float2(z0r+z1r+z2r+z3r, z0i+z1i+z2i+z3i);
        P[2*540 + e2] = make_float2(z0r-z1r+z2r-z3r, z0i-z1i+z2i-z3i);
        P[1*540 + e2] = make_float2(d02r - sign*d13i, d02i + sign*d13r);
        P[3*540 + e2] = make_float2(d02r + sign*d13i, d02i - sign*d13r);
    }
    __syncthreads();
    int tl = t & 31, cl = t >> 5;   // tl<32, cl<4
    int pbase = (tl & 3) * 540;
    const float PH = 6.283185307179586f / 180.0f;
    float Tc[6], Ts[6], sc[6], ss[6];
    float O[6][3][2];
    #pragma unroll
    for (int q = 0; q < 6; q++) {
        int tq = tl + 32*q;
        float s_, c_; sincosf(sign * PH * (float)tq, &s_, &c_);
        sc[q] = c_; ss[q] = s_;
        Tc[q] = 1.f; Ts[q] = 0.f;
        #pragma unroll
        for (int j2 = 0; j2 < 3; j2++) { O[q][j2][0] = 0.f; O[q][j2][1] = 0.f; }
    }
    for (int v = 0; v < 45; v++) {
        float2 u[3];
        #pragma unroll
        for (int j2 = 0; j2 < 3; j2++) u[j2] = P[pbase + v*12 + cl + 4*j2];
        #pragma unroll
        for (int q = 0; q < 6; q++) {
            #pragma unroll
            for (int j2 = 0; j2 < 3; j2++) {
                O[q][j2][0] += u[j2].x*Tc[q] - u[j2].y*Ts[q];
                O[q][j2][1] += u[j2].x*Ts[q] + u[j2].y*Tc[q];
            }
            float nc = Tc[q]*sc[q] - Ts[q]*ss[q];
            float ns = Tc[q]*ss[q] + Ts[q]*sc[q];
            Tc[q] = nc; Ts[q] = ns;
        }
    }
    #pragma unroll
    for (int q = 0; q < 6; q++) {
        int tq = tl + 32*q;
        if (tq < HH) {
            #pragma unroll
            for (int j2 = 0; j2 < 3; j2++) {
                size_t idx = ((size_t)tq*FF + f)*CC + cy*12 + cl + 4*j2;
                Or_[idx] = O[q][j2][0];
                Oi_[idx] = O[q][j2][1];
            }
        }
    }
}

// ---------------- per-frequency block-diagonal complex matmul, full width ----------------
template<int LAYER>
__global__ __launch_bounds__(192) void bd_kernel(
        const float* __restrict__ Ir, const float* __restrict__ Ii,
        const float* __restrict__ wgt, const float* __restrict__ bias,
        const float* __restrict__ sf, const float* __restrict__ tf,
        float* __restrict__ Or_, float* __restrict__ Oi_) {
    int tile = blockIdx.x;
    int wb = blockIdx.y;     // 0..7
    int p0 = tile * 32;
    __shared__ float2 Ls[32*96];
    int t = threadIdx.x;
    for (int e2 = t; e2 < 32*96; e2 += 192) {
        int pp = e2 / 96, cc = e2 - pp*96;
        int p = p0 + pp; if (p >= NPOS) p = NPOS - 1;
        size_t idx = (size_t)p*CC + wb*96 + cc;
        Ls[e2] = make_float2(Ir[idx], Ii[idx]);
    }
    __syncthreads();
    int oc = (t >= 96) ? (t - 96) : t;
    int pg = (t >= 96) ? 1 : 0;
    const float* Wr = wgt + (size_t)wb * 9216;
    const float* Wi = wgt + (size_t)(8 + wb) * 9216;
    float br = bias[wb*96 + oc];
    float bi = bias[768 + wb*96 + oc];
    float ar[16], ai[16];
    #pragma unroll
    for (int i = 0; i < 16; i++) { ar[i] = br; ai[i] = bi; }
    for (int k = 0; k < 96; k++) {
        float wr = Wr[k*96 + oc];
        float wi = Wi[k*96 + oc];
        #pragma unroll
        for (int i = 0; i < 16; i++) {
            float2 y = Ls[(pg + 2*i)*96 + k];
            ar[i] += y.x*wr - y.y*wi;
            ai[i] += y.x*wi + y.y*wr;
        }
    }
    if (LAYER == 0) {
        float s  = sf[wb*96 + oc];
        float tt = tf[wb*96 + oc];
        #pragma unroll
        for (int i = 0; i < 16; i++) {
            int p = p0 + pg + 2*i;
            if (p < NPOS) {
                size_t idx = (size_t)p*CC + wb*96 + oc;
                Or_[idx] = fmaxf(ar[i]*s + tt, 0.0f);
                Oi_[idx] = fmaxf(ai[i]*s + tt, 0.0f);
            }
        }
    } else {
        #pragma unroll
        for (int i = 0; i < 16; i++) {
            int p = p0 + pg + 2*i;
            if (p < NPOS) {
                float vr = ar[i], vi = ai[i];
                vr = (vr > 0.01f) ? (vr - 0.01f) : ((vr < -0.01f) ? (vr + 0.01f) : 0.0f);
                vi = (vi > 0.01f) ? (vi - 0.01f) : ((vi < -0.01f) ? (vi + 0.01f) : 0.0f);
                size_t idx = (size_t)p*CC + wb*96 + oc;
                Or_[idx] = vr;
                Oi_[idx] = vi;
            }
        }
    }
}

// ---------------- inverse W-DFT matrices (bf16): Aw[0][w][f]=m_f cos(th f w), Aw[1]=-m_f sin ----------------
// w<384 (pad), f<96 (pad, zero for f>=91); m_f = rn*(f==0?1:2); exact angle via (f*w)%360
__global__ __launch_bounds__(256) void aw_kernel(__hip_bfloat16* __restrict__ Aw) {
    int idx = blockIdx.x*256 + threadIdx.x;   // 384*96 = 36864
    if (idx >= 384*96) return;
    int w = idx / 96, f = idx - (idx/96)*96;
    const float rn = 0.05270462766947299f;
    float m = (f == 0) ? rn : ((f < FF) ? 2.0f*rn : 0.0f);
    int p = (int)(((long long)f * w) % 360);
    float ang = 6.283185307179586f / 360.0f * (float)p;
    float s_, c_; sincosf(ang, &s_, &c_);
    Aw[idx]          = __float2bfloat16(m * c_);
    Aw[384*96 + idx] = __float2bfloat16(-m * s_);
}

// ---------------- inverse rDFT along W via MFMA, batched over h, in place ----------------
// out[h,w,c] = Ar[w,:]·Zr[h,:,c] + Ai[w,:]·Zi[h,:,c] + hout + x
// block: 256 thr, tile M=128(w) x N=128(c), K=96(f); grid (ntile 6, mtile 3, h 180)
__global__ __launch_bounds__(256) void iwdft_mfma_kernel(
        const float* __restrict__ Zr, const float* __restrict__ Zi,
        const __hip_bfloat16* __restrict__ Aw,
        const float* __restrict__ xin, float* __restrict__ hout) {
    __shared__ __align__(16) unsigned short As[128*104];   // [w][f], pad 104
    __shared__ __align__(16) unsigned short Bs[128*104];   // [c][f], pad 104
    int h = blockIdx.z;
    int mbase = blockIdx.y * 128;   // w
    int nbase = blockIdx.x * 128;   // c
    int tid = threadIdx.x;
    int l = tid & 63, wv = tid >> 6;
    int wm = wv & 1, wn = wv >> 1;
    int lm = l & 15, kq = l >> 4;
    f32x4 acc[4][4] = {};
    #pragma unroll
    for (int ph = 0; ph < 2; ph++) {
        __syncthreads();
        // stage A: 128 rows x 96 bf16 (12 x 16B chunks per row)
        for (int ch = tid; ch < 1536; ch += 256) {
            int row = ch / 12, co = (ch - row*12) * 8;
            u32x4 v = *(const u32x4*)(Aw + ((size_t)ph*384 + mbase + row)*96 + co);
            *(u32x4*)(As + row*104 + co) = v;
        }
        // stage B: Z[h][f][c] fp32 -> Bs[c][f] bf16 (transpose); f>=91 zeroed
        const float* Zp = ph ? Zi : Zr;
        for (int ch = tid; ch < 96*32; ch += 256) {
            int f = ch >> 5, cg = (ch & 31) * 4;
            float4 v;
            if (f < FF) v = *(const float4*)(Zp + ((size_t)h*FF + f)*CC + nbase + cg);
            else        v = make_float4(0.f, 0.f, 0.f, 0.f);
            __hip_bfloat16 b0 = __float2bfloat16(v.x);
            __hip_bfloat16 b1 = __float2bfloat16(v.y);
            __hip_bfloat16 b2 = __float2bfloat16(v.z);
            __hip_bfloat16 b3 = __float2bfloat16(v.w);
            Bs[(cg+0)*104 + f] = *reinterpret_cast<unsigned short*>(&b0);
            Bs[(cg+1)*104 + f] = *reinterpret_cast<unsigned short*>(&b1);
            Bs[(cg+2)*104 + f] = *reinterpret_cast<unsigned short*>(&b2);
            Bs[(cg+3)*104 + f] = *reinterpret_cast<unsigned short*>(&b3);
        }
        __syncthreads();
        #pragma unroll
        for (int ks = 0; ks < 3; ks++) {
            int kg = ks*32 + kq*8;
            bf16x8 af[4], bfv[4];
            #pragma unroll
            for (int i = 0; i < 4; i++) {
                af[i]  = *(const bf16x8*)(As + (wm*64 + i*16 + lm)*104 + kg);
                bfv[i] = *(const bf16x8*)(Bs + (wn*64 + i*16 + lm)*104 + kg);
            }
            #pragma unroll
            for (int i = 0; i < 4; i++)
                #pragma unroll
                for (int j = 0; j < 4; j++)
                    acc[i][j] = __builtin_amdgcn_mfma_f32_16x16x32_bf16(af[i], bfv[j], acc[i][j], 0, 0, 0);
        }
    }
    int r0 = kq * 4;
    #pragma unroll
    for (int j = 0; j < 4; j++) {
        int col = nbase + wn*64 + j*16 + lm;
        #pragma unroll
        for (int i = 0; i < 4; i++) {
            int rowb = wm*64 + i*16 + r0;
            #pragma unroll
            for (int r = 0; r < 4; r++) {
                int wp = mbase + rowb + r;
                if (wp < WW) {
                    size_t idx = ((size_t)h*WW + wp)*CC + col;
                    hout[idx] = acc[i][j][r] + hout[idx] + xin[idx];
                }
            }
        }
    }
}

// ---------------- tiled weight transpose + bf16 convert ----------------
__global__ __launch_bounds__(256) void transpose_bf16_kernel(const float* __restrict__ src,
        __hip_bfloat16* __restrict__ dst, int K, int N) {
    __shared__ float tile[32][33];
    int n0 = blockIdx.x * 32;
    int k0 = blockIdx.y * 32;
    int tx = threadIdx.x & 31;
    int ty = threadIdx.x >> 5;
    #pragma unroll
    for (int r = 0; r < 32; r += 8) {
        tile[ty + r][tx] = src[(size_t)(k0 + ty + r) * N + n0 + tx];
    }
    __syncthreads();
    #pragma unroll
    for (int r = 0; r < 32; r += 8) {
        dst[(size_t)(n0 + ty + r) * K + k0 + tx] = __float2bfloat16(tile[tx][ty + r]);
    }
}

// ---------------- bf16 MFMA GEMM, 128x128 tile, BK=64, 4 waves ----------------
// global_load_lds with XOR-swizzled source (slot = k_chunk ^ (row&7)) -> conflict-free ds_read
// MODE 0: hmid = bf16(gelu((A@B + bias)*s + t)), LDS-staged coalesced store
// MODE 1: out = A@B + bias + resid (fp32, direct store)
template<int MODE>
__global__ __launch_bounds__(256) void gemm_kernel(
        const __hip_bfloat16* __restrict__ A,
        const __hip_bfloat16* __restrict__ Bt,
        int M, int K, int N,
        const float* __restrict__ bias,
        const float* __restrict__ sv, const float* __restrict__ tv,
        const float* resid, void* out) {
    __shared__ __align__(16) unsigned short SH[128*136];  // 34.8KB; staging uses first 32KB
    unsigned short* As = SH;              // [128][64]
    unsigned short* Bs = SH + 128*64;     // [128][64]
    int tid = threadIdx.x;
    int nbase = blockIdx.x * 128;
    int mbase = blockIdx.y * 128;
    int l = tid & 63, wv = tid >> 6;
    int wm = wv & 1, wn = wv >> 1;
    int lm = l & 15;
    int kq = l >> 4;                      // 0..3
    f32x4 acc[4][4] = {};
    int nkt = K >> 6;                     // BK=64
    for (int kt = 0; kt < nkt; kt++) {
        int kb = kt << 6;
        __syncthreads();
        #pragma unroll
        for (int i = 0; i < 4; i++) {
            int ch = i*256 + tid;         // 0..1023 ; LDS dest = ch*16B (lane-linear)
            int row = ch >> 3;
            int sl = ch & 7;
            int kg = (sl ^ (row & 7)) << 3;   // swizzled global k-offset (elements)
            int am = mbase + row; if (am >= M) am = M - 1;
            const __hip_bfloat16* ga = A  + (size_t)am * K + kb + kg;
            const __hip_bfloat16* gb = Bt + (size_t)(nbase + row) * K + kb + kg;
            __builtin_amdgcn_global_load_lds(
                (const __attribute__((address_space(1))) void*)(unsigned long long)(uintptr_t)ga,
                (__attribute__((address_space(3))) void*)(unsigned long long)(uintptr_t)(As + ch*8),
                16, 0, 0);
            __builtin_amdgcn_global_load_lds(
                (const __attribute__((address_space(1))) void*)(unsigned long long)(uintptr_t)gb,
                (__attribute__((address_space(3))) void*)(unsigned long long)(uintptr_t)(Bs + ch*8),
                16, 0, 0);
        }
        __syncthreads();
        #pragma unroll
        for (int kk = 0; kk < 2; kk++) {
            bf16x8 af[4], bfv[4];
            #pragma unroll
            for (int i = 0; i < 4; i++) {
                int ra = wm*64 + i*16 + lm;
                af[i]  = *(const bf16x8*)(As + ra*64 + ((((kk<<2)+kq) ^ (ra&7))<<3));
                int rb = wn*64 + i*16 + lm;
                bfv[i] = *(const bf16x8*)(Bs + rb*64 + ((((kk<<2)+kq) ^ (rb&7))<<3));
            }
            #pragma unroll
            for (int i = 0; i < 4; i++)
                #pragma unroll
                for (int j = 0; j < 4; j++)
                    acc[i][j] = __builtin_amdgcn_mfma_f32_16x16x32_bf16(af[i], bfv[j], acc[i][j], 0, 0, 0);
        }
    }
    int r0 = kq * 4;
    if (MODE == 0) {
        __syncthreads();   // staging LDS now dead; reuse for epilogue tile [128][136]
        #pragma unroll
        for (int j = 0; j < 4; j++) {
            int col = wn*64 + j*16 + lm;
            int gcol = nbase + col;
            float bb = bias[gcol];
            float ss = sv[gcol], tt = tv[gcol];
            #pragma unroll
            for (int i = 0; i < 4; i++) {
                int rowb = wm*64 + i*16 + r0;
                #pragma unroll
                for (int r = 0; r < 4; r++) {
                    float v = gelu_f((acc[i][j][r] + bb)*ss + tt);
                    __hip_bfloat16 hb = __float2bfloat16(v);
                    SH[(rowb + r)*136 + col] = *reinterpret_cast<unsigned short*>(&hb);
                }
            }
        }
        __syncthreads();
        #pragma unroll
        for (int it = 0; it < 8; it++) {
            int chunk = it*256 + tid;     // 0..2047 ; 16 chunks of 8 cols per row
            int row = chunk >> 4;
            int c8 = chunk & 15;
            int mr = mbase + row;
            if (mr < M) {
                *(u32x4*)((__hip_bfloat16*)out + (size_t)mr*N + nbase + c8*8) =
                    *(const u32x4*)(SH + row*136 + c8*8);
            }
        }
    } else {
        #pragma unroll
        for (int j = 0; j < 4; j++) {
            int col = nbase + wn*64 + j*16 + lm;
            float bb = bias[col];
            #pragma unroll
            for (int i = 0; i < 4; i++) {
                int rowb = mbase + wm*64 + i*16 + r0;
                #pragma unroll
                for (int r = 0; r < 4; r++) {
                    int row = rowb + r;
                    if (row < M) {
                        float v = acc[i][j][r] + bb;
                        ((float*)out)[(size_t)row*N + col] = v + resid[(size_t)row*N + col];
                    }
                }
            }
        }
    }
}

extern "C" void kernel_launch(void* const* d_in, const int* in_sizes, int n_in,
                              void* d_out, int out_size, void* d_ws, size_t ws_size,
                              hipStream_t stream) {
    const float* x     = (const float*)d_in[0];
    const float* emb   = (const float*)d_in[1];
    const float* n1w   = (const float*)d_in[2];
    const float* n1b   = (const float*)d_in[3];
    const float* n2w   = (const float*)d_in[4];
    const float* n2b   = (const float*)d_in[5];
    const float* w1    = (const float*)d_in[6];
    const float* b1    = (const float*)d_in[7];
    const float* w2    = (const float*)d_in[8];
    const float* b2    = (const float*)d_in[9];
    const float* fs_w0 = (const float*)d_in[10];
    const float* fs_b0 = (const float*)d_in[11];
    const float* fs_w1 = (const float*)d_in[12];
    const float* fs_b1 = (const float*)d_in[13];
    const float* fc1w  = (const float*)d_in[14];
    const float* fc1b  = (const float*)d_in[15];
    const float* fc2w  = (const float*)d_in[16];
    const float* fc2b  = (const float*)d_in[17];
    const float* ms_w0 = (const float*)d_in[18];
    const float* ms_b0 = (const float*)d_in[19];
    const float* ms_w1 = (const float*)d_in[20];
    const float* ms_b1 = (const float*)d_in[21];
    float* out = (float*)d_out;
    (void)in_sizes; (void)n_in; (void)out_size; (void)ws_size;

    char* wsb = (char*)d_ws;
    size_t off = 0;
    auto alloc = [&](size_t nbytes) -> void* {
        void* p = wsb + off;
        off += (nbytes + 255) & ~(size_t)255;
        return p;
    };
    float* s_f  = (float*)alloc(768*4);
    float* t_f  = (float*)alloc(768*4);
    float* s_m  = (float*)alloc(3072*4);
    float* t_m  = (float*)alloc(3072*4);
    float* midf = (float*)alloc(1536*4);
    float* midm = (float*)alloc(6144*4);
    __hip_bfloat16* Aw = (__hip_bfloat16*)alloc((size_t)2*384*96*2);
    float* Yr   = (float*)alloc((size_t)NPOS*CC*4);
    float* Yi   = (float*)alloc((size_t)NPOS*CC*4);
    float* Zr   = (float*)alloc((size_t)NPOS*CC*4);
    float* Zi   = (float*)alloc((size_t)NPOS*CC*4);
    __hip_bfloat16* wT1  = (__hip_bfloat16*)alloc((size_t)CC*LAT*2);
    __hip_bfloat16* wT2  = (__hip_bfloat16*)alloc((size_t)CC*LAT*2);
    __hip_bfloat16* h2   = (__hip_bfloat16*)alloc((size_t)NROW*CC*2);
    __hip_bfloat16* hmid = (__hip_bfloat16*)alloc((size_t)NROW*LAT*2);

    // 1. modulation scale/shift vectors + idft matrix
    mod_a_kernel<<<30, 256, 0, stream>>>(emb, fs_w0, fs_b0, ms_w0, ms_b0, midf, midm);
    mod_b_kernel<<<120, 512, 0, stream>>>(midf, midm, fs_w1, fs_b1, ms_w1, ms_b1,
                                          s_f, t_f, s_m, t_m);
    aw_kernel<<<144, 256, 0, stream>>>(Aw);
    // 2. LN1 -> d_out (h_ln lives in d_out)
    ln_f32_kernel<<<NROW/4, 256, 0, stream>>>(x, n1w, n1b, out);
    // 3. weight convert+transpose
    transpose_bf16_kernel<<<dim3(LAT/32, CC/32), 256, 0, stream>>>(fc1w, wT1, 768, 3072);
    transpose_bf16_kernel<<<dim3(CC/32, LAT/32), 256, 0, stream>>>(fc2w, wT2, 3072, 768);

    // 4. filter path, full width (6 dispatches)
    wdft_kernel<<<dim3(48, 180), 256, 0, stream>>>(out, Yr, Yi);
    hfft_kernel<<<dim3(91, 64), 128, 0, stream>>>(Yr, Yi, Zr, Zi, -1.0f);
    bd_kernel<0><<<dim3(512, 8), 192, 0, stream>>>(Zr, Zi, w1, b1, s_f, t_f, Yr, Yi);
    bd_kernel<1><<<dim3(512, 8), 192, 0, stream>>>(Yr, Yi, w2, b2, nullptr, nullptr, Zr, Zi);
    hfft_kernel<<<dim3(91, 64), 128, 0, stream>>>(Zr, Zi, Yr, Yi, 1.0f);
    // inverse W-DFT via MFMA, in place: out = idft(Y) + out(h_ln) + x
    iwdft_mfma_kernel<<<dim3(6, 3, 180), 256, 0, stream>>>(Yr, Yi, Aw, x, out);

    // 5. MLP path, single pass (d_out holds h; update in place)
    ln_bf16_kernel<<<NROW/4, 256, 0, stream>>>(out, n2w, n2b, h2);
    gemm_kernel<0><<<dim3(LAT/128, (NROW+127)/128), 256, 0, stream>>>(
        h2, wT1, NROW, CC, LAT, fc1b, s_m, t_m, nullptr, hmid);
    gemm_kernel<1><<<dim3(CC/128, (NROW+127)/128), 256, 0, stream>>>(
        hmid, wT2, NROW, LAT, CC, fc2b, nullptr, nullptr, out, out);
}

// Round 8
// 2453.053 us; speedup vs baseline: 2.6198x; 1.0945x over previous
//
#include <hip/hip_runtime.h>
#include <hip/hip_bf16.h>
#include <math.h>

// Problem constants
#define HH 180
#define WW 360
#define CC 768
#define FF 91          // kept W-frequencies (km = 91)
#define NPOS (HH*FF)   // 16380 frequency positions
#define NROW (HH*WW)   // 64800 spatial rows
#define LAT 3072

typedef __attribute__((ext_vector_type(8))) short bf16x8;
typedef __attribute__((ext_vector_type(4))) float f32x4;
typedef __attribute__((ext_vector_type(4))) unsigned int u32x4;

__device__ __forceinline__ float gelu_f(float x) {
    return 0.5f * x * (1.0f + erff(x * 0.7071067811865476f));
}

// ---------------- modulation stage A ----------------
__global__ __launch_bounds__(256) void mod_a_kernel(
        const float* __restrict__ e,
        const float* __restrict__ fs_w0, const float* __restrict__ fs_b0,
        const float* __restrict__ ms_w0, const float* __restrict__ ms_b0,
        float* __restrict__ mid_f, float* __restrict__ mid_m) {
    __shared__ float es[64];
    int t = threadIdx.x;
    if (t < 64) es[t] = e[t];
    __syncthreads();
    int j = blockIdx.x * 256 + t;
    if (j < 1536) {
        float a = fs_b0[j];
        #pragma unroll 8
        for (int k = 0; k < 64; k++) a += es[k] * fs_w0[k*1536 + j];
        mid_f[j] = gelu_f(a);
    } else {
        int jm = j - 1536;
        float a = ms_b0[jm];
        #pragma unroll 8
        for (int k = 0; k < 64; k++) a += es[k] * ms_w0[k*6144 + jm];
        mid_m[jm] = gelu_f(a);
    }
}

// ---------------- modulation stage B ----------------
__global__ __launch_bounds__(512) void mod_b_kernel(
        const float* __restrict__ mid_f, const float* __restrict__ mid_m,
        const float* __restrict__ fs_w1, const float* __restrict__ fs_b1,
        const float* __restrict__ ms_w1, const float* __restrict__ ms_b1,
        float* __restrict__ s_f, float* __restrict__ t_f,
        float* __restrict__ s_m, float* __restrict__ t_m) {
    __shared__ float red[8*64];
    int t = threadIdx.x;
    int g = t >> 6;
    int jl = t & 63;
    int blk = blockIdx.x;
    if (blk < 24) {
        int jo = blk*64 + jl;
        const int N = 1536, NQ = 192;
        float a = 0.f;
        const float* w = fs_w1 + (size_t)(g*NQ)*N + jo;
        for (int j = 0; j < NQ; j++) a += mid_f[g*NQ + j] * w[(size_t)j*N];
        red[t] = a;
        __syncthreads();
        if (t < 64) {
            float s = fs_b1[jo];
            #pragma unroll
            for (int q = 0; q < 8; q++) s += red[q*64 + jl];
            if (jo < 768) s_f[jo] = 1.0f + s;
            else          t_f[jo - 768] = s;
        }
    } else {
        int jo = (blk - 24)*64 + jl;
        const int N = 6144, NQ = 768;
        float a = 0.f;
        const float* w = ms_w1 + (size_t)(g*NQ)*N + jo;
        for (int j = 0; j < NQ; j++) a += mid_m[g*NQ + j] * w[(size_t)j*N];
        red[t] = a;
        __syncthreads();
        if (t < 64) {
            float s = ms_b1[jo];
            #pragma unroll
            for (int q = 0; q < 8; q++) s += red[q*64 + jl];
            if (jo < 3072) s_m[jo] = 1.0f + s;
            else           t_m[jo - 3072] = s;
        }
    }
}

// ---------------- LayerNorm fp32 out ----------------
__global__ __launch_bounds__(256) void ln_f32_kernel(const float* __restrict__ in,
        const float* __restrict__ w, const float* __restrict__ b,
        float* __restrict__ out) {
    int row = blockIdx.x*4 + (threadIdx.x >> 6);
    int l = threadIdx.x & 63;
    const float* p = in + (size_t)row*CC;
    float v[12]; float s = 0.f, sq = 0.f;
    #pragma unroll
    for (int i = 0; i < 12; i++) { float tv = p[l + 64*i]; v[i] = tv; s += tv; sq += tv*tv; }
    #pragma unroll
    for (int m = 1; m < 64; m <<= 1) { s += __shfl_xor(s, m); sq += __shfl_xor(sq, m); }
    float mean = s * (1.0f/768.0f);
    float var  = sq * (1.0f/768.0f) - mean*mean;
    float rstd = rsqrtf(var + 1e-5f);
    float* o = out + (size_t)row*CC;
    #pragma unroll
    for (int i = 0; i < 12; i++) { int c = l + 64*i; o[c] = (v[i]-mean)*rstd*w[c] + b[c]; }
}

// ---------------- LayerNorm bf16 out ----------------
__global__ __launch_bounds__(256) void ln_bf16_kernel(const float* __restrict__ in,
        const float* __restrict__ w, const float* __restrict__ b,
        __hip_bfloat16* __restrict__ out) {
    int row = blockIdx.x*4 + (threadIdx.x >> 6);
    int l = threadIdx.x & 63;
    const float* p = in + (size_t)row*CC;
    float v[12]; float s = 0.f, sq = 0.f;
    #pragma unroll
    for (int i = 0; i < 12; i++) { float tv = p[l + 64*i]; v[i] = tv; s += tv; sq += tv*tv; }
    #pragma unroll
    for (int m = 1; m < 64; m <<= 1) { s += __shfl_xor(s, m); sq += __shfl_xor(sq, m); }
    float mean = s * (1.0f/768.0f);
    float var  = sq * (1.0f/768.0f) - mean*mean;
    float rstd = rsqrtf(var + 1e-5f);
    __hip_bfloat16* o = out + (size_t)row*CC;
    #pragma unroll
    for (int i = 0; i < 12; i++) { int c = l + 64*i; o[c] = __float2bfloat16((v[i]-mean)*rstd*w[c] + b[c]); }
}

// ---------------- twiddle matrices ----------------
// Ew[192][384]: rows 0-95: cos(th f w)*rn (f<91,w<360 else 0); rows 96-191: -sin*rn
__global__ __launch_bounds__(256) void ew_kernel(__hip_bfloat16* __restrict__ Ew) {
    int idx = blockIdx.x*256 + threadIdx.x;
    if (idx >= 192*384) return;
    int r = idx / 384, w = idx - (idx/384)*384;
    int f = (r < 96) ? r : r - 96;
    const float rn = 0.05270462766947299f;  // 1/sqrt(360)
    float v = 0.f;
    if (f < FF && w < WW) {
        int p = (f * w) % 360;
        float ang = 6.283185307179586f/360.0f * (float)p;
        float s_, c_; sincosf(ang, &s_, &c_);
        v = (r < 96) ? c_*rn : -s_*rn;
    }
    Ew[idx] = __float2bfloat16(v);
}

// Eh[sig][plane][192][384]: E=e^{s i ph t h}*rnh; plane0(Or)=[C | -sS]; plane1(Oi)=[sS | C]
// sig 0 -> s=-1 (fwd), sig 1 -> s=+1 (inv); k<192: h=k (Ir cols), k>=192: h=k-192 (Ii cols)
__global__ __launch_bounds__(256) void eh_kernel(__hip_bfloat16* __restrict__ Eh) {
    int idx = blockIdx.x*256 + threadIdx.x;
    if (idx >= 4*192*384) return;
    int sp = idx / (192*384);
    int rem = idx - sp*(192*384);
    int t = rem / 384, k = rem - (rem/384)*384;
    int sig = sp >> 1, plane = sp & 1;
    float s = (sig == 0) ? -1.f : 1.f;
    int h = (k < 192) ? k : k - 192;
    const float rnh = 0.07453559924999299f;  // 1/sqrt(180)
    float v = 0.f;
    if (t < HH && h < HH) {
        int p = (t * h) % 180;
        float ang = 6.283185307179586f/180.0f * (float)p;
        float s_, c_; sincosf(ang, &s_, &c_);
        float C = c_*rnh, S = s_*rnh;
        if (plane == 0) v = (k < 192) ? C : -s*S;
        else            v = (k < 192) ? s*S : C;
    }
    Eh[idx] = __float2bfloat16(v);
}

// ---------------- MFMA transform: C[192 rows][128 c] = A[192][384] @ B[384][c] ----------------
// MODE 0 (wdft): batch=h; B rows k=w<360 from B0=hln[h][w][c]; out rows<96 -> Yr[h][f][c], >=96 -> Yi
// MODE 1 (hfft): batch=f; B rows k<192 -> B0=Ir[h=k][f][c] (h<180), k>=192 -> B1=Ii; plane=blockIdx.y
//                selects A plane and output (0->O0, 1->O1); out [t][f][c]
template<int MODE>
__global__ __launch_bounds__(256) void transform_mfma(
        const __hip_bfloat16* __restrict__ Amat,
        const float* __restrict__ B0, const float* __restrict__ B1,
        float* __restrict__ O0, float* __restrict__ O1) {
    __shared__ __align__(16) unsigned short As[192*72];
    __shared__ __align__(16) unsigned short Bs[128*72];
    int nbase = blockIdx.x * 128;
    int bat = blockIdx.z;
    int tid = threadIdx.x;
    int l = tid & 63, wv = tid >> 6;
    int wm = wv & 1, wn = wv >> 1;
    int lm = l & 15, kq = l >> 4;
    const __hip_bfloat16* Ab = Amat + (MODE == 1 ? (size_t)blockIdx.y*192*384 : 0);
    size_t bRowStride = (MODE == 0) ? (size_t)CC : (size_t)FF*CC;
    size_t bBase      = (MODE == 0) ? (size_t)bat*WW*CC : (size_t)bat*CC;
    f32x4 acc[6][4] = {};
    for (int kt = 0; kt < 6; kt++) {
        int kb = kt*64;
        __syncthreads();
        // stage A [192][64] bf16 (L2-hot)
        #pragma unroll
        for (int it = 0; it < 6; it++) {
            int ch = it*256 + tid;           // 1536 chunks of 16B
            int row = ch >> 3, co = (ch & 7) * 8;
            u32x4 v = *(const u32x4*)(Ab + (size_t)row*384 + kb + co);
            *(u32x4*)(As + row*72 + co) = v;
        }
        // stage B [64 k][128 c] fp32 -> Bs[c][k] bf16 (transpose)
        #pragma unroll
        for (int it = 0; it < 8; it++) {
            int idx = it*256 + tid;          // 2048 float4 quads
            int row = idx >> 5;              // k-local 0..63
            int cq = (idx & 31) * 4;
            int k = kb + row;
            float4 v = make_float4(0.f, 0.f, 0.f, 0.f);
            if (MODE == 0) {
                if (k < WW) v = *(const float4*)(B0 + bBase + (size_t)k*bRowStride + nbase + cq);
            } else {
                if (k < 192) { if (k < HH) v = *(const float4*)(B0 + bBase + (size_t)k*bRowStride + nbase + cq); }
                else { int h2 = k - 192; if (h2 < HH) v = *(const float4*)(B1 + bBase + (size_t)h2*bRowStride + nbase + cq); }
            }
            __hip_bfloat16 b0 = __float2bfloat16(v.x);
            __hip_bfloat16 b1 = __float2bfloat16(v.y);
            __hip_bfloat16 b2 = __float2bfloat16(v.z);
            __hip_bfloat16 b3 = __float2bfloat16(v.w);
            Bs[(cq+0)*72 + row] = *reinterpret_cast<unsigned short*>(&b0);
            Bs[(cq+1)*72 + row] = *reinterpret_cast<unsigned short*>(&b1);
            Bs[(cq+2)*72 + row] = *reinterpret_cast<unsigned short*>(&b2);
            Bs[(cq+3)*72 + row] = *reinterpret_cast<unsigned short*>(&b3);
        }
        __syncthreads();
        #pragma unroll
        for (int kk = 0; kk < 2; kk++) {
            int kg = kk*32 + kq*8;
            bf16x8 af[6], bfv[4];
            #pragma unroll
            for (int i = 0; i < 6; i++)
                af[i] = *(const bf16x8*)(As + (wm*96 + i*16 + lm)*72 + kg);
            #pragma unroll
            for (int j = 0; j < 4; j++)
                bfv[j] = *(const bf16x8*)(Bs + (wn*64 + j*16 + lm)*72 + kg);
            #pragma unroll
            for (int i = 0; i < 6; i++)
                #pragma unroll
                for (int j = 0; j < 4; j++)
                    acc[i][j] = __builtin_amdgcn_mfma_f32_16x16x32_bf16(af[i], bfv[j], acc[i][j], 0, 0, 0);
        }
    }
    int r0 = kq * 4;
    #pragma unroll
    for (int j = 0; j < 4; j++) {
        int col = nbase + wn*64 + j*16 + lm;
        #pragma unroll
        for (int i = 0; i < 6; i++) {
            #pragma unroll
            for (int r = 0; r < 4; r++) {
                int row = wm*96 + i*16 + r0 + r;
                float v = acc[i][j][r];
                if (MODE == 0) {
                    if (row < 96) {
                        if (row < FF) O0[(size_t)bat*FF*CC + (size_t)row*CC + col] = v;
                    } else {
                        int f2 = row - 96;
                        if (f2 < FF) O1[(size_t)bat*FF*CC + (size_t)f2*CC + col] = v;
                    }
                } else {
                    if (row < HH) {
                        float* Op = blockIdx.y ? O1 : O0;
                        Op[(size_t)row*FF*CC + (size_t)bat*CC + col] = v;
                    }
                }
            }
        }
    }
}

// ---------------- per-frequency block-diagonal complex matmul, full width ----------------
template<int LAYER>
__global__ __launch_bounds__(192) void bd_kernel(
        const float* __restrict__ Ir, const float* __restrict__ Ii,
        const float* __restrict__ wgt, const float* __restrict__ bias,
        const float* __restrict__ sf, const float* __restrict__ tf,
        float* __restrict__ Or_, float* __restrict__ Oi_) {
    int tile = blockIdx.x;
    int wb = blockIdx.y;     // 0..7
    int p0 = tile * 32;
    __shared__ float2 Ls[32*96];
    int t = threadIdx.x;
    for (int e2 = t; e2 < 32*96; e2 += 192) {
        int pp = e2 / 96, cc = e2 - pp*96;
        int p = p0 + pp; if (p >= NPOS) p = NPOS - 1;
        size_t idx = (size_t)p*CC + wb*96 + cc;
        Ls[e2] = make_float2(Ir[idx], Ii[idx]);
    }
    __syncthreads();
    int oc = (t >= 96) ? (t - 96) : t;
    int pg = (t >= 96) ? 1 : 0;
    const float* Wr = wgt + (size_t)wb * 9216;
    const float* Wi = wgt + (size_t)(8 + wb) * 9216;
    float br = bias[wb*96 + oc];
    float bi = bias[768 + wb*96 + oc];
    float ar[16], ai[16];
    #pragma unroll
    for (int i = 0; i < 16; i++) { ar[i] = br; ai[i] = bi; }
    for (int k = 0; k < 96; k++) {
        float wr = Wr[k*96 + oc];
        float wi = Wi[k*96 + oc];
        #pragma unroll
        for (int i = 0; i < 16; i++) {
            float2 y = Ls[(pg + 2*i)*96 + k];
            ar[i] += y.x*wr - y.y*wi;
            ai[i] += y.x*wi + y.y*wr;
        }
    }
    if (LAYER == 0) {
        float s  = sf[wb*96 + oc];
        float tt = tf[wb*96 + oc];
        #pragma unroll
        for (int i = 0; i < 16; i++) {
            int p = p0 + pg + 2*i;
            if (p < NPOS) {
                size_t idx = (size_t)p*CC + wb*96 + oc;
                Or_[idx] = fmaxf(ar[i]*s + tt, 0.0f);
                Oi_[idx] = fmaxf(ai[i]*s + tt, 0.0f);
            }
        }
    } else {
        #pragma unroll
        for (int i = 0; i < 16; i++) {
            int p = p0 + pg + 2*i;
            if (p < NPOS) {
                float vr = ar[i], vi = ai[i];
                vr = (vr > 0.01f) ? (vr - 0.01f) : ((vr < -0.01f) ? (vr + 0.01f) : 0.0f);
                vi = (vi > 0.01f) ? (vi - 0.01f) : ((vi < -0.01f) ? (vi + 0.01f) : 0.0f);
                size_t idx = (size_t)p*CC + wb*96 + oc;
                Or_[idx] = vr;
                Oi_[idx] = vi;
            }
        }
    }
}

// ---------------- inverse W-DFT matrices (bf16): Aw[0][w][f]=m_f cos(th f w), Aw[1]=-m_f sin ----------------
__global__ __launch_bounds__(256) void aw_kernel(__hip_bfloat16* __restrict__ Aw) {
    int idx = blockIdx.x*256 + threadIdx.x;   // 384*96 = 36864
    if (idx >= 384*96) return;
    int w = idx / 96, f = idx - (idx/96)*96;
    const float rn = 0.05270462766947299f;
    float m = (f == 0) ? rn : ((f < FF) ? 2.0f*rn : 0.0f);
    int p = (int)(((long long)f * w) % 360);
    float ang = 6.283185307179586f / 360.0f * (float)p;
    float s_, c_; sincosf(ang, &s_, &c_);
    Aw[idx]          = __float2bfloat16(m * c_);
    Aw[384*96 + idx] = __float2bfloat16(-m * s_);
}

// ---------------- inverse rDFT along W via MFMA, batched over h, in place ----------------
__global__ __launch_bounds__(256) void iwdft_mfma_kernel(
        const float* __restrict__ Zr, const float* __restrict__ Zi,
        const __hip_bfloat16* __restrict__ Aw,
        const float* __restrict__ xin, float* __restrict__ hout) {
    __shared__ __align__(16) unsigned short As[128*104];   // [w][f], pad 104
    __shared__ __align__(16) unsigned short Bs[128*104];   // [c][f], pad 104
    int h = blockIdx.z;
    int mbase = blockIdx.y * 128;   // w
    int nbase = blockIdx.x * 128;   // c
    int tid = threadIdx.x;
    int l = tid & 63, wv = tid >> 6;
    int wm = wv & 1, wn = wv >> 1;
    int lm = l & 15, kq = l >> 4;
    f32x4 acc[4][4] = {};
    #pragma unroll
    for (int ph = 0; ph < 2; ph++) {
        __syncthreads();
        for (int ch = tid; ch < 1536; ch += 256) {
            int row = ch / 12, co = (ch - row*12) * 8;
            u32x4 v = *(const u32x4*)(Aw + ((size_t)ph*384 + mbase + row)*96 + co);
            *(u32x4*)(As + row*104 + co) = v;
        }
        const float* Zp = ph ? Zi : Zr;
        for (int ch = tid; ch < 96*32; ch += 256) {
            int f = ch >> 5, cg = (ch & 31) * 4;
            float4 v;
            if (f < FF) v = *(const float4*)(Zp + ((size_t)h*FF + f)*CC + nbase + cg);
            else        v = make_float4(0.f, 0.f, 0.f, 0.f);
            __hip_bfloat16 b0 = __float2bfloat16(v.x);
            __hip_bfloat16 b1 = __float2bfloat16(v.y);
            __hip_bfloat16 b2 = __float2bfloat16(v.z);
            __hip_bfloat16 b3 = __float2bfloat16(v.w);
            Bs[(cg+0)*104 + f] = *reinterpret_cast<unsigned short*>(&b0);
            Bs[(cg+1)*104 + f] = *reinterpret_cast<unsigned short*>(&b1);
            Bs[(cg+2)*104 + f] = *reinterpret_cast<unsigned short*>(&b2);
            Bs[(cg+3)*104 + f] = *reinterpret_cast<unsigned short*>(&b3);
        }
        __syncthreads();
        #pragma unroll
        for (int ks = 0; ks < 3; ks++) {
            int kg = ks*32 + kq*8;
            bf16x8 af[4], bfv[4];
            #pragma unroll
            for (int i = 0; i < 4; i++) {
                af[i]  = *(const bf16x8*)(As + (wm*64 + i*16 + lm)*104 + kg);
                bfv[i] = *(const bf16x8*)(Bs + (wn*64 + i*16 + lm)*104 + kg);
            }
            #pragma unroll
            for (int i = 0; i < 4; i++)
                #pragma unroll
                for (int j = 0; j < 4; j++)
                    acc[i][j] = __builtin_amdgcn_mfma_f32_16x16x32_bf16(af[i], bfv[j], acc[i][j], 0, 0, 0);
        }
    }
    int r0 = kq * 4;
    #pragma unroll
    for (int j = 0; j < 4; j++) {
        int col = nbase + wn*64 + j*16 + lm;
        #pragma unroll
        for (int i = 0; i < 4; i++) {
            int rowb = wm*64 + i*16 + r0;
            #pragma unroll
            for (int r = 0; r < 4; r++) {
                int wp = mbase + rowb + r;
                if (wp < WW) {
                    size_t idx = ((size_t)h*WW + wp)*CC + col;
                    hout[idx] = acc[i][j][r] + hout[idx] + xin[idx];
                }
            }
        }
    }
}

// ---------------- tiled weight transpose + bf16 convert ----------------
__global__ __launch_bounds__(256) void transpose_bf16_kernel(const float* __restrict__ src,
        __hip_bfloat16* __restrict__ dst, int K, int N) {
    __shared__ float tile[32][33];
    int n0 = blockIdx.x * 32;
    int k0 = blockIdx.y * 32;
    int tx = threadIdx.x & 31;
    int ty = threadIdx.x >> 5;
    #pragma unroll
    for (int r = 0; r < 32; r += 8) {
        tile[ty + r][tx] = src[(size_t)(k0 + ty + r) * N + n0 + tx];
    }
    __syncthreads();
    #pragma unroll
    for (int r = 0; r < 32; r += 8) {
        dst[(size_t)(n0 + ty + r) * K + k0 + tx] = __float2bfloat16(tile[tx][ty + r]);
    }
}

// ---------------- bf16 MFMA GEMM, 128x128 tile, BK=64, 4 waves ----------------
template<int MODE>
__global__ __launch_bounds__(256) void gemm_kernel(
        const __hip_bfloat16* __restrict__ A,
        const __hip_bfloat16* __restrict__ Bt,
        int M, int K, int N,
        const float* __restrict__ bias,
        const float* __restrict__ sv, const float* __restrict__ tv,
        const float* resid, void* out) {
    __shared__ __align__(16) unsigned short SH[128*136];
    unsigned short* As = SH;              // [128][64]
    unsigned short* Bs = SH + 128*64;     // [128][64]
    int tid = threadIdx.x;
    int nbase = blockIdx.x * 128;
    int mbase = blockIdx.y * 128;
    int l = tid & 63, wv = tid >> 6;
    int wm = wv & 1, wn = wv >> 1;
    int lm = l & 15;
    int kq = l >> 4;
    f32x4 acc[4][4] = {};
    int nkt = K >> 6;
    for (int kt = 0; kt < nkt; kt++) {
        int kb = kt << 6;
        __syncthreads();
        #pragma unroll
        for (int i = 0; i < 4; i++) {
            int ch = i*256 + tid;
            int row = ch >> 3;
            int sl = ch & 7;
            int kg = (sl ^ (row & 7)) << 3;
            int am = mbase + row; if (am >= M) am = M - 1;
            const __hip_bfloat16* ga = A  + (size_t)am * K + kb + kg;
            const __hip_bfloat16* gb = Bt + (size_t)(nbase + row) * K + kb + kg;
            __builtin_amdgcn_global_load_lds(
                (const __attribute__((address_space(1))) void*)(unsigned long long)(uintptr_t)ga,
                (__attribute__((address_space(3))) void*)(unsigned long long)(uintptr_t)(As + ch*8),
                16, 0, 0);
            __builtin_amdgcn_global_load_lds(
                (const __attribute__((address_space(1))) void*)(unsigned long long)(uintptr_t)gb,
                (__attribute__((address_space(3))) void*)(unsigned long long)(uintptr_t)(Bs + ch*8),
                16, 0, 0);
        }
        __syncthreads();
        #pragma unroll
        for (int kk = 0; kk < 2; kk++) {
            bf16x8 af[4], bfv[4];
            #pragma unroll
            for (int i = 0; i < 4; i++) {
                int ra = wm*64 + i*16 + lm;
                af[i]  = *(const bf16x8*)(As + ra*64 + ((((kk<<2)+kq) ^ (ra&7))<<3));
                int rb = wn*64 + i*16 + lm;
                bfv[i] = *(const bf16x8*)(Bs + rb*64 + ((((kk<<2)+kq) ^ (rb&7))<<3));
            }
            #pragma unroll
            for (int i = 0; i < 4; i++)
                #pragma unroll
                for (int j = 0; j < 4; j++)
                    acc[i][j] = __builtin_amdgcn_mfma_f32_16x16x32_bf16(af[i], bfv[j], acc[i][j], 0, 0, 0);
        }
    }
    int r0 = kq * 4;
    if (MODE == 0) {
        __syncthreads();
        #pragma unroll
        for (int j = 0; j < 4; j++) {
            int col = wn*64 + j*16 + lm;
            int gcol = nbase + col;
            float bb = bias[gcol];
            float ss = sv[gcol], tt = tv[gcol];
            #pragma unroll
            for (int i = 0; i < 4; i++) {
                int rowb = wm*64 + i*16 + r0;
                #pragma unroll
                for (int r = 0; r < 4; r++) {
                    float v = gelu_f((acc[i][j][r] + bb)*ss + tt);
                    __hip_bfloat16 hb = __float2bfloat16(v);
                    SH[(rowb + r)*136 + col] = *reinterpret_cast<unsigned short*>(&hb);
                }
            }
        }
        __syncthreads();
        #pragma unroll
        for (int it = 0; it < 8; it++) {
            int chunk = it*256 + tid;
            int row = chunk >> 4;
            int c8 = chunk & 15;
            int mr = mbase + row;
            if (mr < M) {
                *(u32x4*)((__hip_bfloat16*)out + (size_t)mr*N + nbase + c8*8) =
                    *(const u32x4*)(SH + row*136 + c8*8);
            }
        }
    } else {
        #pragma unroll
        for (int j = 0; j < 4; j++) {
            int col = nbase + wn*64 + j*16 + lm;
            float bb = bias[col];
            #pragma unroll
            for (int i = 0; i < 4; i++) {
                int rowb = mbase + wm*64 + i*16 + r0;
                #pragma unroll
                for (int r = 0; r < 4; r++) {
                    int row = rowb + r;
                    if (row < M) {
                        float v = acc[i][j][r] + bb;
                        ((float*)out)[(size_t)row*N + col] = v + resid[(size_t)row*N + col];
                    }
                }
            }
        }
    }
}

extern "C" void kernel_launch(void* const* d_in, const int* in_sizes, int n_in,
                              void* d_out, int out_size, void* d_ws, size_t ws_size,
                              hipStream_t stream) {
    const float* x     = (const float*)d_in[0];
    const float* emb   = (const float*)d_in[1];
    const float* n1w   = (const float*)d_in[2];
    const float* n1b   = (const float*)d_in[3];
    const float* n2w   = (const float*)d_in[4];
    const float* n2b   = (const float*)d_in[5];
    const float* w1    = (const float*)d_in[6];
    const float* b1    = (const float*)d_in[7];
    const float* w2    = (const float*)d_in[8];
    const float* b2    = (const float*)d_in[9];
    const float* fs_w0 = (const float*)d_in[10];
    const float* fs_b0 = (const float*)d_in[11];
    const float* fs_w1 = (const float*)d_in[12];
    const float* fs_b1 = (const float*)d_in[13];
    const float* fc1w  = (const float*)d_in[14];
    const float* fc1b  = (const float*)d_in[15];
    const float* fc2w  = (const float*)d_in[16];
    const float* fc2b  = (const float*)d_in[17];
    const float* ms_w0 = (const float*)d_in[18];
    const float* ms_b0 = (const float*)d_in[19];
    const float* ms_w1 = (const float*)d_in[20];
    const float* ms_b1 = (const float*)d_in[21];
    float* out = (float*)d_out;
    (void)in_sizes; (void)n_in; (void)out_size; (void)ws_size;

    char* wsb = (char*)d_ws;
    size_t off = 0;
    auto alloc = [&](size_t nbytes) -> void* {
        void* p = wsb + off;
        off += (nbytes + 255) & ~(size_t)255;
        return p;
    };
    float* s_f  = (float*)alloc(768*4);
    float* t_f  = (float*)alloc(768*4);
    float* s_m  = (float*)alloc(3072*4);
    float* t_m  = (float*)alloc(3072*4);
    float* midf = (float*)alloc(1536*4);
    float* midm = (float*)alloc(6144*4);
    __hip_bfloat16* Aw = (__hip_bfloat16*)alloc((size_t)2*384*96*2);
    __hip_bfloat16* Ew = (__hip_bfloat16*)alloc((size_t)192*384*2);
    __hip_bfloat16* Eh = (__hip_bfloat16*)alloc((size_t)4*192*384*2);
    float* Yr   = (float*)alloc((size_t)NPOS*CC*4);
    float* Yi   = (float*)alloc((size_t)NPOS*CC*4);
    float* Zr   = (float*)alloc((size_t)NPOS*CC*4);
    float* Zi   = (float*)alloc((size_t)NPOS*CC*4);
    __hip_bfloat16* wT1  = (__hip_bfloat16*)alloc((size_t)CC*LAT*2);
    __hip_bfloat16* wT2  = (__hip_bfloat16*)alloc((size_t)CC*LAT*2);
    __hip_bfloat16* h2   = (__hip_bfloat16*)alloc((size_t)NROW*CC*2);
    __hip_bfloat16* hmid = (__hip_bfloat16*)alloc((size_t)NROW*LAT*2);

    // 1. modulation scale/shift vectors + twiddle matrices
    mod_a_kernel<<<30, 256, 0, stream>>>(emb, fs_w0, fs_b0, ms_w0, ms_b0, midf, midm);
    mod_b_kernel<<<120, 512, 0, stream>>>(midf, midm, fs_w1, fs_b1, ms_w1, ms_b1,
                                          s_f, t_f, s_m, t_m);
    aw_kernel<<<144, 256, 0, stream>>>(Aw);
    ew_kernel<<<288, 256, 0, stream>>>(Ew);
    eh_kernel<<<1152, 256, 0, stream>>>(Eh);
    // 2. LN1 -> d_out (h_ln lives in d_out)
    ln_f32_kernel<<<NROW/4, 256, 0, stream>>>(x, n1w, n1b, out);
    // 3. weight convert+transpose
    transpose_bf16_kernel<<<dim3(LAT/32, CC/32), 256, 0, stream>>>(fc1w, wT1, 768, 3072);
    transpose_bf16_kernel<<<dim3(CC/32, LAT/32), 256, 0, stream>>>(fc2w, wT2, 3072, 768);

    // 4. filter path, all MFMA
    transform_mfma<0><<<dim3(6, 1, 180), 256, 0, stream>>>(Ew, out, nullptr, Yr, Yi);
    transform_mfma<1><<<dim3(6, 2, 91), 256, 0, stream>>>(Eh, Yr, Yi, Zr, Zi);               // fwd (sig 0)
    bd_kernel<0><<<dim3(512, 8), 192, 0, stream>>>(Zr, Zi, w1, b1, s_f, t_f, Yr, Yi);
    bd_kernel<1><<<dim3(512, 8), 192, 0, stream>>>(Yr, Yi, w2, b2, nullptr, nullptr, Zr, Zi);
    transform_mfma<1><<<dim3(6, 2, 91), 256, 0, stream>>>(Eh + (size_t)2*192*384, Zr, Zi, Yr, Yi);  // inv (sig 1)
    iwdft_mfma_kernel<<<dim3(6, 3, 180), 256, 0, stream>>>(Yr, Yi, Aw, x, out);

    // 5. MLP path, single pass (d_out holds h; update in place)
    ln_bf16_kernel<<<NROW/4, 256, 0, stream>>>(out, n2w, n2b, h2);
    gemm_kernel<0><<<dim3(LAT/128, (NROW+127)/128), 256, 0, stream>>>(
        h2, wT1, NROW, CC, LAT, fc1b, s_m, t_m, nullptr, hmid);
    gemm_kernel<1><<<dim3(CC/128, (NROW+127)/128), 256, 0, stream>>>(
        hmid, wT2, NROW, LAT, CC, fc2b, nullptr, nullptr, out, out);
}

// Round 9
// 2161.642 us; speedup vs baseline: 2.9730x; 1.1348x over previous
//
#include <hip/hip_runtime.h>
#include <hip/hip_bf16.h>
#include <math.h>

// Problem constants
#define HH 180
#define WW 360
#define CC 768
#define FF 91          // kept W-frequencies (km = 91)
#define NPOS (HH*FF)   // 16380 frequency positions
#define NROW (HH*WW)   // 64800 spatial rows
#define LAT 3072

typedef __attribute__((ext_vector_type(8))) short bf16x8;
typedef __attribute__((ext_vector_type(4))) float f32x4;
typedef __attribute__((ext_vector_type(4))) unsigned int u32x4;

// tanh-form gelu (max |err| vs exact-erf gelu ~1e-3; clamped against exp overflow)
__device__ __forceinline__ float gelu_f(float x) {
    float u = 0.7978845608028654f * x * (1.0f + 0.044715f * x * x);
    float e = __expf(fminf(2.0f * u, 60.0f));
    return x * e / (e + 1.0f);
}

// ---------------- modulation stage A ----------------
__global__ __launch_bounds__(256) void mod_a_kernel(
        const float* __restrict__ e,
        const float* __restrict__ fs_w0, const float* __restrict__ fs_b0,
        const float* __restrict__ ms_w0, const float* __restrict__ ms_b0,
        float* __restrict__ mid_f, float* __restrict__ mid_m) {
    __shared__ float es[64];
    int t = threadIdx.x;
    if (t < 64) es[t] = e[t];
    __syncthreads();
    int j = blockIdx.x * 256 + t;
    if (j < 1536) {
        float a = fs_b0[j];
        #pragma unroll 8
        for (int k = 0; k < 64; k++) a += es[k] * fs_w0[k*1536 + j];
        mid_f[j] = gelu_f(a);
    } else {
        int jm = j - 1536;
        float a = ms_b0[jm];
        #pragma unroll 8
        for (int k = 0; k < 64; k++) a += es[k] * ms_w0[k*6144 + jm];
        mid_m[jm] = gelu_f(a);
    }
}

// ---------------- modulation stage B ----------------
__global__ __launch_bounds__(512) void mod_b_kernel(
        const float* __restrict__ mid_f, const float* __restrict__ mid_m,
        const float* __restrict__ fs_w1, const float* __restrict__ fs_b1,
        const float* __restrict__ ms_w1, const float* __restrict__ ms_b1,
        float* __restrict__ s_f, float* __restrict__ t_f,
        float* __restrict__ s_m, float* __restrict__ t_m) {
    __shared__ float red[8*64];
    int t = threadIdx.x;
    int g = t >> 6;
    int jl = t & 63;
    int blk = blockIdx.x;
    if (blk < 24) {
        int jo = blk*64 + jl;
        const int N = 1536, NQ = 192;
        float a = 0.f;
        const float* w = fs_w1 + (size_t)(g*NQ)*N + jo;
        for (int j = 0; j < NQ; j++) a += mid_f[g*NQ + j] * w[(size_t)j*N];
        red[t] = a;
        __syncthreads();
        if (t < 64) {
            float s = fs_b1[jo];
            #pragma unroll
            for (int q = 0; q < 8; q++) s += red[q*64 + jl];
            if (jo < 768) s_f[jo] = 1.0f + s;
            else          t_f[jo - 768] = s;
        }
    } else {
        int jo = (blk - 24)*64 + jl;
        const int N = 6144, NQ = 768;
        float a = 0.f;
        const float* w = ms_w1 + (size_t)(g*NQ)*N + jo;
        for (int j = 0; j < NQ; j++) a += mid_m[g*NQ + j] * w[(size_t)j*N];
        red[t] = a;
        __syncthreads();
        if (t < 64) {
            float s = ms_b1[jo];
            #pragma unroll
            for (int q = 0; q < 8; q++) s += red[q*64 + jl];
            if (jo < 3072) s_m[jo] = 1.0f + s;
            else           t_m[jo - 3072] = s;
        }
    }
}

// ---------------- LayerNorm bf16 out ----------------
__global__ __launch_bounds__(256) void ln_bf16_kernel(const float* __restrict__ in,
        const float* __restrict__ w, const float* __restrict__ b,
        __hip_bfloat16* __restrict__ out) {
    int row = blockIdx.x*4 + (threadIdx.x >> 6);
    int l = threadIdx.x & 63;
    const float* p = in + (size_t)row*CC;
    float v[12]; float s = 0.f, sq = 0.f;
    #pragma unroll
    for (int i = 0; i < 12; i++) { float tv = p[l + 64*i]; v[i] = tv; s += tv; sq += tv*tv; }
    #pragma unroll
    for (int m = 1; m < 64; m <<= 1) { s += __shfl_xor(s, m); sq += __shfl_xor(sq, m); }
    float mean = s * (1.0f/768.0f);
    float var  = sq * (1.0f/768.0f) - mean*mean;
    float rstd = rsqrtf(var + 1e-5f);
    __hip_bfloat16* o = out + (size_t)row*CC;
    #pragma unroll
    for (int i = 0; i < 12; i++) { int c = l + 64*i; o[c] = __float2bfloat16((v[i]-mean)*rstd*w[c] + b[c]); }
}

// ---------------- twiddle matrices ----------------
// Ew[192][384]: rows 0-95: cos(th f w)*rn (f<91,w<360 else 0); rows 96-191: -sin*rn
__global__ __launch_bounds__(256) void ew_kernel(__hip_bfloat16* __restrict__ Ew) {
    int idx = blockIdx.x*256 + threadIdx.x;
    if (idx >= 192*384) return;
    int r = idx / 384, w = idx - (idx/384)*384;
    int f = (r < 96) ? r : r - 96;
    const float rn = 0.05270462766947299f;  // 1/sqrt(360)
    float v = 0.f;
    if (f < FF && w < WW) {
        int p = (f * w) % 360;
        float ang = 6.283185307179586f/360.0f * (float)p;
        float s_, c_; sincosf(ang, &s_, &c_);
        v = (r < 96) ? c_*rn : -s_*rn;
    }
    Ew[idx] = __float2bfloat16(v);
}

// Eh[sig][plane][192][384]: E=e^{s i ph t h}*rnh; plane0(Or)=[C | -sS]; plane1(Oi)=[sS | C]
__global__ __launch_bounds__(256) void eh_kernel(__hip_bfloat16* __restrict__ Eh) {
    int idx = blockIdx.x*256 + threadIdx.x;
    if (idx >= 4*192*384) return;
    int sp = idx / (192*384);
    int rem = idx - sp*(192*384);
    int t = rem / 384, k = rem - (rem/384)*384;
    int sig = sp >> 1, plane = sp & 1;
    float s = (sig == 0) ? -1.f : 1.f;
    int h = (k < 192) ? k : k - 192;
    const float rnh = 0.07453559924999299f;  // 1/sqrt(180)
    float v = 0.f;
    if (t < HH && h < HH) {
        int p = (t * h) % 180;
        float ang = 6.283185307179586f/180.0f * (float)p;
        float s_, c_; sincosf(ang, &s_, &c_);
        float C = c_*rnh, S = s_*rnh;
        if (plane == 0) v = (k < 192) ? C : -s*S;
        else            v = (k < 192) ? s*S : C;
    }
    Eh[idx] = __float2bfloat16(v);
}

// ---------------- bd stacked-complex weight pack: Bt[wb][n2][k2] bf16 ----------------
// cols n2<96 = Or output, n2>=96 = Oi ; rows k2<96 = Yr input, k2>=96 = Yi
// Or = Yr@W0 - Yi@W1 ; Oi = Yr@W1 + Yi@W0
__global__ __launch_bounds__(256) void bdw_kernel(const float* __restrict__ w,
        __hip_bfloat16* __restrict__ Bt) {
    int idx = blockIdx.x*256 + threadIdx.x;   // 8*192*192 = 294912
    if (idx >= 8*192*192) return;
    int wb = idx / (192*192);
    int rem = idx - wb*(192*192);
    int n2 = rem / 192, k2 = rem - (rem/192)*192;
    int k = (k2 < 96) ? k2 : k2 - 96;
    int oc = (n2 < 96) ? n2 : n2 - 96;
    float w0 = w[((size_t)wb*96 + k)*96 + oc];          // w[0][wb][k][oc]
    float w1v = w[((size_t)(8 + wb)*96 + k)*96 + oc];   // w[1][wb][k][oc]
    float v;
    if (n2 < 96) v = (k2 < 96) ? w0 : -w1v;
    else         v = (k2 < 96) ? w1v : w0;
    Bt[idx] = __float2bfloat16(v);
}

// ---------------- MFMA transform: C[192 rows][128 c] = A[192][384] @ B[384][c] ----------------
// MODE 0 (wdft): batch=h; B rows k=w<360 from B0 (BSRC=1 -> bf16 hln); out -> Yr/Yi
// MODE 1 (hfft): batch=f; B rows k<192 -> B0=Ir[h=k], k>=192 -> B1=Ii; plane=blockIdx.y
template<int MODE, int BSRC>
__global__ __launch_bounds__(256) void transform_mfma(
        const __hip_bfloat16* __restrict__ Amat,
        const float* __restrict__ B0, const float* __restrict__ B1,
        float* __restrict__ O0, float* __restrict__ O1) {
    __shared__ __align__(16) unsigned short As[192*72];
    __shared__ __align__(16) unsigned short Bs[128*72];
    int nbase = blockIdx.x * 128;
    int bat = blockIdx.z;
    int tid = threadIdx.x;
    int l = tid & 63, wv = tid >> 6;
    int wm = wv & 1, wn = wv >> 1;
    int lm = l & 15, kq = l >> 4;
    const __hip_bfloat16* Ab = Amat + (MODE == 1 ? (size_t)blockIdx.y*192*384 : 0);
    size_t bRowStride = (MODE == 0) ? (size_t)CC : (size_t)FF*CC;
    size_t bBase      = (MODE == 0) ? (size_t)bat*WW*CC : (size_t)bat*CC;
    f32x4 acc[6][4] = {};
    for (int kt = 0; kt < 6; kt++) {
        int kb = kt*64;
        __syncthreads();
        // stage A [192][64] bf16 (L2-hot)
        #pragma unroll
        for (int it = 0; it < 6; it++) {
            int ch = it*256 + tid;           // 1536 chunks of 16B
            int row = ch >> 3, co = (ch & 7) * 8;
            u32x4 v = *(const u32x4*)(Ab + (size_t)row*384 + kb + co);
            *(u32x4*)(As + row*72 + co) = v;
        }
        if (MODE == 0 && BSRC == 1) {
            // stage B [64 k][128 c] bf16 -> Bs[c][k] (transpose, raw copy)
            const __hip_bfloat16* Bb = (const __hip_bfloat16*)B0;
            #pragma unroll
            for (int it = 0; it < 4; it++) {
                int idx = it*256 + tid;      // 1024 chunks of 8 channels
                int row = idx >> 4;          // k-local 0..63
                int cq = (idx & 15) * 8;
                int k = kb + row;
                unsigned int u[4] = {0u, 0u, 0u, 0u};
                if (k < WW) {
                    u32x4 v = *(const u32x4*)(Bb + bBase + (size_t)k*bRowStride + nbase + cq);
                    u[0] = v[0]; u[1] = v[1]; u[2] = v[2]; u[3] = v[3];
                }
                #pragma unroll
                for (int j = 0; j < 4; j++) {
                    Bs[(cq + 2*j    )*72 + row] = (unsigned short)(u[j] & 0xffffu);
                    Bs[(cq + 2*j + 1)*72 + row] = (unsigned short)(u[j] >> 16);
                }
            }
        } else {
            // stage B [64 k][128 c] fp32 -> Bs[c][k] bf16 (transpose)
            #pragma unroll
            for (int it = 0; it < 8; it++) {
                int idx = it*256 + tid;          // 2048 float4 quads
                int row = idx >> 5;              // k-local 0..63
                int cq = (idx & 31) * 4;
                int k = kb + row;
                float4 v = make_float4(0.f, 0.f, 0.f, 0.f);
                if (MODE == 0) {
                    if (k < WW) v = *(const float4*)(B0 + bBase + (size_t)k*bRowStride + nbase + cq);
                } else {
                    if (k < 192) { if (k < HH) v = *(const float4*)(B0 + bBase + (size_t)k*bRowStride + nbase + cq); }
                    else { int h2 = k - 192; if (h2 < HH) v = *(const float4*)(B1 + bBase + (size_t)h2*bRowStride + nbase + cq); }
                }
                __hip_bfloat16 b0 = __float2bfloat16(v.x);
                __hip_bfloat16 b1 = __float2bfloat16(v.y);
                __hip_bfloat16 b2 = __float2bfloat16(v.z);
                __hip_bfloat16 b3 = __float2bfloat16(v.w);
                Bs[(cq+0)*72 + row] = *reinterpret_cast<unsigned short*>(&b0);
                Bs[(cq+1)*72 + row] = *reinterpret_cast<unsigned short*>(&b1);
                Bs[(cq+2)*72 + row] = *reinterpret_cast<unsigned short*>(&b2);
                Bs[(cq+3)*72 + row] = *reinterpret_cast<unsigned short*>(&b3);
            }
        }
        __syncthreads();
        #pragma unroll
        for (int kk = 0; kk < 2; kk++) {
            int kg = kk*32 + kq*8;
            bf16x8 af[6], bfv[4];
            #pragma unroll
            for (int i = 0; i < 6; i++)
                af[i] = *(const bf16x8*)(As + (wm*96 + i*16 + lm)*72 + kg);
            #pragma unroll
            for (int j = 0; j < 4; j++)
                bfv[j] = *(const bf16x8*)(Bs + (wn*64 + j*16 + lm)*72 + kg);
            #pragma unroll
            for (int i = 0; i < 6; i++)
                #pragma unroll
                for (int j = 0; j < 4; j++)
                    acc[i][j] = __builtin_amdgcn_mfma_f32_16x16x32_bf16(af[i], bfv[j], acc[i][j], 0, 0, 0);
        }
    }
    int r0 = kq * 4;
    #pragma unroll
    for (int j = 0; j < 4; j++) {
        int col = nbase + wn*64 + j*16 + lm;
        #pragma unroll
        for (int i = 0; i < 6; i++) {
            #pragma unroll
            for (int r = 0; r < 4; r++) {
                int row = wm*96 + i*16 + r0 + r;
                float v = acc[i][j][r];
                if (MODE == 0) {
                    if (row < 96) {
                        if (row < FF) O0[(size_t)bat*FF*CC + (size_t)row*CC + col] = v;
                    } else {
                        int f2 = row - 96;
                        if (f2 < FF) O1[(size_t)bat*FF*CC + (size_t)f2*CC + col] = v;
                    }
                } else {
                    if (row < HH) {
                        float* Op = blockIdx.y ? O1 : O0;
                        Op[(size_t)row*FF*CC + (size_t)bat*CC + col] = v;
                    }
                }
            }
        }
    }
}

// ---------------- block-diagonal complex matmul via MFMA (stacked-complex GEMM) ----------------
// per wb: C[16380 p][192 n2] = A[p][192 k2] @ Bt[wb][n2][k2]^T ; 6 waves, tile 128x192, BK=64
// LAYER 0: v = relu((acc+bias)*s + t) ; LAYER 1: v = softshrink(acc+bias)
template<int LAYER>
__global__ __launch_bounds__(384) void bd_mfma_kernel(
        const float* __restrict__ Ir, const float* __restrict__ Ii,
        const __hip_bfloat16* __restrict__ Bt,
        const float* __restrict__ bias,
        const float* __restrict__ sf, const float* __restrict__ tf,
        float* __restrict__ Or_, float* __restrict__ Oi_) {
    __shared__ __align__(16) unsigned short As[128*72];
    __shared__ __align__(16) unsigned short Bs[192*72];
    int mbase = blockIdx.x * 128;
    int wb = blockIdx.y;
    int tid = threadIdx.x;
    int l = tid & 63, wv = tid >> 6;      // 6 waves
    int wm = wv & 1, wn = wv >> 1;        // wm 0..1, wn 0..2
    int lm = l & 15, kq = l >> 4;
    const __hip_bfloat16* Bw = Bt + (size_t)wb*192*192;
    f32x4 acc[4][4] = {};
    for (int kt = 0; kt < 3; kt++) {
        __syncthreads();
        // stage A: [128 p][64 k2] from Yr/Yi fp32 -> bf16 (k2<96: Yr, else Yi)
        for (int ch = tid; ch < 2048; ch += 384) {
            int row = ch >> 4, q = ch & 15;
            int k2 = kt*64 + q*4;
            int p = mbase + row; if (p >= NPOS) p = NPOS - 1;
            const float* src = (k2 < 96) ? (Ir + (size_t)p*CC + wb*96 + k2)
                                         : (Ii + (size_t)p*CC + wb*96 + (k2 - 96));
            float4 v = *(const float4*)src;
            __hip_bfloat16 b0 = __float2bfloat16(v.x);
            __hip_bfloat16 b1 = __float2bfloat16(v.y);
            __hip_bfloat16 b2 = __float2bfloat16(v.z);
            __hip_bfloat16 b3 = __float2bfloat16(v.w);
            unsigned int lo = (unsigned int)*reinterpret_cast<unsigned short*>(&b0)
                            | ((unsigned int)*reinterpret_cast<unsigned short*>(&b1) << 16);
            unsigned int hi = (unsigned int)*reinterpret_cast<unsigned short*>(&b2)
                            | ((unsigned int)*reinterpret_cast<unsigned short*>(&b3) << 16);
            *(uint2*)(As + row*72 + q*4) = make_uint2(lo, hi);
        }
        // stage B: [192 n2][64 k2] bf16 raw copy
        for (int ch = tid; ch < 1536; ch += 384) {
            int row = ch >> 3, co = (ch & 7) * 8;
            u32x4 v = *(const u32x4*)(Bw + (size_t)row*192 + kt*64 + co);
            *(u32x4*)(Bs + row*72 + co) = v;
        }
        __syncthreads();
        #pragma unroll
        for (int kk = 0; kk < 2; kk++) {
            int kg = kk*32 + kq*8;
            bf16x8 af[4], bfv[4];
            #pragma unroll
            for (int i = 0; i < 4; i++) {
                af[i]  = *(const bf16x8*)(As + (wm*64 + i*16 + lm)*72 + kg);
                bfv[i] = *(const bf16x8*)(Bs + (wn*64 + i*16 + lm)*72 + kg);
            }
            #pragma unroll
            for (int i = 0; i < 4; i++)
                #pragma unroll
                for (int j = 0; j < 4; j++)
                    acc[i][j] = __builtin_amdgcn_mfma_f32_16x16x32_bf16(af[i], bfv[j], acc[i][j], 0, 0, 0);
        }
    }
    int r0 = kq * 4;
    #pragma unroll
    for (int j = 0; j < 4; j++) {
        int n2 = wn*64 + j*16 + lm;
        int oc = (n2 < 96) ? n2 : n2 - 96;
        float bb = bias[((n2 < 96) ? 0 : 768) + wb*96 + oc];
        float ss = 0.f, tt = 0.f;
        if (LAYER == 0) { ss = sf[wb*96 + oc]; tt = tf[wb*96 + oc]; }
        float* Op = (n2 < 96) ? Or_ : Oi_;
        #pragma unroll
        for (int i = 0; i < 4; i++) {
            #pragma unroll
            for (int r = 0; r < 4; r++) {
                int p = mbase + wm*64 + i*16 + r0 + r;
                if (p < NPOS) {
                    float v = acc[i][j][r] + bb;
                    if (LAYER == 0) {
                        v = fmaxf(v*ss + tt, 0.0f);
                    } else {
                        v = (v > 0.01f) ? (v - 0.01f) : ((v < -0.01f) ? (v + 0.01f) : 0.0f);
                    }
                    Op[(size_t)p*CC + wb*96 + oc] = v;
                }
            }
        }
    }
}

// ---------------- inverse W-DFT matrices (bf16) ----------------
__global__ __launch_bounds__(256) void aw_kernel(__hip_bfloat16* __restrict__ Aw) {
    int idx = blockIdx.x*256 + threadIdx.x;   // 384*96 = 36864
    if (idx >= 384*96) return;
    int w = idx / 96, f = idx - (idx/96)*96;
    const float rn = 0.05270462766947299f;
    float m = (f == 0) ? rn : ((f < FF) ? 2.0f*rn : 0.0f);
    int p = (int)(((long long)f * w) % 360);
    float ang = 6.283185307179586f / 360.0f * (float)p;
    float s_, c_; sincosf(ang, &s_, &c_);
    Aw[idx]          = __float2bfloat16(m * c_);
    Aw[384*96 + idx] = __float2bfloat16(-m * s_);
}

// ---------------- inverse rDFT along W via MFMA; out = idft + hln(bf16) + x ----------------
__global__ __launch_bounds__(256) void iwdft_mfma_kernel(
        const float* __restrict__ Zr, const float* __restrict__ Zi,
        const __hip_bfloat16* __restrict__ Aw,
        const __hip_bfloat16* __restrict__ hlnb,
        const float* __restrict__ xin, float* __restrict__ hout) {
    __shared__ __align__(16) unsigned short As[128*104];   // [w][f], pad 104
    __shared__ __align__(16) unsigned short Bs[128*104];   // [c][f], pad 104
    int h = blockIdx.z;
    int mbase = blockIdx.y * 128;   // w
    int nbase = blockIdx.x * 128;   // c
    int tid = threadIdx.x;
    int l = tid & 63, wv = tid >> 6;
    int wm = wv & 1, wn = wv >> 1;
    int lm = l & 15, kq = l >> 4;
    f32x4 acc[4][4] = {};
    #pragma unroll
    for (int ph = 0; ph < 2; ph++) {
        __syncthreads();
        for (int ch = tid; ch < 1536; ch += 256) {
            int row = ch / 12, co = (ch - row*12) * 8;
            u32x4 v = *(const u32x4*)(Aw + ((size_t)ph*384 + mbase + row)*96 + co);
            *(u32x4*)(As + row*104 + co) = v;
        }
        const float* Zp = ph ? Zi : Zr;
        for (int ch = tid; ch < 96*32; ch += 256) {
            int f = ch >> 5, cg = (ch & 31) * 4;
            float4 v;
            if (f < FF) v = *(const float4*)(Zp + ((size_t)h*FF + f)*CC + nbase + cg);
            else        v = make_float4(0.f, 0.f, 0.f, 0.f);
            __hip_bfloat16 b0 = __float2bfloat16(v.x);
            __hip_bfloat16 b1 = __float2bfloat16(v.y);
            __hip_bfloat16 b2 = __float2bfloat16(v.z);
            __hip_bfloat16 b3 = __float2bfloat16(v.w);
            Bs[(cg+0)*104 + f] = *reinterpret_cast<unsigned short*>(&b0);
            Bs[(cg+1)*104 + f] = *reinterpret_cast<unsigned short*>(&b1);
            Bs[(cg+2)*104 + f] = *reinterpret_cast<unsigned short*>(&b2);
            Bs[(cg+3)*104 + f] = *reinterpret_cast<unsigned short*>(&b3);
        }
        __syncthreads();
        #pragma unroll
        for (int ks = 0; ks < 3; ks++) {
            int kg = ks*32 + kq*8;
            bf16x8 af[4], bfv[4];
            #pragma unroll
            for (int i = 0; i < 4; i++) {
                af[i]  = *(const bf16x8*)(As + (wm*64 + i*16 + lm)*104 + kg);
                bfv[i] = *(const bf16x8*)(Bs + (wn*64 + i*16 + lm)*104 + kg);
            }
            #pragma unroll
            for (int i = 0; i < 4; i++)
                #pragma unroll
                for (int j = 0; j < 4; j++)
                    acc[i][j] = __builtin_amdgcn_mfma_f32_16x16x32_bf16(af[i], bfv[j], acc[i][j], 0, 0, 0);
        }
    }
    int r0 = kq * 4;
    #pragma unroll
    for (int j = 0; j < 4; j++) {
        int col = nbase + wn*64 + j*16 + lm;
        #pragma unroll
        for (int i = 0; i < 4; i++) {
            int rowb = wm*64 + i*16 + r0;
            #pragma unroll
            for (int r = 0; r < 4; r++) {
                int wp = mbase + rowb + r;
                if (wp < WW) {
                    size_t idx = ((size_t)h*WW + wp)*CC + col;
                    hout[idx] = acc[i][j][r] + __bfloat162float(hlnb[idx]) + xin[idx];
                }
            }
        }
    }
}

// ---------------- tiled weight transpose + bf16 convert ----------------
__global__ __launch_bounds__(256) void transpose_bf16_kernel(const float* __restrict__ src,
        __hip_bfloat16* __restrict__ dst, int K, int N) {
    __shared__ float tile[32][33];
    int n0 = blockIdx.x * 32;
    int k0 = blockIdx.y * 32;
    int tx = threadIdx.x & 31;
    int ty = threadIdx.x >> 5;
    #pragma unroll
    for (int r = 0; r < 32; r += 8) {
        tile[ty + r][tx] = src[(size_t)(k0 + ty + r) * N + n0 + tx];
    }
    __syncthreads();
    #pragma unroll
    for (int r = 0; r < 32; r += 8) {
        dst[(size_t)(n0 + ty + r) * K + k0 + tx] = __float2bfloat16(tile[tx][ty + r]);
    }
}

// ---------------- bf16 MFMA GEMM, 128x128 tile, BK=64, 4 waves ----------------
template<int MODE>
__global__ __launch_bounds__(256) void gemm_kernel(
        const __hip_bfloat16* __restrict__ A,
        const __hip_bfloat16* __restrict__ Bt,
        int M, int K, int N,
        const float* __restrict__ bias,
        const float* __restrict__ sv, const float* __restrict__ tv,
        const float* resid, void* out) {
    __shared__ __align__(16) unsigned short SH[128*136];
    unsigned short* As = SH;              // [128][64]
    unsigned short* Bs = SH + 128*64;     // [128][64]
    int tid = threadIdx.x;
    int nbase = blockIdx.x * 128;
    int mbase = blockIdx.y * 128;
    int l = tid & 63, wv = tid >> 6;
    int wm = wv & 1, wn = wv >> 1;
    int lm = l & 15;
    int kq = l >> 4;
    f32x4 acc[4][4] = {};
    int nkt = K >> 6;
    for (int kt = 0; kt < nkt; kt++) {
        int kb = kt << 6;
        __syncthreads();
        #pragma unroll
        for (int i = 0; i < 4; i++) {
            int ch = i*256 + tid;
            int row = ch >> 3;
            int sl = ch & 7;
            int kg = (sl ^ (row & 7)) << 3;
            int am = mbase + row; if (am >= M) am = M - 1;
            const __hip_bfloat16* ga = A  + (size_t)am * K + kb + kg;
            const __hip_bfloat16* gb = Bt + (size_t)(nbase + row) * K + kb + kg;
            __builtin_amdgcn_global_load_lds(
                (const __attribute__((address_space(1))) void*)(unsigned long long)(uintptr_t)ga,
                (__attribute__((address_space(3))) void*)(unsigned long long)(uintptr_t)(As + ch*8),
                16, 0, 0);
            __builtin_amdgcn_global_load_lds(
                (const __attribute__((address_space(1))) void*)(unsigned long long)(uintptr_t)gb,
                (__attribute__((address_space(3))) void*)(unsigned long long)(uintptr_t)(Bs + ch*8),
                16, 0, 0);
        }
        __syncthreads();
        #pragma unroll
        for (int kk = 0; kk < 2; kk++) {
            bf16x8 af[4], bfv[4];
            #pragma unroll
            for (int i = 0; i < 4; i++) {
                int ra = wm*64 + i*16 + lm;
                af[i]  = *(const bf16x8*)(As + ra*64 + ((((kk<<2)+kq) ^ (ra&7))<<3));
                int rb = wn*64 + i*16 + lm;
                bfv[i] = *(const bf16x8*)(Bs + rb*64 + ((((kk<<2)+kq) ^ (rb&7))<<3));
            }
            #pragma unroll
            for (int i = 0; i < 4; i++)
                #pragma unroll
                for (int j = 0; j < 4; j++)
                    acc[i][j] = __builtin_amdgcn_mfma_f32_16x16x32_bf16(af[i], bfv[j], acc[i][j], 0, 0, 0);
        }
    }
    int r0 = kq * 4;
    if (MODE == 0) {
        __syncthreads();
        #pragma unroll
        for (int j = 0; j < 4; j++) {
            int col = wn*64 + j*16 + lm;
            int gcol = nbase + col;
            float bb = bias[gcol];
            float ss = sv[gcol], tt = tv[gcol];
            #pragma unroll
            for (int i = 0; i < 4; i++) {
                int rowb = wm*64 + i*16 + r0;
                #pragma unroll
                for (int r = 0; r < 4; r++) {
                    float v = gelu_f((acc[i][j][r] + bb)*ss + tt);
                    __hip_bfloat16 hb = __float2bfloat16(v);
                    SH[(rowb + r)*136 + col] = *reinterpret_cast<unsigned short*>(&hb);
                }
            }
        }
        __syncthreads();
        #pragma unroll
        for (int it = 0; it < 8; it++) {
            int chunk = it*256 + tid;
            int row = chunk >> 4;
            int c8 = chunk & 15;
            int mr = mbase + row;
            if (mr < M) {
                *(u32x4*)((__hip_bfloat16*)out + (size_t)mr*N + nbase + c8*8) =
                    *(const u32x4*)(SH + row*136 + c8*8);
            }
        }
    } else {
        #pragma unroll
        for (int j = 0; j < 4; j++) {
            int col = nbase + wn*64 + j*16 + lm;
            float bb = bias[col];
            #pragma unroll
            for (int i = 0; i < 4; i++) {
                int rowb = mbase + wm*64 + i*16 + r0;
                #pragma unroll
                for (int r = 0; r < 4; r++) {
                    int row = rowb + r;
                    if (row < M) {
                        float v = acc[i][j][r] + bb;
                        ((float*)out)[(size_t)row*N + col] = v + resid[(size_t)row*N + col];
                    }
                }
            }
        }
    }
}

extern "C" void kernel_launch(void* const* d_in, const int* in_sizes, int n_in,
                              void* d_out, int out_size, void* d_ws, size_t ws_size,
                              hipStream_t stream) {
    const float* x     = (const float*)d_in[0];
    const float* emb   = (const float*)d_in[1];
    const float* n1w   = (const float*)d_in[2];
    const float* n1b   = (const float*)d_in[3];
    const float* n2w   = (const float*)d_in[4];
    const float* n2b   = (const float*)d_in[5];
    const float* w1    = (const float*)d_in[6];
    const float* b1    = (const float*)d_in[7];
    const float* w2    = (const float*)d_in[8];
    const float* b2    = (const float*)d_in[9];
    const float* fs_w0 = (const float*)d_in[10];
    const float* fs_b0 = (const float*)d_in[11];
    const float* fs_w1 = (const float*)d_in[12];
    const float* fs_b1 = (const float*)d_in[13];
    const float* fc1w  = (const float*)d_in[14];
    const float* fc1b  = (const float*)d_in[15];
    const float* fc2w  = (const float*)d_in[16];
    const float* fc2b  = (const float*)d_in[17];
    const float* ms_w0 = (const float*)d_in[18];
    const float* ms_b0 = (const float*)d_in[19];
    const float* ms_w1 = (const float*)d_in[20];
    const float* ms_b1 = (const float*)d_in[21];
    float* out = (float*)d_out;
    (void)in_sizes; (void)n_in; (void)out_size; (void)ws_size;

    char* wsb = (char*)d_ws;
    size_t off = 0;
    auto alloc = [&](size_t nbytes) -> void* {
        void* p = wsb + off;
        off += (nbytes + 255) & ~(size_t)255;
        return p;
    };
    float* s_f  = (float*)alloc(768*4);
    float* t_f  = (float*)alloc(768*4);
    float* s_m  = (float*)alloc(3072*4);
    float* t_m  = (float*)alloc(3072*4);
    float* midf = (float*)alloc(1536*4);
    float* midm = (float*)alloc(6144*4);
    __hip_bfloat16* Aw  = (__hip_bfloat16*)alloc((size_t)2*384*96*2);
    __hip_bfloat16* Ew  = (__hip_bfloat16*)alloc((size_t)192*384*2);
    __hip_bfloat16* Eh  = (__hip_bfloat16*)alloc((size_t)4*192*384*2);
    __hip_bfloat16* Bt1 = (__hip_bfloat16*)alloc((size_t)8*192*192*2);
    __hip_bfloat16* Bt2 = (__hip_bfloat16*)alloc((size_t)8*192*192*2);
    float* Yr   = (float*)alloc((size_t)NPOS*CC*4);
    float* Yi   = (float*)alloc((size_t)NPOS*CC*4);
    float* Zr   = (float*)alloc((size_t)NPOS*CC*4);
    float* Zi   = (float*)alloc((size_t)NPOS*CC*4);
    __hip_bfloat16* wT1  = (__hip_bfloat16*)alloc((size_t)CC*LAT*2);
    __hip_bfloat16* wT2  = (__hip_bfloat16*)alloc((size_t)CC*LAT*2);
    __hip_bfloat16* h2   = (__hip_bfloat16*)alloc((size_t)NROW*CC*2);
    __hip_bfloat16* hmid = (__hip_bfloat16*)alloc((size_t)NROW*LAT*2);
    // h_ln (bf16) aliases h2: lifetimes are disjoint (hlnb dead before ln2 writes h2)
    __hip_bfloat16* hlnb = h2;

    // 1. modulation scale/shift vectors + twiddle/weight matrices
    mod_a_kernel<<<30, 256, 0, stream>>>(emb, fs_w0, fs_b0, ms_w0, ms_b0, midf, midm);
    mod_b_kernel<<<120, 512, 0, stream>>>(midf, midm, fs_w1, fs_b1, ms_w1, ms_b1,
                                          s_f, t_f, s_m, t_m);
    aw_kernel<<<144, 256, 0, stream>>>(Aw);
    ew_kernel<<<288, 256, 0, stream>>>(Ew);
    eh_kernel<<<1152, 256, 0, stream>>>(Eh);
    bdw_kernel<<<1152, 256, 0, stream>>>(w1, Bt1);
    bdw_kernel<<<1152, 256, 0, stream>>>(w2, Bt2);
    // 2. LN1 -> hlnb (bf16)
    ln_bf16_kernel<<<NROW/4, 256, 0, stream>>>(x, n1w, n1b, hlnb);
    // 3. weight convert+transpose
    transpose_bf16_kernel<<<dim3(LAT/32, CC/32), 256, 0, stream>>>(fc1w, wT1, 768, 3072);
    transpose_bf16_kernel<<<dim3(CC/32, LAT/32), 256, 0, stream>>>(fc2w, wT2, 3072, 768);

    // 4. filter path, all MFMA
    transform_mfma<0,1><<<dim3(6, 1, 180), 256, 0, stream>>>(Ew, (const float*)hlnb, nullptr, Yr, Yi);
    transform_mfma<1,0><<<dim3(6, 2, 91), 256, 0, stream>>>(Eh, Yr, Yi, Zr, Zi);               // fwd
    bd_mfma_kernel<0><<<dim3(128, 8), 384, 0, stream>>>(Zr, Zi, Bt1, b1, s_f, t_f, Yr, Yi);
    bd_mfma_kernel<1><<<dim3(128, 8), 384, 0, stream>>>(Yr, Yi, Bt2, b2, nullptr, nullptr, Zr, Zi);
    transform_mfma<1,0><<<dim3(6, 2, 91), 256, 0, stream>>>(Eh + (size_t)2*192*384, Zr, Zi, Yr, Yi);  // inv
    iwdft_mfma_kernel<<<dim3(6, 3, 180), 256, 0, stream>>>(Yr, Yi, Aw, hlnb, x, out);

    // 5. MLP path (d_out holds h; update in place)
    ln_bf16_kernel<<<NROW/4, 256, 0, stream>>>(out, n2w, n2b, h2);
    gemm_kernel<0><<<dim3(LAT/128, (NROW+127)/128), 256, 0, stream>>>(
        h2, wT1, NROW, CC, LAT, fc1b, s_m, t_m, nullptr, hmid);
    gemm_kernel<1><<<dim3(CC/128, (NROW+127)/128), 256, 0, stream>>>(
        hmid, wT2, NROW, LAT, CC, fc2b, nullptr, nullptr, out, out);
}

// Round 10
// 2030.521 us; speedup vs baseline: 3.1650x; 1.0646x over previous
//
#include <hip/hip_runtime.h>
#include <hip/hip_bf16.h>
#include <math.h>

// Problem constants
#define HH 180
#define WW 360
#define CC 768
#define FF 91          // kept W-frequencies (km = 91)
#define NPOS (HH*FF)   // 16380 frequency positions
#define NROW (HH*WW)   // 64800 spatial rows
#define LAT 3072

typedef __attribute__((ext_vector_type(8))) short bf16x8;
typedef __attribute__((ext_vector_type(4))) float f32x4;
typedef __attribute__((ext_vector_type(4))) unsigned int u32x4;

__device__ __forceinline__ float gelu_f(float x) {
    return 0.5f * x * (1.0f + erff(x * 0.7071067811865476f));
}

// ---------------- modulation stage A ----------------
__global__ __launch_bounds__(256) void mod_a_kernel(
        const float* __restrict__ e,
        const float* __restrict__ fs_w0, const float* __restrict__ fs_b0,
        const float* __restrict__ ms_w0, const float* __restrict__ ms_b0,
        float* __restrict__ mid_f, float* __restrict__ mid_m) {
    __shared__ float es[64];
    int t = threadIdx.x;
    if (t < 64) es[t] = e[t];
    __syncthreads();
    int j = blockIdx.x * 256 + t;
    if (j < 1536) {
        float a = fs_b0[j];
        #pragma unroll 8
        for (int k = 0; k < 64; k++) a += es[k] * fs_w0[k*1536 + j];
        mid_f[j] = gelu_f(a);
    } else {
        int jm = j - 1536;
        float a = ms_b0[jm];
        #pragma unroll 8
        for (int k = 0; k < 64; k++) a += es[k] * ms_w0[k*6144 + jm];
        mid_m[jm] = gelu_f(a);
    }
}

// ---------------- modulation stage B ----------------
__global__ __launch_bounds__(512) void mod_b_kernel(
        const float* __restrict__ mid_f, const float* __restrict__ mid_m,
        const float* __restrict__ fs_w1, const float* __restrict__ fs_b1,
        const float* __restrict__ ms_w1, const float* __restrict__ ms_b1,
        float* __restrict__ s_f, float* __restrict__ t_f,
        float* __restrict__ s_m, float* __restrict__ t_m) {
    __shared__ float red[8*64];
    int t = threadIdx.x;
    int g = t >> 6;
    int jl = t & 63;
    int blk = blockIdx.x;
    if (blk < 24) {
        int jo = blk*64 + jl;
        const int N = 1536, NQ = 192;
        float a = 0.f;
        const float* w = fs_w1 + (size_t)(g*NQ)*N + jo;
        for (int j = 0; j < NQ; j++) a += mid_f[g*NQ + j] * w[(size_t)j*N];
        red[t] = a;
        __syncthreads();
        if (t < 64) {
            float s = fs_b1[jo];
            #pragma unroll
            for (int q = 0; q < 8; q++) s += red[q*64 + jl];
            if (jo < 768) s_f[jo] = 1.0f + s;
            else          t_f[jo - 768] = s;
        }
    } else {
        int jo = (blk - 24)*64 + jl;
        const int N = 6144, NQ = 768;
        float a = 0.f;
        const float* w = ms_w1 + (size_t)(g*NQ)*N + jo;
        for (int j = 0; j < NQ; j++) a += mid_m[g*NQ + j] * w[(size_t)j*N];
        red[t] = a;
        __syncthreads();
        if (t < 64) {
            float s = ms_b1[jo];
            #pragma unroll
            for (int q = 0; q < 8; q++) s += red[q*64 + jl];
            if (jo < 3072) s_m[jo] = 1.0f + s;
            else           t_m[jo - 3072] = s;
        }
    }
}

// ---------------- LayerNorm bf16 out ----------------
__global__ __launch_bounds__(256) void ln_bf16_kernel(const float* __restrict__ in,
        const float* __restrict__ w, const float* __restrict__ b,
        __hip_bfloat16* __restrict__ out) {
    int row = blockIdx.x*4 + (threadIdx.x >> 6);
    int l = threadIdx.x & 63;
    const float* p = in + (size_t)row*CC;
    float v[12]; float s = 0.f, sq = 0.f;
    #pragma unroll
    for (int i = 0; i < 12; i++) { float tv = p[l + 64*i]; v[i] = tv; s += tv; sq += tv*tv; }
    #pragma unroll
    for (int m = 1; m < 64; m <<= 1) { s += __shfl_xor(s, m); sq += __shfl_xor(sq, m); }
    float mean = s * (1.0f/768.0f);
    float var  = sq * (1.0f/768.0f) - mean*mean;
    float rstd = rsqrtf(var + 1e-5f);
    __hip_bfloat16* o = out + (size_t)row*CC;
    #pragma unroll
    for (int i = 0; i < 12; i++) { int c = l + 64*i; o[c] = __float2bfloat16((v[i]-mean)*rstd*w[c] + b[c]); }
}

// ---------------- twiddle matrices ----------------
__global__ __launch_bounds__(256) void ew_kernel(__hip_bfloat16* __restrict__ Ew) {
    int idx = blockIdx.x*256 + threadIdx.x;
    if (idx >= 192*384) return;
    int r = idx / 384, w = idx - (idx/384)*384;
    int f = (r < 96) ? r : r - 96;
    const float rn = 0.05270462766947299f;  // 1/sqrt(360)
    float v = 0.f;
    if (f < FF && w < WW) {
        int p = (f * w) % 360;
        float ang = 6.283185307179586f/360.0f * (float)p;
        float s_, c_; sincosf(ang, &s_, &c_);
        v = (r < 96) ? c_*rn : -s_*rn;
    }
    Ew[idx] = __float2bfloat16(v);
}

__global__ __launch_bounds__(256) void eh_kernel(__hip_bfloat16* __restrict__ Eh) {
    int idx = blockIdx.x*256 + threadIdx.x;
    if (idx >= 4*192*384) return;
    int sp = idx / (192*384);
    int rem = idx - sp*(192*384);
    int t = rem / 384, k = rem - (rem/384)*384;
    int sig = sp >> 1, plane = sp & 1;
    float s = (sig == 0) ? -1.f : 1.f;
    int h = (k < 192) ? k : k - 192;
    const float rnh = 0.07453559924999299f;  // 1/sqrt(180)
    float v = 0.f;
    if (t < HH && h < HH) {
        int p = (t * h) % 180;
        float ang = 6.283185307179586f/180.0f * (float)p;
        float s_, c_; sincosf(ang, &s_, &c_);
        float C = c_*rnh, S = s_*rnh;
        if (plane == 0) v = (k < 192) ? C : -s*S;
        else            v = (k < 192) ? s*S : C;
    }
    Eh[idx] = __float2bfloat16(v);
}

// ---------------- bd stacked-complex weight pack ----------------
__global__ __launch_bounds__(256) void bdw_kernel(const float* __restrict__ w,
        __hip_bfloat16* __restrict__ Bt) {
    int idx = blockIdx.x*256 + threadIdx.x;   // 8*192*192 = 294912
    if (idx >= 8*192*192) return;
    int wb = idx / (192*192);
    int rem = idx - wb*(192*192);
    int n2 = rem / 192, k2 = rem - (rem/192)*192;
    int k = (k2 < 96) ? k2 : k2 - 96;
    int oc = (n2 < 96) ? n2 : n2 - 96;
    float w0 = w[((size_t)wb*96 + k)*96 + oc];
    float w1v = w[((size_t)(8 + wb)*96 + k)*96 + oc];
    float v;
    if (n2 < 96) v = (k2 < 96) ? w0 : -w1v;
    else         v = (k2 < 96) ? w1v : w0;
    Bt[idx] = __float2bfloat16(v);
}

// ---------------- MFMA transform: C[192 rows][128 c] = A[192][384] @ B[384][c] ----------------
template<int MODE, int BSRC>
__global__ __launch_bounds__(256) void transform_mfma(
        const __hip_bfloat16* __restrict__ Amat,
        const float* __restrict__ B0, const float* __restrict__ B1,
        float* __restrict__ O0, float* __restrict__ O1) {
    __shared__ __align__(16) unsigned short As[192*72];
    __shared__ __align__(16) unsigned short Bs[128*72];
    int nbase = blockIdx.x * 128;
    int bat = blockIdx.z;
    int tid = threadIdx.x;
    int l = tid & 63, wv = tid >> 6;
    int wm = wv & 1, wn = wv >> 1;
    int lm = l & 15, kq = l >> 4;
    const __hip_bfloat16* Ab = Amat + (MODE == 1 ? (size_t)blockIdx.y*192*384 : 0);
    size_t bRowStride = (MODE == 0) ? (size_t)CC : (size_t)FF*CC;
    size_t bBase      = (MODE == 0) ? (size_t)bat*WW*CC : (size_t)bat*CC;
    f32x4 acc[6][4] = {};
    for (int kt = 0; kt < 6; kt++) {
        int kb = kt*64;
        __syncthreads();
        #pragma unroll
        for (int it = 0; it < 6; it++) {
            int ch = it*256 + tid;
            int row = ch >> 3, co = (ch & 7) * 8;
            u32x4 v = *(const u32x4*)(Ab + (size_t)row*384 + kb + co);
            *(u32x4*)(As + row*72 + co) = v;
        }
        if (MODE == 0 && BSRC == 1) {
            const __hip_bfloat16* Bb = (const __hip_bfloat16*)B0;
            #pragma unroll
            for (int it = 0; it < 4; it++) {
                int idx = it*256 + tid;
                int row = idx >> 4;
                int cq = (idx & 15) * 8;
                int k = kb + row;
                unsigned int u[4] = {0u, 0u, 0u, 0u};
                if (k < WW) {
                    u32x4 v = *(const u32x4*)(Bb + bBase + (size_t)k*bRowStride + nbase + cq);
                    u[0] = v[0]; u[1] = v[1]; u[2] = v[2]; u[3] = v[3];
                }
                #pragma unroll
                for (int j = 0; j < 4; j++) {
                    Bs[(cq + 2*j    )*72 + row] = (unsigned short)(u[j] & 0xffffu);
                    Bs[(cq + 2*j + 1)*72 + row] = (unsigned short)(u[j] >> 16);
                }
            }
        } else {
            #pragma unroll
            for (int it = 0; it < 8; it++) {
                int idx = it*256 + tid;
                int row = idx >> 5;
                int cq = (idx & 31) * 4;
                int k = kb + row;
                float4 v = make_float4(0.f, 0.f, 0.f, 0.f);
                if (MODE == 0) {
                    if (k < WW) v = *(const float4*)(B0 + bBase + (size_t)k*bRowStride + nbase + cq);
                } else {
                    if (k < 192) { if (k < HH) v = *(const float4*)(B0 + bBase + (size_t)k*bRowStride + nbase + cq); }
                    else { int h2 = k - 192; if (h2 < HH) v = *(const float4*)(B1 + bBase + (size_t)h2*bRowStride + nbase + cq); }
                }
                __hip_bfloat16 b0 = __float2bfloat16(v.x);
                __hip_bfloat16 b1 = __float2bfloat16(v.y);
                __hip_bfloat16 b2 = __float2bfloat16(v.z);
                __hip_bfloat16 b3 = __float2bfloat16(v.w);
                Bs[(cq+0)*72 + row] = *reinterpret_cast<unsigned short*>(&b0);
                Bs[(cq+1)*72 + row] = *reinterpret_cast<unsigned short*>(&b1);
                Bs[(cq+2)*72 + row] = *reinterpret_cast<unsigned short*>(&b2);
                Bs[(cq+3)*72 + row] = *reinterpret_cast<unsigned short*>(&b3);
            }
        }
        __syncthreads();
        #pragma unroll
        for (int kk = 0; kk < 2; kk++) {
            int kg = kk*32 + kq*8;
            bf16x8 af[6], bfv[4];
            #pragma unroll
            for (int i = 0; i < 6; i++)
                af[i] = *(const bf16x8*)(As + (wm*96 + i*16 + lm)*72 + kg);
            #pragma unroll
            for (int j = 0; j < 4; j++)
                bfv[j] = *(const bf16x8*)(Bs + (wn*64 + j*16 + lm)*72 + kg);
            #pragma unroll
            for (int i = 0; i < 6; i++)
                #pragma unroll
                for (int j = 0; j < 4; j++)
                    acc[i][j] = __builtin_amdgcn_mfma_f32_16x16x32_bf16(af[i], bfv[j], acc[i][j], 0, 0, 0);
        }
    }
    int r0 = kq * 4;
    #pragma unroll
    for (int j = 0; j < 4; j++) {
        int col = nbase + wn*64 + j*16 + lm;
        #pragma unroll
        for (int i = 0; i < 6; i++) {
            #pragma unroll
            for (int r = 0; r < 4; r++) {
                int row = wm*96 + i*16 + r0 + r;
                float v = acc[i][j][r];
                if (MODE == 0) {
                    if (row < 96) {
                        if (row < FF) O0[(size_t)bat*FF*CC + (size_t)row*CC + col] = v;
                    } else {
                        int f2 = row - 96;
                        if (f2 < FF) O1[(size_t)bat*FF*CC + (size_t)f2*CC + col] = v;
                    }
                } else {
                    if (row < HH) {
                        float* Op = blockIdx.y ? O1 : O0;
                        Op[(size_t)row*FF*CC + (size_t)bat*CC + col] = v;
                    }
                }
            }
        }
    }
}

// ---------------- block-diagonal complex matmul via MFMA (stacked-complex GEMM) ----------------
template<int LAYER>
__global__ __launch_bounds__(384) void bd_mfma_kernel(
        const float* __restrict__ Ir, const float* __restrict__ Ii,
        const __hip_bfloat16* __restrict__ Bt,
        const float* __restrict__ bias,
        const float* __restrict__ sf, const float* __restrict__ tf,
        float* __restrict__ Or_, float* __restrict__ Oi_) {
    __shared__ __align__(16) unsigned short As[128*72];
    __shared__ __align__(16) unsigned short Bs[192*72];
    int mbase = blockIdx.x * 128;
    int wb = blockIdx.y;
    int tid = threadIdx.x;
    int l = tid & 63, wv = tid >> 6;      // 6 waves
    int wm = wv & 1, wn = wv >> 1;
    int lm = l & 15, kq = l >> 4;
    const __hip_bfloat16* Bw = Bt + (size_t)wb*192*192;
    f32x4 acc[4][4] = {};
    for (int kt = 0; kt < 3; kt++) {
        __syncthreads();
        for (int ch = tid; ch < 2048; ch += 384) {
            int row = ch >> 4, q = ch & 15;
            int k2 = kt*64 + q*4;
            int p = mbase + row; if (p >= NPOS) p = NPOS - 1;
            const float* src = (k2 < 96) ? (Ir + (size_t)p*CC + wb*96 + k2)
                                         : (Ii + (size_t)p*CC + wb*96 + (k2 - 96));
            float4 v = *(const float4*)src;
            __hip_bfloat16 b0 = __float2bfloat16(v.x);
            __hip_bfloat16 b1 = __float2bfloat16(v.y);
            __hip_bfloat16 b2 = __float2bfloat16(v.z);
            __hip_bfloat16 b3 = __float2bfloat16(v.w);
            unsigned int lo = (unsigned int)*reinterpret_cast<unsigned short*>(&b0)
                            | ((unsigned int)*reinterpret_cast<unsigned short*>(&b1) << 16);
            unsigned int hi = (unsigned int)*reinterpret_cast<unsigned short*>(&b2)
                            | ((unsigned int)*reinterpret_cast<unsigned short*>(&b3) << 16);
            *(uint2*)(As + row*72 + q*4) = make_uint2(lo, hi);
        }
        for (int ch = tid; ch < 1536; ch += 384) {
            int row = ch >> 3, co = (ch & 7) * 8;
            u32x4 v = *(const u32x4*)(Bw + (size_t)row*192 + kt*64 + co);
            *(u32x4*)(Bs + row*72 + co) = v;
        }
        __syncthreads();
        #pragma unroll
        for (int kk = 0; kk < 2; kk++) {
            int kg = kk*32 + kq*8;
            bf16x8 af[4], bfv[4];
            #pragma unroll
            for (int i = 0; i < 4; i++) {
                af[i]  = *(const bf16x8*)(As + (wm*64 + i*16 + lm)*72 + kg);
                bfv[i] = *(const bf16x8*)(Bs + (wn*64 + i*16 + lm)*72 + kg);
            }
            #pragma unroll
            for (int i = 0; i < 4; i++)
                #pragma unroll
                for (int j = 0; j < 4; j++)
                    acc[i][j] = __builtin_amdgcn_mfma_f32_16x16x32_bf16(af[i], bfv[j], acc[i][j], 0, 0, 0);
        }
    }
    int r0 = kq * 4;
    #pragma unroll
    for (int j = 0; j < 4; j++) {
        int n2 = wn*64 + j*16 + lm;
        int oc = (n2 < 96) ? n2 : n2 - 96;
        float bb = bias[((n2 < 96) ? 0 : 768) + wb*96 + oc];
        float ss = 0.f, tt = 0.f;
        if (LAYER == 0) { ss = sf[wb*96 + oc]; tt = tf[wb*96 + oc]; }
        float* Op = (n2 < 96) ? Or_ : Oi_;
        #pragma unroll
        for (int i = 0; i < 4; i++) {
            #pragma unroll
            for (int r = 0; r < 4; r++) {
                int p = mbase + wm*64 + i*16 + r0 + r;
                if (p < NPOS) {
                    float v = acc[i][j][r] + bb;
                    if (LAYER == 0) {
                        v = fmaxf(v*ss + tt, 0.0f);
                    } else {
                        v = (v > 0.01f) ? (v - 0.01f) : ((v < -0.01f) ? (v + 0.01f) : 0.0f);
                    }
                    Op[(size_t)p*CC + wb*96 + oc] = v;
                }
            }
        }
    }
}

// ---------------- inverse W-DFT matrices (bf16) ----------------
__global__ __launch_bounds__(256) void aw_kernel(__hip_bfloat16* __restrict__ Aw) {
    int idx = blockIdx.x*256 + threadIdx.x;   // 384*96 = 36864
    if (idx >= 384*96) return;
    int w = idx / 96, f = idx - (idx/96)*96;
    const float rn = 0.05270462766947299f;
    float m = (f == 0) ? rn : ((f < FF) ? 2.0f*rn : 0.0f);
    int p = (int)(((long long)f * w) % 360);
    float ang = 6.283185307179586f / 360.0f * (float)p;
    float s_, c_; sincosf(ang, &s_, &c_);
    Aw[idx]          = __float2bfloat16(m * c_);
    Aw[384*96 + idx] = __float2bfloat16(-m * s_);
}

// ---------------- inverse rDFT along W via MFMA; out = idft + hln(bf16) + x ----------------
__global__ __launch_bounds__(256) void iwdft_mfma_kernel(
        const float* __restrict__ Zr, const float* __restrict__ Zi,
        const __hip_bfloat16* __restrict__ Aw,
        const __hip_bfloat16* __restrict__ hlnb,
        const float* __restrict__ xin, float* __restrict__ hout) {
    __shared__ __align__(16) unsigned short As[128*104];
    __shared__ __align__(16) unsigned short Bs[128*104];
    int h = blockIdx.z;
    int mbase = blockIdx.y * 128;   // w
    int nbase = blockIdx.x * 128;   // c
    int tid = threadIdx.x;
    int l = tid & 63, wv = tid >> 6;
    int wm = wv & 1, wn = wv >> 1;
    int lm = l & 15, kq = l >> 4;
    f32x4 acc[4][4] = {};
    #pragma unroll
    for (int ph = 0; ph < 2; ph++) {
        __syncthreads();
        for (int ch = tid; ch < 1536; ch += 256) {
            int row = ch / 12, co = (ch - row*12) * 8;
            u32x4 v = *(const u32x4*)(Aw + ((size_t)ph*384 + mbase + row)*96 + co);
            *(u32x4*)(As + row*104 + co) = v;
        }
        const float* Zp = ph ? Zi : Zr;
        for (int ch = tid; ch < 96*32; ch += 256) {
            int f = ch >> 5, cg = (ch & 31) * 4;
            float4 v;
            if (f < FF) v = *(const float4*)(Zp + ((size_t)h*FF + f)*CC + nbase + cg);
            else        v = make_float4(0.f, 0.f, 0.f, 0.f);
            __hip_bfloat16 b0 = __float2bfloat16(v.x);
            __hip_bfloat16 b1 = __float2bfloat16(v.y);
            __hip_bfloat16 b2 = __float2bfloat16(v.z);
            __hip_bfloat16 b3 = __float2bfloat16(v.w);
            Bs[(cg+0)*104 + f] = *reinterpret_cast<unsigned short*>(&b0);
            Bs[(cg+1)*104 + f] = *reinterpret_cast<unsigned short*>(&b1);
            Bs[(cg+2)*104 + f] = *reinterpret_cast<unsigned short*>(&b2);
            Bs[(cg+3)*104 + f] = *reinterpret_cast<unsigned short*>(&b3);
        }
        __syncthreads();
        #pragma unroll
        for (int ks = 0; ks < 3; ks++) {
            int kg = ks*32 + kq*8;
            bf16x8 af[4], bfv[4];
            #pragma unroll
            for (int i = 0; i < 4; i++) {
                af[i]  = *(const bf16x8*)(As + (wm*64 + i*16 + lm)*104 + kg);
                bfv[i] = *(const bf16x8*)(Bs + (wn*64 + i*16 + lm)*104 + kg);
            }
            #pragma unroll
            for (int i = 0; i < 4; i++)
                #pragma unroll
                for (int j = 0; j < 4; j++)
                    acc[i][j] = __builtin_amdgcn_mfma_f32_16x16x32_bf16(af[i], bfv[j], acc[i][j], 0, 0, 0);
        }
    }
    int r0 = kq * 4;
    #pragma unroll
    for (int j = 0; j < 4; j++) {
        int col = nbase + wn*64 + j*16 + lm;
        #pragma unroll
        for (int i = 0; i < 4; i++) {
            int rowb = wm*64 + i*16 + r0;
            #pragma unroll
            for (int r = 0; r < 4; r++) {
                int wp = mbase + rowb + r;
                if (wp < WW) {
                    size_t idx = ((size_t)h*WW + wp)*CC + col;
                    hout[idx] = acc[i][j][r] + __bfloat162float(hlnb[idx]) + xin[idx];
                }
            }
        }
    }
}

// ---------------- tiled weight transpose + bf16 convert ----------------
__global__ __launch_bounds__(256) void transpose_bf16_kernel(const float* __restrict__ src,
        __hip_bfloat16* __restrict__ dst, int K, int N) {
    __shared__ float tile[32][33];
    int n0 = blockIdx.x * 32;
    int k0 = blockIdx.y * 32;
    int tx = threadIdx.x & 31;
    int ty = threadIdx.x >> 5;
    #pragma unroll
    for (int r = 0; r < 32; r += 8) {
        tile[ty + r][tx] = src[(size_t)(k0 + ty + r) * N + n0 + tx];
    }
    __syncthreads();
    #pragma unroll
    for (int r = 0; r < 32; r += 8) {
        dst[(size_t)(n0 + ty + r) * K + k0 + tx] = __float2bfloat16(tile[tx][ty + r]);
    }
}

// ---------------- bf16 MFMA GEMM, 256x256 tile, BK=64, 8 waves (2M x 4N), 2-phase dbuf ----------------
// LDS: A dbuf 2x[256][64] + B dbuf 2x[256][64] = 128 KB; XOR-swizzle slot = kchunk ^ (row&7)
// MODE 0: out = bf16(gelu((A@B + bias)*s + t)), LDS-staged coalesced store
// MODE 1: out = A@B + bias + resid (fp32)
template<int MODE>
__global__ __launch_bounds__(512, 2) void gemm256_kernel(
        const __hip_bfloat16* __restrict__ A,
        const __hip_bfloat16* __restrict__ Bt,
        int M, int K, int N,
        const float* __restrict__ bias,
        const float* __restrict__ sv, const float* __restrict__ tv,
        const float* resid, void* out) {
    __shared__ __align__(16) unsigned short SH[65536];    // 128 KB
    unsigned short* Asb = SH;            // [2][256*64]
    unsigned short* Bsb = SH + 32768;    // [2][256*64]
    int tid = threadIdx.x;
    int nbase = blockIdx.x * 256;
    int mbase = blockIdx.y * 256;
    int l = tid & 63, wv = tid >> 6;     // 8 waves
    int wm = wv & 1, wn = wv >> 1;       // wm 0..1 (128 rows), wn 0..3 (64 cols)
    int lm = l & 15, kq = l >> 4;
    f32x4 acc[8][4] = {};
    int nkt = K >> 6;

    auto stage = [&](int d, int kt) {
        int kb = kt << 6;
        #pragma unroll
        for (int i = 0; i < 4; i++) {
            int ch = i*512 + tid;            // 0..2047
            int row = ch >> 3;
            int sl = ch & 7;
            int kg = (sl ^ (row & 7)) << 3;  // swizzled source k-offset (elements)
            int am = mbase + row; if (am >= M) am = M - 1;
            const __hip_bfloat16* ga = A  + (size_t)am * K + kb + kg;
            const __hip_bfloat16* gb = Bt + (size_t)(nbase + row) * K + kb + kg;
            __builtin_amdgcn_global_load_lds(
                (const __attribute__((address_space(1))) void*)(unsigned long long)(uintptr_t)ga,
                (__attribute__((address_space(3))) void*)(unsigned long long)(uintptr_t)(Asb + d*16384 + ch*8),
                16, 0, 0);
            __builtin_amdgcn_global_load_lds(
                (const __attribute__((address_space(1))) void*)(unsigned long long)(uintptr_t)gb,
                (__attribute__((address_space(3))) void*)(unsigned long long)(uintptr_t)(Bsb + d*16384 + ch*8),
                16, 0, 0);
        }
    };

    stage(0, 0);
    __syncthreads();                 // compiler drains vmcnt(0) before barrier
    for (int kt = 0; kt < nkt; kt++) {
        if (kt + 1 < nkt) stage((kt + 1) & 1, kt + 1);   // prefetch next K-tile
        int d = kt & 1;
        const unsigned short* Ab = Asb + d*16384;
        const unsigned short* Bb = Bsb + d*16384;
        #pragma unroll
        for (int kk = 0; kk < 2; kk++) {
            bf16x8 af[8], bfv[4];
            #pragma unroll
            for (int i = 0; i < 8; i++) {
                int ra = wm*128 + i*16 + lm;
                af[i] = *(const bf16x8*)(Ab + ra*64 + ((((kk<<2)+kq) ^ (ra&7))<<3));
            }
            #pragma unroll
            for (int j = 0; j < 4; j++) {
                int rb = wn*64 + j*16 + lm;
                bfv[j] = *(const bf16x8*)(Bb + rb*64 + ((((kk<<2)+kq) ^ (rb&7))<<3));
            }
            #pragma unroll
            for (int i = 0; i < 8; i++)
                #pragma unroll
                for (int j = 0; j < 4; j++)
                    acc[i][j] = __builtin_amdgcn_mfma_f32_16x16x32_bf16(af[i], bfv[j], acc[i][j], 0, 0, 0);
        }
        __syncthreads();             // drains this iter's prefetch loads + frees buf d
    }

    int r0 = kq * 4;
    if (MODE == 0) {
        // epilogue: gelu+mod -> bf16 tile in LDS [256][256], then coalesced store
        #pragma unroll
        for (int j = 0; j < 4; j++) {
            int col = wn*64 + j*16 + lm;
            int gcol = nbase + col;
            float bb = bias[gcol];
            float ss = sv[gcol], tt = tv[gcol];
            #pragma unroll
            for (int i = 0; i < 8; i++) {
                int rowb = wm*128 + i*16 + r0;
                #pragma unroll
                for (int r = 0; r < 4; r++) {
                    float v = gelu_f((acc[i][j][r] + bb)*ss + tt);
                    __hip_bfloat16 hb = __float2bfloat16(v);
                    SH[(rowb + r)*256 + col] = *reinterpret_cast<unsigned short*>(&hb);
                }
            }
        }
        __syncthreads();
        #pragma unroll
        for (int it = 0; it < 16; it++) {
            int chunk = it*512 + tid;    // 8192 chunks of 16B (256 rows x 32)
            int row = chunk >> 5;
            int c8 = chunk & 31;
            int mr = mbase + row;
            if (mr < M) {
                *(u32x4*)((__hip_bfloat16*)out + (size_t)mr*N + nbase + c8*8) =
                    *(const u32x4*)(SH + row*256 + c8*8);
            }
        }
    } else {
        #pragma unroll
        for (int j = 0; j < 4; j++) {
            int col = nbase + wn*64 + j*16 + lm;
            float bb = bias[col];
            #pragma unroll
            for (int i = 0; i < 8; i++) {
                int rowb = mbase + wm*128 + i*16 + r0;
                #pragma unroll
                for (int r = 0; r < 4; r++) {
                    int row = rowb + r;
                    if (row < M) {
                        float v = acc[i][j][r] + bb;
                        ((float*)out)[(size_t)row*N + col] = v + resid[(size_t)row*N + col];
                    }
                }
            }
        }
    }
}

extern "C" void kernel_launch(void* const* d_in, const int* in_sizes, int n_in,
                              void* d_out, int out_size, void* d_ws, size_t ws_size,
                              hipStream_t stream) {
    const float* x     = (const float*)d_in[0];
    const float* emb   = (const float*)d_in[1];
    const float* n1w   = (const float*)d_in[2];
    const float* n1b   = (const float*)d_in[3];
    const float* n2w   = (const float*)d_in[4];
    const float* n2b   = (const float*)d_in[5];
    const float* w1    = (const float*)d_in[6];
    const float* b1    = (const float*)d_in[7];
    const float* w2    = (const float*)d_in[8];
    const float* b2    = (const float*)d_in[9];
    const float* fs_w0 = (const float*)d_in[10];
    const float* fs_b0 = (const float*)d_in[11];
    const float* fs_w1 = (const float*)d_in[12];
    const float* fs_b1 = (const float*)d_in[13];
    const float* fc1w  = (const float*)d_in[14];
    const float* fc1b  = (const float*)d_in[15];
    const float* fc2w  = (const float*)d_in[16];
    const float* fc2b  = (const float*)d_in[17];
    const float* ms_w0 = (const float*)d_in[18];
    const float* ms_b0 = (const float*)d_in[19];
    const float* ms_w1 = (const float*)d_in[20];
    const float* ms_b1 = (const float*)d_in[21];
    float* out = (float*)d_out;
    (void)in_sizes; (void)n_in; (void)out_size; (void)ws_size;

    char* wsb = (char*)d_ws;
    size_t off = 0;
    auto alloc = [&](size_t nbytes) -> void* {
        void* p = wsb + off;
        off += (nbytes + 255) & ~(size_t)255;
        return p;
    };
    float* s_f  = (float*)alloc(768*4);
    float* t_f  = (float*)alloc(768*4);
    float* s_m  = (float*)alloc(3072*4);
    float* t_m  = (float*)alloc(3072*4);
    float* midf = (float*)alloc(1536*4);
    float* midm = (float*)alloc(6144*4);
    __hip_bfloat16* Aw  = (__hip_bfloat16*)alloc((size_t)2*384*96*2);
    __hip_bfloat16* Ew  = (__hip_bfloat16*)alloc((size_t)192*384*2);
    __hip_bfloat16* Eh  = (__hip_bfloat16*)alloc((size_t)4*192*384*2);
    __hip_bfloat16* Bt1 = (__hip_bfloat16*)alloc((size_t)8*192*192*2);
    __hip_bfloat16* Bt2 = (__hip_bfloat16*)alloc((size_t)8*192*192*2);
    float* Yr   = (float*)alloc((size_t)NPOS*CC*4);
    float* Yi   = (float*)alloc((size_t)NPOS*CC*4);
    float* Zr   = (float*)alloc((size_t)NPOS*CC*4);
    float* Zi   = (float*)alloc((size_t)NPOS*CC*4);
    __hip_bfloat16* wT1  = (__hip_bfloat16*)alloc((size_t)CC*LAT*2);
    __hip_bfloat16* wT2  = (__hip_bfloat16*)alloc((size_t)CC*LAT*2);
    __hip_bfloat16* h2   = (__hip_bfloat16*)alloc((size_t)NROW*CC*2);
    __hip_bfloat16* hmid = (__hip_bfloat16*)alloc((size_t)NROW*LAT*2);
    // h_ln (bf16) aliases h2: lifetimes are disjoint
    __hip_bfloat16* hlnb = h2;

    // 1. modulation scale/shift vectors + twiddle/weight matrices
    mod_a_kernel<<<30, 256, 0, stream>>>(emb, fs_w0, fs_b0, ms_w0, ms_b0, midf, midm);
    mod_b_kernel<<<120, 512, 0, stream>>>(midf, midm, fs_w1, fs_b1, ms_w1, ms_b1,
                                          s_f, t_f, s_m, t_m);
    aw_kernel<<<144, 256, 0, stream>>>(Aw);
    ew_kernel<<<288, 256, 0, stream>>>(Ew);
    eh_kernel<<<1152, 256, 0, stream>>>(Eh);
    bdw_kernel<<<1152, 256, 0, stream>>>(w1, Bt1);
    bdw_kernel<<<1152, 256, 0, stream>>>(w2, Bt2);
    // 2. LN1 -> hlnb (bf16)
    ln_bf16_kernel<<<NROW/4, 256, 0, stream>>>(x, n1w, n1b, hlnb);
    // 3. weight convert+transpose
    transpose_bf16_kernel<<<dim3(LAT/32, CC/32), 256, 0, stream>>>(fc1w, wT1, 768, 3072);
    transpose_bf16_kernel<<<dim3(CC/32, LAT/32), 256, 0, stream>>>(fc2w, wT2, 3072, 768);

    // 4. filter path, all MFMA
    transform_mfma<0,1><<<dim3(6, 1, 180), 256, 0, stream>>>(Ew, (const float*)hlnb, nullptr, Yr, Yi);
    transform_mfma<1,0><<<dim3(6, 2, 91), 256, 0, stream>>>(Eh, Yr, Yi, Zr, Zi);               // fwd
    bd_mfma_kernel<0><<<dim3(128, 8), 384, 0, stream>>>(Zr, Zi, Bt1, b1, s_f, t_f, Yr, Yi);
    bd_mfma_kernel<1><<<dim3(128, 8), 384, 0, stream>>>(Yr, Yi, Bt2, b2, nullptr, nullptr, Zr, Zi);
    transform_mfma<1,0><<<dim3(6, 2, 91), 256, 0, stream>>>(Eh + (size_t)2*192*384, Zr, Zi, Yr, Yi);  // inv
    iwdft_mfma_kernel<<<dim3(6, 3, 180), 256, 0, stream>>>(Yr, Yi, Aw, hlnb, x, out);

    // 5. MLP path (d_out holds h; update in place)
    ln_bf16_kernel<<<NROW/4, 256, 0, stream>>>(out, n2w, n2b, h2);
    gemm256_kernel<0><<<dim3(LAT/256, (NROW+255)/256), 512, 0, stream>>>(
        h2, wT1, NROW, CC, LAT, fc1b, s_m, t_m, nullptr, hmid);
    gemm256_kernel<1><<<dim3(CC/256, (NROW+255)/256), 512, 0, stream>>>(
        hmid, wT2, NROW, LAT, CC, fc2b, nullptr, nullptr, out, out);
}